// Round 5
// baseline (33085.117 us; speedup 1.0000x reference)
//
#include <hip/hip_runtime.h>

// ---------------------------------------------------------------------------
// DCRNN (2-layer DCGRU encoder) -- MFMA round, weight-stream fix.
// Round-4 post-mortem: spill stores eliminated (WRITE 4.9GB -> 0.3MB), but
// FETCH stayed 5.8GB == repacked weights re-streamed from global EVERY step
// (960KB/step/block x 96 x 64 = 5.9GB), loaded at point-of-use one barrier
// apart -> latency-bound at 238GB/s == the whole 26ms runtime.
// This round:
//   * lo-plane weight loads conditional on wlo (bf16 bench never needs them)
//     -> stream halves to ~3GB
//   * per-phase software pipeline: gate weights in named double-buffer regs
//     ga0..3/gb0..3 (4 s8v each), cand ca0..1/cb0..1 (2 s8v each), loaded
//     ONE PHASE AHEAD (prologue in P0) -> latency hidden under compute
//   * apply's S-lo LDS read also wlo-guarded
// Algorithm identical to round 4 (verified absmax 2.4e-4).
// ---------------------------------------------------------------------------

#define RS 68              // term-buffer row stride (bf16 elems)
#define TPB 17408          // one term plane: 128*68*2 bytes
#define SPB 8704           // one 64-row plane: 64*68*2 bytes
#define OFF_S   104448     // 3 term buffers * 2 planes
#define OFF_HB  139264     // OFF_S + 4*SPB
#define OFF_BG  156672     // OFF_HB + 2*SPB
#define OFF_BC  157696
#define OFF_CTL 158208
#define SMEM_SZ 158240
#define GN 81920           // gate repack elems per (layer,plane)
#define CN 40960           // cand repack elems per (layer,plane)
#define WS_NEED ((4*GN + 4*CN) * 2)

typedef __attribute__((ext_vector_type(4))) short s4v;
typedef __attribute__((ext_vector_type(8))) short s8v;
typedef __attribute__((ext_vector_type(4))) float f4v;

#define MFMA16(a, b, c) __builtin_amdgcn_mfma_f32_16x16x32_bf16((a), (b), (c), 0, 0, 0)

__device__ __forceinline__ float dcr_b2f(unsigned short x) {
  return __uint_as_float(((unsigned)x) << 16);
}
__device__ __forceinline__ unsigned short dcr_f2b(float x) {
  unsigned u = __float_as_uint(x);
  u += 0x7fffu + ((u >> 16) & 1u);
  return (unsigned short)(u >> 16);
}
__device__ __forceinline__ void dcr_split(float v, unsigned short& h, unsigned short& l) {
  h = dcr_f2b(v);
  l = dcr_f2b(v - dcr_b2f(h));
}
__device__ __forceinline__ float dcr_ld(const void* p, int idx, int isf) {
  if (isf) return ((const float*)p)[idx];
  return dcr_b2f(((const unsigned short*)p)[idx]);
}
__device__ __forceinline__ float dcr_sigm(float x) {
  return 1.0f / (1.0f + __expf(-x));
}
__device__ __forceinline__ float dcr_tanh(float x) {
  return 2.0f / (1.0f + __expf(-2.0f * x)) - 1.0f;
}
__device__ __forceinline__ s8v dcr_ld8(const unsigned short* p) {
  s8v r;
  *(s4v*)&r = *(const s4v*)p;
  *((s4v*)&r + 1) = *(const s4v*)(p + 4);
  return r;
}

// ---------------- weight repack: W[(f*5+m)][col] -> fragment order -----------
// gate (per layer,plane): e = (((m*8+nt)*4+ks)*64+lane)*8 + j
// cand (per layer,plane): e = (((m*4+nt)*4+ks)*64+lane)*8 + j
// element = W[(ks*32 + ((lane>>4)&3)*8 + j)*5 + m][nt*16 + (lane&15)]
__global__ void dcr_repack(const void* wg0, const void* wc0,
                           const void* wg1, const void* wc1,
                           const void* s0, unsigned short* o) {
  __shared__ int sisf;
  if (threadIdx.x == 0) {
    const unsigned short* ss = (const unsigned short*)s0;
    int hits = 0;
    for (int i = 0; i < 32; ++i) {
      unsigned hb = ((unsigned)ss[2 * i] >> 8) & 0xFFu;
      if (hb >= 0x30u && hb <= 0x3Fu) ++hits;
    }
    sisf = (hits < 16) ? 1 : 0;
  }
  __syncthreads();
  const int isf = sisf;
  const int NT = 4 * GN + 4 * CN;
  for (int e = blockIdx.x * blockDim.x + threadIdx.x; e < NT;
       e += gridDim.x * blockDim.x) {
    const void* W;
    int pl, ee, ncol, m, nt, ks, lane, j;
    if (e < 4 * GN) {
      int li = e / (2 * GN);
      int rem = e - li * 2 * GN;
      pl = rem / GN;
      ee = rem - pl * GN;
      W = li ? wg1 : wg0;
      ncol = 128;
      j = ee & 7; lane = (ee >> 3) & 63; ks = (ee >> 9) & 3;
      nt = (ee >> 11) & 7; m = ee >> 14;
    } else {
      int c = e - 4 * GN;
      int li = c / (2 * CN);
      int rem = c - li * 2 * CN;
      pl = rem / CN;
      ee = rem - pl * CN;
      W = li ? wc1 : wc0;
      ncol = 64;
      j = ee & 7; lane = (ee >> 3) & 63; ks = (ee >> 9) & 3;
      nt = (ee >> 11) & 3; m = ee >> 13;
    }
    if (pl == 1 && !isf) continue;
    const int f = ks * 32 + ((lane >> 4) & 3) * 8 + j;
    const int col = nt * 16 + (lane & 15);
    const int si = (f * 5 + m) * ncol + col;
    unsigned short v;
    if (!isf) {
      v = ((const unsigned short*)W)[si];
    } else {
      float w = ((const float*)W)[si];
      unsigned short hh = dcr_f2b(w);
      v = (pl == 0) ? hh : dcr_f2b(w - dcr_b2f(hh));
    }
    o[e] = v;
  }
}

// ---------------- MFMA building blocks --------------------------------------
// gate proj one m-term: wave w (0..7) owns N-tile w, M-tiles 0..3.
// hi weights arrive as pre-loaded regs bh0..bh3 (one per ks); lo streamed
// at-use only when wlo (fp32 inputs).
__device__ __forceinline__ void dcr_gp(f4v& A0, f4v& A1, f4v& A2, f4v& A3,
                                       const unsigned short* th,
                                       const unsigned short* tl,
                                       s8v bh0, s8v bh1, s8v bh2, s8v bh3,
                                       const unsigned short* rpl,
                                       int m, int w, int lane, int wlo) {
  const int ln15 = lane & 15;
  const int k8 = ((lane >> 4) & 3) * 8;
#define DCR_GP_KS(BH, KS)                                                  \
  {                                                                        \
    s8v bl;                                                                \
    if (wlo)                                                               \
      bl = *(const s8v*)(rpl + (((m * 8 + w) * 4 + (KS)) * 64 + lane) * 8);\
    const int kb = (KS) * 32 + k8;                                         \
    DCR_GP_MT(A0, 0, BH)                                                   \
    DCR_GP_MT(A1, 1, BH)                                                   \
    DCR_GP_MT(A2, 2, BH)                                                   \
    DCR_GP_MT(A3, 3, BH)                                                   \
  }
#define DCR_GP_MT(AX, MT, BH)                                              \
    {                                                                      \
      const int node = (MT) * 16 + ln15;                                   \
      s8v ah, al;                                                          \
      _Pragma("unroll") for (int j = 0; j < 8; ++j) {                      \
        const int a = (kb + j) * RS + node;                                \
        ah[j] = (short)th[a];                                              \
        al[j] = (short)tl[a];                                              \
      }                                                                    \
      AX = MFMA16(ah, BH, AX);                                             \
      AX = MFMA16(al, BH, AX);                                             \
      if (wlo) AX = MFMA16(ah, bl, AX);                                    \
    }
  DCR_GP_KS(bh0, 0)
  DCR_GP_KS(bh1, 1)
  DCR_GP_KS(bh2, 2)
  DCR_GP_KS(bh3, 3)
#undef DCR_GP_KS
#undef DCR_GP_MT
}

// cand proj one m-term: wave w4 (0..3) owns cand N-tile w4. pass 0 = x-half
// (abs ks 0..1), pass 1 = rh-half (abs ks 2..3). hi weights pre-loaded
// (bh0, bh1); lo streamed at-use when wlo.
__device__ __forceinline__ void dcr_cp(f4v& A0, f4v& A1, f4v& A2, f4v& A3,
                                       const unsigned short* th,
                                       const unsigned short* tl,
                                       s8v bh0, s8v bh1,
                                       const unsigned short* rpl,
                                       int m, int w4, int lane, int wlo,
                                       int pass) {
  const int ln15 = lane & 15;
  const int k8 = ((lane >> 4) & 3) * 8;
#define DCR_CP_KS(BH, KS2)                                                 \
  {                                                                        \
    s8v bl;                                                                \
    if (wlo)                                                               \
      bl = *(const s8v*)(rpl + (((m * 4 + w4) * 4 + pass * 2 + (KS2)) *    \
                                64 + lane) * 8);                           \
    const int kb = (KS2) * 32 + k8;                                        \
    DCR_CP_MT(A0, 0, BH)                                                   \
    DCR_CP_MT(A1, 1, BH)                                                   \
    DCR_CP_MT(A2, 2, BH)                                                   \
    DCR_CP_MT(A3, 3, BH)                                                   \
  }
#define DCR_CP_MT(AX, MT, BH)                                              \
    {                                                                      \
      const int node = (MT) * 16 + ln15;                                   \
      s8v ah, al;                                                          \
      _Pragma("unroll") for (int j = 0; j < 8; ++j) {                      \
        const int a = (kb + j) * RS + node;                                \
        ah[j] = (short)th[a];                                              \
        al[j] = (short)tl[a];                                              \
      }                                                                    \
      AX = MFMA16(ah, BH, AX);                                             \
      AX = MFMA16(al, BH, AX);                                             \
      if (wlo) AX = MFMA16(ah, bl, AX);                                    \
    }
  DCR_CP_KS(bh0, 0)
  DCR_CP_KS(bh1, 1)
#undef DCR_CP_KS
#undef DCR_CP_MT
}

// apply: dst^T = S @ src (as Y^T = src^T @ S^T), optional cheb via
// C-init = -init/2 and 2x writeback. Named accumulators AC0..AC7.
#define DCR_AP_INIT(ACX, MT)                                               \
  {                                                                        \
    if (ih_) {                                                             \
      _Pragma("unroll") for (int r = 0; r < 4; ++r) {                      \
        const int row = (MT) * 16 + rq + r;                                \
        ACX[r] = -0.5f * (dcr_b2f(ih_[row * RS + col]) +                   \
                          dcr_b2f(il_[row * RS + col]));                   \
      }                                                                    \
    } else {                                                               \
      ACX[0] = 0.0f; ACX[1] = 0.0f; ACX[2] = 0.0f; ACX[3] = 0.0f;          \
    }                                                                      \
  }
#define DCR_AP_MFMA(ACX, MT)                                               \
  {                                                                        \
    const int arow = ((MT) * 16 + ln15) * RS;                              \
    s8v ah = dcr_ld8(ah_ + arow + kb);                                     \
    s8v al = dcr_ld8(al_ + arow + kb);                                     \
    ACX = MFMA16(ah, bh, ACX);                                             \
    ACX = MFMA16(al, bh, ACX);                                             \
    if (wlo) ACX = MFMA16(ah, bl, ACX);                                    \
  }
#define DCR_AP_STORE(ACX, MT)                                              \
  {                                                                        \
    _Pragma("unroll") for (int r = 0; r < 4; ++r) {                        \
      const int row = (MT) * 16 + rq + r;                                  \
      const float v = fct * ACX[r];                                        \
      unsigned short hh, hl;                                               \
      dcr_split(v, hh, hl);                                                \
      dh_[row * RS + col] = hh;                                            \
      dl_[row * RS + col] = hl;                                            \
    }                                                                      \
  }

template <int NMT>
__device__ __forceinline__ void dcr_ap(const unsigned short* sh_,
                                       const unsigned short* sl_,
                                       const unsigned short* ah_,
                                       const unsigned short* al_,
                                       unsigned short* dh_, unsigned short* dl_,
                                       const unsigned short* ih_,
                                       const unsigned short* il_,
                                       int idx, int lane, int wlo) {
  const int ln15 = lane & 15;
  const int k8 = ((lane >> 4) & 3) * 8;
  const int col = idx * 16 + ln15;  // out-node
  const int rq = ((lane >> 4) & 3) * 4;
  f4v AC0, AC1, AC2, AC3, AC4, AC5, AC6, AC7;
  DCR_AP_INIT(AC0, 0)
  DCR_AP_INIT(AC1, 1)
  DCR_AP_INIT(AC2, 2)
  DCR_AP_INIT(AC3, 3)
  if constexpr (NMT == 8) {
    DCR_AP_INIT(AC4, 4)
    DCR_AP_INIT(AC5, 5)
    DCR_AP_INIT(AC6, 6)
    DCR_AP_INIT(AC7, 7)
  }
#pragma unroll
  for (int ks = 0; ks < 2; ++ks) {
    const int kb = ks * 32 + k8;
    s8v bh = dcr_ld8(sh_ + col * RS + kb);
    s8v bl;
    if (wlo) bl = dcr_ld8(sl_ + col * RS + kb);
    DCR_AP_MFMA(AC0, 0)
    DCR_AP_MFMA(AC1, 1)
    DCR_AP_MFMA(AC2, 2)
    DCR_AP_MFMA(AC3, 3)
    if constexpr (NMT == 8) {
      DCR_AP_MFMA(AC4, 4)
      DCR_AP_MFMA(AC5, 5)
      DCR_AP_MFMA(AC6, 6)
      DCR_AP_MFMA(AC7, 7)
    }
  }
  const float fct = ih_ ? 2.0f : 1.0f;
  DCR_AP_STORE(AC0, 0)
  DCR_AP_STORE(AC1, 1)
  DCR_AP_STORE(AC2, 2)
  DCR_AP_STORE(AC3, 3)
  if constexpr (NMT == 8) {
    DCR_AP_STORE(AC4, 4)
    DCR_AP_STORE(AC5, 5)
    DCR_AP_STORE(AC6, 6)
    DCR_AP_STORE(AC7, 7)
  }
}

// weight prefetch macros: hi planes only (lo streamed at-use under wlo).
// gate wave slice for (m): base = rpgh + (m*8+wid)*2048 + lane*8, ks*512.
#define GATE_LD(D0, D1, D2, D3, M)                                         \
  if (wid < 8) {                                                           \
    const unsigned short* gb_ = rpgh + ((M) * 8 + wid) * 2048 + lane * 8;  \
    D0 = *(const s8v*)(gb_);                                               \
    D1 = *(const s8v*)(gb_ + 512);                                         \
    D2 = *(const s8v*)(gb_ + 1024);                                        \
    D3 = *(const s8v*)(gb_ + 1536);                                        \
  }
#define CAND_LD(D0, D1, M, PASS)                                           \
  if (wid >= 8 && wid < 12) {                                              \
    const unsigned short* cb_ =                                            \
        rpch + (((M) * 4 + (wid - 8)) * 4 + (PASS) * 2) * 512 + lane * 8;  \
    D0 = *(const s8v*)(cb_);                                               \
    D1 = *(const s8v*)(cb_ + 512);                                         \
  }

// ---------------- one DCGRU layer step (compile-time L, no ptr selects) -----
template <int L>
__device__ __forceinline__ void dcr_layer(
    f4v& hA0, f4v& hA1, f4v& hA2, f4v& hA3,
    f4v& hB0, f4v& hB1, f4v& hB2, f4v& hB3,
    const void* xseq, int b, int t, int isf, int wlo,
    const unsigned short* rp,
    unsigned short* T0h, unsigned short* T0l,
    unsigned short* T1h, unsigned short* T1l,
    unsigned short* T2h, unsigned short* T2l,
    const unsigned short* S0h, const unsigned short* S0l,
    const unsigned short* S1h, const unsigned short* S1l,
    unsigned short* HBh, unsigned short* HBl,
    const float* BG, const float* BC,
    int tid, int lane, int wid) {
  const int ln15 = lane & 15;
  const int rq = ((lane >> 4) & 3) * 4;
  const unsigned short* rpgh = rp + (L * 2 + 0) * GN;
  const unsigned short* rpgl = rp + (L * 2 + 1) * GN;
  const unsigned short* rpch = rp + 4 * GN + (L * 2 + 0) * CN;
  const unsigned short* rpcl = rp + 4 * GN + (L * 2 + 1) * CN;

  f4v A0 = {0.0f, 0.0f, 0.0f, 0.0f};
  f4v A1 = {0.0f, 0.0f, 0.0f, 0.0f};
  f4v A2 = {0.0f, 0.0f, 0.0f, 0.0f};
  f4v A3 = {0.0f, 0.0f, 0.0f, 0.0f};

  // weight double-buffers (hi): gate ga/gb, cand ca/cb
  s8v ga0, ga1, ga2, ga3, gb0, gb1, gb2, gb3;
  s8v ca0, ca1, cb0, cb1;

  // ---------------- P0: build cat^T = [x | h] in T0, h copy in HB ----------
  // (also prologue weight prefetch: gate m0, cand (m0, pass0))
  GATE_LD(ga0, ga1, ga2, ga3, 0)
  CAND_LD(ca0, ca1, 0, 0)
  if constexpr (L == 0) {
    if (wid < 8) {
      const int n = tid >> 3;
      const int f0 = (tid & 7) * 8;
      const int xo = (b * 96 + t) * 4096 + n * 64 + f0;
      if (isf) {
        const float* xp = (const float*)xseq + xo;
#pragma unroll
        for (int j = 0; j < 8; ++j) {
          unsigned short hh, hl;
          dcr_split(xp[j], hh, hl);
          T0h[(f0 + j) * RS + n] = hh;
          T0l[(f0 + j) * RS + n] = hl;
        }
      } else {
        const unsigned short* xp = (const unsigned short*)xseq + xo;
        s8v v = *(const s8v*)xp;
#pragma unroll
        for (int j = 0; j < 8; ++j) {
          T0h[(f0 + j) * RS + n] = (unsigned short)v[j];
          T0l[(f0 + j) * RS + n] = 0;
        }
      }
    } else if (wid < 12) {
      const int f = (wid - 8) * 16 + ln15;
#define DCR_ST0(HX, MT)                                                    \
      { _Pragma("unroll") for (int r = 0; r < 4; ++r) {                    \
          const int node = (MT) * 16 + rq + r;                             \
          unsigned short hh, hl;                                           \
          dcr_split(HX[r], hh, hl);                                        \
          T0h[(64 + f) * RS + node] = hh;                                  \
          T0l[(64 + f) * RS + node] = hl;                                  \
          HBh[f * RS + node] = hh;                                         \
          HBl[f * RS + node] = hl; } }
      DCR_ST0(hA0, 0)
      DCR_ST0(hA1, 1)
      DCR_ST0(hA2, 2)
      DCR_ST0(hA3, 3)
#undef DCR_ST0
    }
  } else {
    if (wid >= 8 && wid < 12) {
      const int f = (wid - 8) * 16 + ln15;
#define DCR_ST1(HAX, HBX, MT)                                              \
      { _Pragma("unroll") for (int r = 0; r < 4; ++r) {                    \
          const int node = (MT) * 16 + rq + r;                             \
          unsigned short hh, hl;                                           \
          dcr_split(HAX[r], hh, hl);                                       \
          T0h[f * RS + node] = hh;                                         \
          T0l[f * RS + node] = hl;                                         \
          dcr_split(HBX[r], hh, hl);                                       \
          T0h[(64 + f) * RS + node] = hh;                                  \
          T0l[(64 + f) * RS + node] = hl;                                  \
          HBh[f * RS + node] = hh;                                         \
          HBl[f * RS + node] = hl; } }
      DCR_ST1(hA0, hB0, 0)
      DCR_ST1(hA1, hB1, 1)
      DCR_ST1(hA2, hB2, 2)
      DCR_ST1(hA3, hB3, 3)
#undef DCR_ST1
    }
  }
  __syncthreads();

  // ---------------- gate pass: pm0..pm4 (prefetch next phase's weights) ----
  // pm0: uses ga/ca(m0); loads gb<-m1, cb<-(m1,p0)
  GATE_LD(gb0, gb1, gb2, gb3, 1)
  CAND_LD(cb0, cb1, 1, 0)
  if (wid < 8) dcr_gp(A0, A1, A2, A3, T0h, T0l, ga0, ga1, ga2, ga3, rpgl, 0, wid, lane, wlo);
  else if (wid < 12) dcr_cp(A0, A1, A2, A3, T0h, T0l, ca0, ca1, rpcl, 0, wid - 8, lane, wlo, 0);
  else dcr_ap<8>(S0h, S0l, T0h, T0l, T1h, T1l, nullptr, nullptr, wid - 12, lane, wlo);
  __syncthreads();
  // pm1: uses gb/cb(m1); loads ga<-m2, ca<-(m2,p0)
  GATE_LD(ga0, ga1, ga2, ga3, 2)
  CAND_LD(ca0, ca1, 2, 0)
  if (wid < 8) dcr_gp(A0, A1, A2, A3, T1h, T1l, gb0, gb1, gb2, gb3, rpgl, 1, wid, lane, wlo);
  else if (wid < 12) dcr_cp(A0, A1, A2, A3, T1h, T1l, cb0, cb1, rpcl, 1, wid - 8, lane, wlo, 0);
  else dcr_ap<8>(S0h, S0l, T1h, T1l, T2h, T2l, T0h, T0l, wid - 12, lane, wlo);
  __syncthreads();
  // pm2: uses ga/ca(m2); loads gb<-m3, cb<-(m3,p0)
  GATE_LD(gb0, gb1, gb2, gb3, 3)
  CAND_LD(cb0, cb1, 3, 0)
  if (wid < 8) dcr_gp(A0, A1, A2, A3, T2h, T2l, ga0, ga1, ga2, ga3, rpgl, 2, wid, lane, wlo);
  else if (wid < 12) dcr_cp(A0, A1, A2, A3, T2h, T2l, ca0, ca1, rpcl, 2, wid - 8, lane, wlo, 0);
  else dcr_ap<8>(S1h, S1l, T1h, T1l, T0h, T0l, nullptr, nullptr, wid - 12, lane, wlo);
  __syncthreads();
  // pm3: uses gb/cb(m3); loads ga<-m4, ca<-(m4,p0)
  GATE_LD(ga0, ga1, ga2, ga3, 4)
  CAND_LD(ca0, ca1, 4, 0)
  if (wid < 8) dcr_gp(A0, A1, A2, A3, T0h, T0l, gb0, gb1, gb2, gb3, rpgl, 3, wid, lane, wlo);
  else if (wid < 12) dcr_cp(A0, A1, A2, A3, T0h, T0l, cb0, cb1, rpcl, 3, wid - 8, lane, wlo, 0);
  else dcr_ap<8>(S1h, S1l, T0h, T0l, T2h, T2l, T1h, T1l, wid - 12, lane, wlo);
  __syncthreads();
  // pm4: uses ga/ca(m4); loads cb<-(m0,p1) for the rh pass
  CAND_LD(cb0, cb1, 0, 1)
  if (wid < 8) dcr_gp(A0, A1, A2, A3, T2h, T2l, ga0, ga1, ga2, ga3, rpgl, 4, wid, lane, wlo);
  else if (wid < 12) dcr_cp(A0, A1, A2, A3, T2h, T2l, ca0, ca1, rpcl, 4, wid - 8, lane, wlo, 0);
  __syncthreads();

  // ---------------- gate finish: r -> rh (T0 low), u -> T1 upper -----------
  if (wid < 8) {
    const int g = wid * 16 + ln15;
    const float bgv = BG[L * 128 + g];
#define DCR_GFIN(AX, MT)                                                   \
    { _Pragma("unroll") for (int r = 0; r < 4; ++r) {                      \
        const int node = (MT) * 16 + rq + r;                               \
        const float s = dcr_sigm(AX[r] + bgv);                             \
        unsigned short hh, hl;                                             \
        if (wid < 4) {                                                     \
          const float h = dcr_b2f(HBh[g * RS + node]) +                    \
                          dcr_b2f(HBl[g * RS + node]);                     \
          dcr_split(s * h, hh, hl);                                        \
          T0h[g * RS + node] = hh;                                         \
          T0l[g * RS + node] = hl;                                         \
        } else {                                                           \
          dcr_split(s, hh, hl);                                            \
          T1h[g * RS + node] = hh;                                         \
          T1l[g * RS + node] = hl;                                         \
        } } }
    DCR_GFIN(A0, 0)
    DCR_GFIN(A1, 1)
    DCR_GFIN(A2, 2)
    DCR_GFIN(A3, 3)
#undef DCR_GFIN
  }
  __syncthreads();

  // ---------------- rh pass: pr0..pr4 (64-wide, low halves) ----------------
  // pr0: uses cb(m0,p1); loads ca<-(m1,p1)
  CAND_LD(ca0, ca1, 1, 1)
  if (wid >= 8 && wid < 12) dcr_cp(A0, A1, A2, A3, T0h, T0l, cb0, cb1, rpcl, 0, wid - 8, lane, wlo, 1);
  else if (wid >= 12) dcr_ap<4>(S0h, S0l, T0h, T0l, T1h, T1l, nullptr, nullptr, wid - 12, lane, wlo);
  __syncthreads();
  // pr1: uses ca(m1,p1); loads cb<-(m2,p1)
  CAND_LD(cb0, cb1, 2, 1)
  if (wid >= 8 && wid < 12) dcr_cp(A0, A1, A2, A3, T1h, T1l, ca0, ca1, rpcl, 1, wid - 8, lane, wlo, 1);
  else if (wid >= 12) dcr_ap<4>(S0h, S0l, T1h, T1l, T2h, T2l, T0h, T0l, wid - 12, lane, wlo);
  __syncthreads();
  // pr2: uses cb(m2,p1); loads ca<-(m3,p1)
  CAND_LD(ca0, ca1, 3, 1)
  if (wid >= 8 && wid < 12) dcr_cp(A0, A1, A2, A3, T2h, T2l, cb0, cb1, rpcl, 2, wid - 8, lane, wlo, 1);
  else if (wid >= 12) dcr_ap<4>(S1h, S1l, T1h, T1l, T0h, T0l, nullptr, nullptr, wid - 12, lane, wlo);
  __syncthreads();
  // pr3: uses ca(m3,p1); loads cb<-(m4,p1)
  CAND_LD(cb0, cb1, 4, 1)
  if (wid >= 8 && wid < 12) dcr_cp(A0, A1, A2, A3, T0h, T0l, ca0, ca1, rpcl, 3, wid - 8, lane, wlo, 1);
  else if (wid >= 12) dcr_ap<4>(S1h, S1l, T0h, T0l, T1h, T1l, T1h, T1l, wid - 12, lane, wlo);
  __syncthreads();
  // pr4: uses cb(m4,p1)
  if (wid >= 8 && wid < 12) dcr_cp(A0, A1, A2, A3, T1h, T1l, cb0, cb1, rpcl, 4, wid - 8, lane, wlo, 1);
  __syncthreads();

  // ---------------- cand finish: h_new = u*h + (1-u)*tanh(C+bc) ------------
  if (wid >= 8 && wid < 12) {
    const int f = (wid - 8) * 16 + ln15;
    const float bcv = BC[L * 64 + f];
#define DCR_CFIN(AX, HX, MT)                                               \
    { _Pragma("unroll") for (int r = 0; r < 4; ++r) {                      \
        const int node = (MT) * 16 + rq + r;                               \
        const float c = dcr_tanh(AX[r] + bcv);                             \
        const float u = dcr_b2f(T1h[(64 + f) * RS + node]) +               \
                        dcr_b2f(T1l[(64 + f) * RS + node]);                \
        HX[r] = u * HX[r] + (1.0f - u) * c; } }
    if constexpr (L == 0) {
      DCR_CFIN(A0, hA0, 0)
      DCR_CFIN(A1, hA1, 1)
      DCR_CFIN(A2, hA2, 2)
      DCR_CFIN(A3, hA3, 3)
    } else {
      DCR_CFIN(A0, hB0, 0)
      DCR_CFIN(A1, hB1, 1)
      DCR_CFIN(A2, hB2, 2)
      DCR_CFIN(A3, hB3, 3)
    }
#undef DCR_CFIN
  }
  __syncthreads();
}

// ---------------- main MFMA kernel ------------------------------------------
__global__ __launch_bounds__(1024)
__attribute__((amdgpu_waves_per_eu(4, 4)))
void dcr_mfma(
    const void* xseq, const void* s0, const void* s1,
    const void* bg0, const void* bg1,
    const void* p64a, const void* p64b, const void* p64c,
    const void* fcw, const void* fcb, const void* idw, const void* idb,
    const unsigned short* rp, void* outp) {
  extern __shared__ char sm[];
  unsigned short* const T0h = (unsigned short*)(sm);
  unsigned short* const T0l = (unsigned short*)(sm + TPB);
  unsigned short* const T1h = (unsigned short*)(sm + 2 * TPB);
  unsigned short* const T1l = (unsigned short*)(sm + 3 * TPB);
  unsigned short* const T2h = (unsigned short*)(sm + 4 * TPB);
  unsigned short* const T2l = (unsigned short*)(sm + 5 * TPB);
  unsigned short* const S0h = (unsigned short*)(sm + OFF_S);
  unsigned short* const S0l = (unsigned short*)(sm + OFF_S + SPB);
  unsigned short* const S1h = (unsigned short*)(sm + OFF_S + 2 * SPB);
  unsigned short* const S1l = (unsigned short*)(sm + OFF_S + 3 * SPB);
  unsigned short* const HBh = (unsigned short*)(sm + OFF_HB);
  unsigned short* const HBl = (unsigned short*)(sm + OFF_HB + SPB);
  float* const BG = (float*)(sm + OFF_BG);
  float* const BC = (float*)(sm + OFF_BC);
  int* const ctl = (int*)(sm + OFF_CTL);

  const int tid = threadIdx.x;
  const int b = blockIdx.x;
  const int lane = tid & 63;
  const int wid = tid >> 6;

  // ---- on-device identification ----
  if (tid == 0) {
    const unsigned short* ss = (const unsigned short*)s0;
    int hits = 0;
    for (int i = 0; i < 32; ++i) {
      unsigned hb = ((unsigned)ss[2 * i] >> 8) & 0xFFu;
      if (hb >= 0x30u && hb <= 0x3Fu) ++hits;
    }
    int isf_ = (hits < 16) ? 1 : 0;
    int sel = 0;
    {
      const unsigned* w = (const unsigned*)p64a;
      unsigned any = 0;
      for (int i = 0; i < 16; ++i) any |= w[i];
      if (!any) {
        sel = 1;
        const unsigned* w1 = (const unsigned*)p64b;
        unsigned any1 = 0;
        for (int i = 0; i < 16; ++i) any1 |= w1[i];
        if (!any1) sel = 2;
      }
    }
    const unsigned* w =
        (const unsigned*)(sel == 0 ? p64a : (sel == 1 ? p64b : p64c));
    int i64 = 1;
    for (int i = 0; i < 8; ++i)
      if (w[2 * i + 1] != 0u) i64 = 0;
    ctl[0] = isf_;
    ctl[1] = sel;
    ctl[2] = i64;
  }
  __syncthreads();
  const int isf = ctl[0];
  const int sel = ctl[1];
  const int i64 = ctl[2];
  const int wlo = isf;  // B-side lo planes exist only for fp32 inputs
  const void* seqp = (sel == 0) ? p64a : (sel == 1 ? p64b : p64c);
  const void* bcA = (sel == 0) ? p64b : p64a;
  const void* bcB = (sel == 2) ? p64b : p64c;

  // ---- stage supports (hi/lo) and biases ----
  for (int i = 0; i < 4; ++i) {
    const int flat = i * 1024 + tid;
    const int out = flat >> 6, in = flat & 63;
    float v0, v1;
    if (isf) {
      v0 = ((const float*)s0)[flat];
      v1 = ((const float*)s1)[flat];
    } else {
      v0 = dcr_b2f(((const unsigned short*)s0)[flat]);
      v1 = dcr_b2f(((const unsigned short*)s1)[flat]);
    }
    unsigned short hh, hl;
    dcr_split(v0, hh, hl);
    S0h[out * RS + in] = hh;
    S0l[out * RS + in] = hl;
    dcr_split(v1, hh, hl);
    S1h[out * RS + in] = hh;
    S1l[out * RS + in] = hl;
  }
  if (tid < 128) {
    BG[tid] = dcr_ld(bg0, tid, isf);
    BG[128 + tid] = dcr_ld(bg1, tid, isf);
  } else if (tid < 192) {
    const int j = tid - 128;
    BC[j] = dcr_ld(bcA, j, isf);
    BC[64 + j] = dcr_ld(bcB, j, isf);
  }

  int tl_;
  if (i64) tl_ = (int)((const long long*)seqp)[b] - 1;
  else     tl_ = ((const int*)seqp)[b] - 1;
  if (tl_ < 0) tl_ = 0;
  if (tl_ > 95) tl_ = 95;

  f4v hA0 = {0.0f, 0.0f, 0.0f, 0.0f};
  f4v hA1 = {0.0f, 0.0f, 0.0f, 0.0f};
  f4v hA2 = {0.0f, 0.0f, 0.0f, 0.0f};
  f4v hA3 = {0.0f, 0.0f, 0.0f, 0.0f};
  f4v hB0 = {0.0f, 0.0f, 0.0f, 0.0f};
  f4v hB1 = {0.0f, 0.0f, 0.0f, 0.0f};
  f4v hB2 = {0.0f, 0.0f, 0.0f, 0.0f};
  f4v hB3 = {0.0f, 0.0f, 0.0f, 0.0f};
  __syncthreads();

  for (int t = 0; t < 96; ++t) {
    dcr_layer<0>(hA0, hA1, hA2, hA3, hB0, hB1, hB2, hB3,
                 xseq, b, t, isf, wlo, rp,
                 T0h, T0l, T1h, T1l, T2h, T2l,
                 S0h, S0l, S1h, S1l, HBh, HBl, BG, BC, tid, lane, wid);
    dcr_layer<1>(hA0, hA1, hA2, hA3, hB0, hB1, hB2, hB3,
                 xseq, b, t, isf, wlo, rp,
                 T0h, T0l, T1h, T1l, T2h, T2l,
                 S0h, S0l, S1h, S1l, HBh, HBl, BG, BC, tid, lane, wid);
    if (t == tl_) break;
  }

  // ---------------- heads: relu(h1) -> fc/id matmul -> max over nodes -------
  __syncthreads();
  const int ln15 = lane & 15;
  const int rq = ((lane >> 4) & 3) * 4;
  float* const hx = (float*)sm;              // [64][66]
  float* const hw = (float*)(sm + 2 * TPB);  // [64][56]
  float* const red = (float*)(sm + 4 * TPB); // [16][54]
  if (wid >= 8 && wid < 12) {
    const int f = (wid - 8) * 16 + ln15;
#define DCR_HX(HX, MT)                                                     \
    { _Pragma("unroll") for (int r = 0; r < 4; ++r) {                      \
        const int node = (MT) * 16 + rq + r;                               \
        hx[node * 66 + f] = fmaxf(HX[r], 0.0f); } }
    DCR_HX(hB0, 0)
    DCR_HX(hB1, 1)
    DCR_HX(hB2, 2)
    DCR_HX(hB3, 3)
#undef DCR_HX
  }
  {
    const int u = tid >> 4;
    for (int c = (tid & 15); c < 54; c += 16)
      hw[u * 56 + c] = (c < 4) ? dcr_ld(fcw, u * 4 + c, isf)
                               : dcr_ld(idw, u * 50 + (c - 4), isf);
  }
  __syncthreads();
  if (tid < 864) {
    const int c = tid % 54, nb = tid / 54;
    float mx = -3.4e38f;
    for (int nn = nb * 4; nn < nb * 4 + 4; ++nn) {
      float s = 0.0f;
#pragma unroll 8
      for (int uu = 0; uu < 64; ++uu) s += hx[nn * 66 + uu] * hw[uu * 56 + c];
      mx = fmaxf(mx, s);
    }
    red[nb * 54 + c] = mx;
  }
  __syncthreads();
  if (tid < 54) {
    float mx = red[tid];
#pragma unroll
    for (int g = 1; g < 16; ++g) mx = fmaxf(mx, red[g * 54 + tid]);
    mx += (tid < 4) ? dcr_ld(fcb, tid, isf) : dcr_ld(idb, tid - 4, isf);
    const int o = (tid < 4) ? (b * 4 + tid) : (256 + b * 50 + (tid - 4));
    if (isf) ((float*)outp)[o] = mx;
    else     ((unsigned short*)outp)[o] = dcr_f2b(mx);
  }
}

// ============================================================================
// Fallback: proven scalar kernel (round-1, 1024 threads) for ws-too-small.
// ============================================================================
__device__ void dcr_proj(float* aG, float* aC, const float (*buf)[68],
                         const void* Wg, const void* Wc, int m, int fh,
                         int n, int fb, int doG, int doC, int isf) {
  if (!isf) {
    const unsigned* G = (const unsigned*)Wg;
    const unsigned* C = (const unsigned*)Wc;
    const int fd = fb >> 1;
#pragma unroll 4
    for (int k = 0; k < 64; ++k) {
      float xk = buf[n][k];
      int row = (fh + k) * 5 + m;
      if (doG) {
        const unsigned* wr = G + row * 64 + fd;
        unsigned p0 = wr[0], p1 = wr[1], p2 = wr[32], p3 = wr[33];
        aG[0] += xk * __uint_as_float(p0 << 16);
        aG[1] += xk * __uint_as_float(p0 & 0xFFFF0000u);
        aG[2] += xk * __uint_as_float(p1 << 16);
        aG[3] += xk * __uint_as_float(p1 & 0xFFFF0000u);
        aG[4] += xk * __uint_as_float(p2 << 16);
        aG[5] += xk * __uint_as_float(p2 & 0xFFFF0000u);
        aG[6] += xk * __uint_as_float(p3 << 16);
        aG[7] += xk * __uint_as_float(p3 & 0xFFFF0000u);
      }
      if (doC) {
        const unsigned* wr = C + row * 32 + fd;
        unsigned p0 = wr[0], p1 = wr[1];
        aC[0] += xk * __uint_as_float(p0 << 16);
        aC[1] += xk * __uint_as_float(p0 & 0xFFFF0000u);
        aC[2] += xk * __uint_as_float(p1 << 16);
        aC[3] += xk * __uint_as_float(p1 & 0xFFFF0000u);
      }
    }
  } else {
    const float* G = (const float*)Wg;
    const float* C = (const float*)Wc;
#pragma unroll 4
    for (int k = 0; k < 64; ++k) {
      float xk = buf[n][k];
      int row = (fh + k) * 5 + m;
      if (doG) {
        const float* wr = G + row * 128 + fb;
#pragma unroll
        for (int j = 0; j < 4; ++j) {
          aG[j] += xk * wr[j];
          aG[4 + j] += xk * wr[64 + j];
        }
      }
      if (doC) {
        const float* wr = C + row * 64 + fb;
#pragma unroll
        for (int j = 0; j < 4; ++j) aC[j] += xk * wr[j];
      }
    }
  }
}

__device__ void dcr_apply(float (*dst)[68], const float (*src)[68],
                          const unsigned short (*sS)[65], int n, int fb,
                          int cheb) {
  float a0 = 0.0f, a1 = 0.0f, a2 = 0.0f, a3 = 0.0f;
#pragma unroll 8
  for (int m = 0; m < 64; ++m) {
    float s = dcr_b2f(sS[n][m]);
    float4 v = *(const float4*)(&src[m][fb]);
    a0 += s * v.x;
    a1 += s * v.y;
    a2 += s * v.z;
    a3 += s * v.w;
  }
  if (cheb) {
    dst[n][fb + 0] = 2.0f * a0 - dst[n][fb + 0];
    dst[n][fb + 1] = 2.0f * a1 - dst[n][fb + 1];
    dst[n][fb + 2] = 2.0f * a2 - dst[n][fb + 2];
    dst[n][fb + 3] = 2.0f * a3 - dst[n][fb + 3];
  } else {
    dst[n][fb + 0] = a0;
    dst[n][fb + 1] = a1;
    dst[n][fb + 2] = a2;
    dst[n][fb + 3] = a3;
  }
}

__device__ void dcr_half(float* aG, float* aC, const void* Wg, const void* Wc,
                         int fh, int doG, int doC, float (*xa)[68],
                         float (*xb)[68], const unsigned short (*sS0)[65],
                         const unsigned short (*sS1)[65], int n, int fb,
                         int isf) {
  dcr_proj(aG, aC, xa, Wg, Wc, 0, fh, n, fb, doG, doC, isf);
  dcr_apply(xb, xa, sS0, n, fb, 0);
  __syncthreads();
  dcr_proj(aG, aC, xb, Wg, Wc, 1, fh, n, fb, doG, doC, isf);
  dcr_apply(xa, xb, sS0, n, fb, 1);
  __syncthreads();
  dcr_proj(aG, aC, xa, Wg, Wc, 2, fh, n, fb, doG, doC, isf);
  __syncthreads();
  dcr_apply(xa, xb, sS1, n, fb, 0);
  __syncthreads();
  dcr_proj(aG, aC, xa, Wg, Wc, 3, fh, n, fb, doG, doC, isf);
  dcr_apply(xb, xa, sS1, n, fb, 1);
  __syncthreads();
  dcr_proj(aG, aC, xb, Wg, Wc, 4, fh, n, fb, doG, doC, isf);
  __syncthreads();
}

__global__ __launch_bounds__(1024) void dcr_scalar(
    const void* xseq, const void* s0, const void* s1, const void* wg0,
    const void* wc0, const void* wg1, const void* wc1, const void* bg0,
    const void* bg1, const void* p64a, const void* p64b, const void* p64c,
    const void* fcw, const void* fcb, const void* idw, const void* idb,
    void* outp) {
  __shared__ float xa[64][68];
  __shared__ float xb[64][68];
  __shared__ unsigned short sS[2][64][65];
  __shared__ float bGs[2][128];
  __shared__ float bCs[2][64];
  __shared__ float red[16][54];
  __shared__ int ctl[4];

  const int tid = threadIdx.x;
  const int b = blockIdx.x;
  const int n = tid >> 4;
  const int fb = (tid & 15) * 4;

  if (tid == 0) {
    const unsigned short* ss = (const unsigned short*)s0;
    int hits = 0;
    for (int i = 0; i < 32; ++i) {
      unsigned hb = ((unsigned)ss[2 * i] >> 8) & 0xFFu;
      if (hb >= 0x30u && hb <= 0x3Fu) ++hits;
    }
    int isf = (hits < 16) ? 1 : 0;
    int sel = 0;
    {
      const unsigned* w = (const unsigned*)p64a;
      unsigned any = 0;
      for (int i = 0; i < 16; ++i) any |= w[i];
      if (!any) {
        sel = 1;
        const unsigned* w1 = (const unsigned*)p64b;
        unsigned any1 = 0;
        for (int i = 0; i < 16; ++i) any1 |= w1[i];
        if (!any1) sel = 2;
      }
    }
    const unsigned* w =
        (const unsigned*)(sel == 0 ? p64a : (sel == 1 ? p64b : p64c));
    int i64 = 1;
    for (int i = 0; i < 8; ++i)
      if (w[2 * i + 1] != 0u) i64 = 0;
    ctl[0] = isf;
    ctl[1] = sel;
    ctl[2] = i64;
  }
  __syncthreads();
  const int isf = ctl[0];
  const int sel = ctl[1];
  const int i64 = ctl[2];
  const void* seqp = (sel == 0) ? p64a : (sel == 1 ? p64b : p64c);
  const void* bcA = (sel == 0) ? p64b : p64a;
  const void* bcB = (sel == 2) ? p64b : p64c;

  for (int i = 0; i < 4; ++i) {
    int flat = i * 1024 + tid;
    int nn = flat >> 6, mm = flat & 63;
    unsigned short v0, v1;
    if (isf) {
      v0 = dcr_f2b(((const float*)s0)[flat]);
      v1 = dcr_f2b(((const float*)s1)[flat]);
    } else {
      v0 = ((const unsigned short*)s0)[flat];
      v1 = ((const unsigned short*)s1)[flat];
    }
    sS[0][nn][mm] = v0;
    sS[1][nn][mm] = v1;
  }
  if (tid < 128) {
    bGs[0][tid] = dcr_ld(bg0, tid, isf);
    bGs[1][tid] = dcr_ld(bg1, tid, isf);
  } else if (tid < 192) {
    int j = tid - 128;
    bCs[0][j] = dcr_ld(bcA, j, isf);
    bCs[1][j] = dcr_ld(bcB, j, isf);
  }

  int tl;
  if (i64) tl = (int)((const long long*)seqp)[b] - 1;
  else     tl = ((const int*)seqp)[b] - 1;
  if (tl < 0) tl = 0;
  if (tl > 95) tl = 95;

  float h0r[4], h1r[4];
#pragma unroll
  for (int j = 0; j < 4; ++j) {
    h0r[j] = 0.0f;
    h1r[j] = 0.0f;
  }
  __syncthreads();

  for (int t = 0; t < 96; ++t) {
    {
      float aG[8], aC[4];
#pragma unroll
      for (int j = 0; j < 8; ++j) aG[j] = 0.0f;
#pragma unroll
      for (int j = 0; j < 4; ++j) aC[j] = 0.0f;
      int xoff = (b * 96 + t) * 4096 + n * 64 + fb;
#pragma unroll
      for (int j = 0; j < 4; ++j) xa[n][fb + j] = dcr_ld(xseq, xoff + j, isf);
      __syncthreads();
      dcr_half(aG, aC, wg0, wc0, 0, 1, 1, xa, xb, sS[0], sS[1], n, fb, isf);
#pragma unroll
      for (int j = 0; j < 4; ++j) xa[n][fb + j] = h0r[j];
      __syncthreads();
      dcr_half(aG, aC, wg0, wc0, 64, 1, 0, xa, xb, sS[0], sS[1], n, fb, isf);
      float rr[4], uu[4];
#pragma unroll
      for (int j = 0; j < 4; ++j) {
        rr[j] = dcr_sigm(aG[j] + bGs[0][fb + j]);
        uu[j] = dcr_sigm(aG[4 + j] + bGs[0][64 + fb + j]);
      }
#pragma unroll
      for (int j = 0; j < 4; ++j) xa[n][fb + j] = rr[j] * h0r[j];
      __syncthreads();
      dcr_half(aG, aC, wg0, wc0, 64, 0, 1, xa, xb, sS[0], sS[1], n, fb, isf);
#pragma unroll
      for (int j = 0; j < 4; ++j) {
        float c = dcr_tanh(aC[j] + bCs[0][fb + j]);
        h0r[j] = uu[j] * h0r[j] + (1.0f - uu[j]) * c;
      }
    }
    {
      float aG[8], aC[4];
#pragma unroll
      for (int j = 0; j < 8; ++j) aG[j] = 0.0f;
#pragma unroll
      for (int j = 0; j < 4; ++j) aC[j] = 0.0f;
#pragma unroll
      for (int j = 0; j < 4; ++j) xa[n][fb + j] = h0r[j];
      __syncthreads();
      dcr_half(aG, aC, wg1, wc1, 0, 1, 1, xa, xb, sS[0], sS[1], n, fb, isf);
#pragma unroll
      for (int j = 0; j < 4; ++j) xa[n][fb + j] = h1r[j];
      __syncthreads();
      dcr_half(aG, aC, wg1, wc1, 64, 1, 0, xa, xb, sS[0], sS[1], n, fb, isf);
      float rr[4], uu[4];
#pragma unroll
      for (int j = 0; j < 4; ++j) {
        rr[j] = dcr_sigm(aG[j] + bGs[1][fb + j]);
        uu[j] = dcr_sigm(aG[4 + j] + bGs[1][64 + fb + j]);
      }
#pragma unroll
      for (int j = 0; j < 4; ++j) xa[n][fb + j] = rr[j] * h1r[j];
      __syncthreads();
      dcr_half(aG, aC, wg1, wc1, 64, 0, 1, xa, xb, sS[0], sS[1], n, fb, isf);
#pragma unroll
      for (int j = 0; j < 4; ++j) {
        float c = dcr_tanh(aC[j] + bCs[1][fb + j]);
        h1r[j] = uu[j] * h1r[j] + (1.0f - uu[j]) * c;
      }
    }
    if (t == tl) break;
  }

  __syncthreads();
#pragma unroll
  for (int j = 0; j < 4; ++j) xa[n][fb + j] = fmaxf(h1r[j], 0.0f);
  {
    int u = tid >> 4;
    for (int c = (tid & 15); c < 54; c += 16)
      xb[u][c] = (c < 4) ? dcr_ld(fcw, u * 4 + c, isf)
                         : dcr_ld(idw, u * 50 + (c - 4), isf);
  }
  __syncthreads();
  if (tid < 864) {
    int c = tid % 54, nb = tid / 54;
    float mx = -3.4e38f;
    for (int nn = nb * 4; nn < nb * 4 + 4; ++nn) {
      float s = 0.0f;
#pragma unroll 8
      for (int u = 0; u < 64; ++u) s += xa[nn][u] * xb[u][c];
      mx = fmaxf(mx, s);
    }
    red[nb][c] = mx;
  }
  __syncthreads();
  if (tid < 54) {
    float mx = red[0][tid];
#pragma unroll
    for (int g = 1; g < 16; ++g) mx = fmaxf(mx, red[g][tid]);
    mx += (tid < 4) ? dcr_ld(fcb, tid, isf) : dcr_ld(idb, tid - 4, isf);
    int o = (tid < 4) ? (b * 4 + tid) : (256 + b * 50 + (tid - 4));
    if (isf) ((float*)outp)[o] = mx;
    else     ((unsigned short*)outp)[o] = dcr_f2b(mx);
  }
}

// ---------------------------------------------------------------------------
static int dcr_find_nth(const int* s, int n, int sz, int nth) {
  int c = 0;
  for (int i = 0; i < n; ++i)
    if (s[i] == sz) {
      if (c == nth) return i;
      ++c;
    }
  return -1;
}

extern "C" void kernel_launch(void* const* d_in, const int* in_sizes, int n_in,
                              void* d_out, int out_size, void* d_ws,
                              size_t ws_size, hipStream_t stream) {
  (void)out_size;
  int i_seq = dcr_find_nth(in_sizes, n_in, 393216, 0);
  int i_s0 = dcr_find_nth(in_sizes, n_in, 4096, 0);
  int i_s1 = dcr_find_nth(in_sizes, n_in, 4096, 1);
  int i_wg0 = dcr_find_nth(in_sizes, n_in, 81920, 0);
  int i_wg1 = dcr_find_nth(in_sizes, n_in, 81920, 1);
  int i_wc0 = dcr_find_nth(in_sizes, n_in, 40960, 0);
  int i_wc1 = dcr_find_nth(in_sizes, n_in, 40960, 1);
  int i_bg0 = dcr_find_nth(in_sizes, n_in, 128, 0);
  int i_bg1 = dcr_find_nth(in_sizes, n_in, 128, 1);
  int i_64a = dcr_find_nth(in_sizes, n_in, 64, 0);
  int i_64b = dcr_find_nth(in_sizes, n_in, 64, 1);
  int i_64c = dcr_find_nth(in_sizes, n_in, 64, 2);
  int i_fcw = dcr_find_nth(in_sizes, n_in, 256, 0);
  int i_fcb = dcr_find_nth(in_sizes, n_in, 4, 0);
  int i_idw = dcr_find_nth(in_sizes, n_in, 3200, 0);
  int i_idb = dcr_find_nth(in_sizes, n_in, 50, 0);
  if (i_seq < 0 || i_s0 < 0 || i_s1 < 0 || i_wg0 < 0 || i_wg1 < 0 ||
      i_wc0 < 0 || i_wc1 < 0 || i_bg0 < 0 || i_bg1 < 0 || i_64a < 0 ||
      i_64b < 0 || i_64c < 0 || i_fcw < 0 || i_fcb < 0 || i_idw < 0 ||
      i_idb < 0) {
    i_seq = 0;  i_64a = 1;  i_s0 = 2;   i_s1 = 3;
    i_wg0 = 4;  i_bg0 = 5;  i_wc0 = 6;  i_64b = 7;
    i_wg1 = 8;  i_bg1 = 9;  i_wc1 = 10; i_64c = 11;
    i_fcw = 12; i_fcb = 13; i_idw = 14; i_idb = 15;
  }

  if (d_ws == nullptr || ws_size < (size_t)WS_NEED) {
    dcr_scalar<<<dim3(64), dim3(1024), 0, stream>>>(
        d_in[i_seq], d_in[i_s0], d_in[i_s1], d_in[i_wg0], d_in[i_wc0],
        d_in[i_wg1], d_in[i_wc1], d_in[i_bg0], d_in[i_bg1], d_in[i_64a],
        d_in[i_64b], d_in[i_64c], d_in[i_fcw], d_in[i_fcb], d_in[i_idw],
        d_in[i_idb], d_out);
    return;
  }

  dcr_repack<<<dim3(256), dim3(256), 0, stream>>>(
      d_in[i_wg0], d_in[i_wc0], d_in[i_wg1], d_in[i_wc1], d_in[i_s0],
      (unsigned short*)d_ws);

  static bool attr_set = false;
  if (!attr_set) {
    (void)hipFuncSetAttribute((const void*)dcr_mfma,
                              hipFuncAttributeMaxDynamicSharedMemorySize,
                              SMEM_SZ);
    attr_set = true;
  }

  dcr_mfma<<<dim3(64), dim3(1024), SMEM_SZ, stream>>>(
      d_in[i_seq], d_in[i_s0], d_in[i_s1], d_in[i_bg0], d_in[i_bg1],
      d_in[i_64a], d_in[i_64b], d_in[i_64c], d_in[i_fcw], d_in[i_fcb],
      d_in[i_idw], d_in[i_idb], (const unsigned short*)d_ws, d_out);
}

// Round 6
// 15493.120 us; speedup vs baseline: 2.1355x; 2.1355x over previous
//
#include <hip/hip_runtime.h>

// ---------------------------------------------------------------------------
// DCRNN (2-layer DCGRU encoder) -- MFMA round, LDS-layout flip.
// R5 post-mortem: (1) inputs are fp32 (isf=1) so wlo-guards saved nothing;
// (2) cross-barrier reg prefetch is defeated by the compiler's vmcnt(0)
// drain at __syncthreads and its VGPR pressure cost 26->33ms. Reverted.
// R4's real bottleneck: ~3100 scalar ds_read_u16 A-fragment gathers per CU
// per phase through the single LDS port (~18K cyc = the 12us phase time).
// This round: terms stored NODE-major [node][feat] (L_nf) with XOR swizzle
// feat ^= ((node>>3)&7)<<4:
//   * proj A-fragments: 8-feat runs are contiguous -> ds_read_b128
//     (256 u16 -> 32 b128 per proj wave per phase, 12 waves)
//   * apply reoriented: A = S [out][in] (b128), B = term (u16 gathers, but
//     only 4 waves; swizzle makes the 4 lane-groups bank-disjoint),
//     D-writes/init coalesced
//   * x-staging becomes two 16B LDS stores per thread
// Same phases/roles/hi-lo math/weight path as R4 (verified absmax 2.4e-4).
// ---------------------------------------------------------------------------

#define RSF 136            // term row stride (u16): 272B = 16B-aligned, bank step 4
#define RSS 64             // S plane row stride (u16)
#define RSH 68             // HB row stride (u16)
#define TPB 17408          // one term plane: 64*136*2 bytes
#define OFF_S   104448     // 6 term planes
#define OFF_HB  137216     // OFF_S + 4*8192
#define OFF_BG  154624     // OFF_HB + 2*8704
#define OFF_BC  155648
#define OFF_CTL 156160
#define SMEM_SZ 156176
#define GN 81920           // gate repack elems per (layer,plane)
#define CN 40960           // cand repack elems per (layer,plane)
#define WS_NEED ((4*GN + 4*CN) * 2)

// swizzled term address: element (node, feat)
#define TADDR(node, feat) ((node) * RSF + ((feat) ^ ((((node) >> 3) & 7) << 4)))

typedef __attribute__((ext_vector_type(4))) short s4v;
typedef __attribute__((ext_vector_type(8))) short s8v;
typedef __attribute__((ext_vector_type(4))) float f4v;

#define MFMA16(a, b, c) __builtin_amdgcn_mfma_f32_16x16x32_bf16((a), (b), (c), 0, 0, 0)

__device__ __forceinline__ float dcr_b2f(unsigned short x) {
  return __uint_as_float(((unsigned)x) << 16);
}
__device__ __forceinline__ unsigned short dcr_f2b(float x) {
  unsigned u = __float_as_uint(x);
  u += 0x7fffu + ((u >> 16) & 1u);
  return (unsigned short)(u >> 16);
}
__device__ __forceinline__ void dcr_split(float v, unsigned short& h, unsigned short& l) {
  h = dcr_f2b(v);
  l = dcr_f2b(v - dcr_b2f(h));
}
__device__ __forceinline__ float dcr_ld(const void* p, int idx, int isf) {
  if (isf) return ((const float*)p)[idx];
  return dcr_b2f(((const unsigned short*)p)[idx]);
}
__device__ __forceinline__ float dcr_sigm(float x) {
  return 1.0f / (1.0f + __expf(-x));
}
__device__ __forceinline__ float dcr_tanh(float x) {
  return 2.0f / (1.0f + __expf(-2.0f * x)) - 1.0f;
}
__device__ __forceinline__ s8v dcr_ld8(const unsigned short* p) {
  s8v r;
  *(s4v*)&r = *(const s4v*)p;
  *((s4v*)&r + 1) = *(const s4v*)(p + 4);
  return r;
}
__device__ __forceinline__ void dcr_st8(unsigned short* p, s8v v) {
  *(s4v*)p = *(const s4v*)&v;
  *(s4v*)(p + 4) = *((const s4v*)&v + 1);
}

// ---------------- weight repack: W[(f*5+m)][col] -> fragment order -----------
// gate (per layer,plane): e = (((m*8+nt)*4+ks)*64+lane)*8 + j
// cand (per layer,plane): e = (((m*4+nt)*4+ks)*64+lane)*8 + j
// element = W[(ks*32 + ((lane>>4)&3)*8 + j)*5 + m][nt*16 + (lane&15)]
__global__ void dcr_repack(const void* wg0, const void* wc0,
                           const void* wg1, const void* wc1,
                           const void* s0, unsigned short* o) {
  __shared__ int sisf;
  if (threadIdx.x == 0) {
    const unsigned short* ss = (const unsigned short*)s0;
    int hits = 0;
    for (int i = 0; i < 32; ++i) {
      unsigned hb = ((unsigned)ss[2 * i] >> 8) & 0xFFu;
      if (hb >= 0x30u && hb <= 0x3Fu) ++hits;
    }
    sisf = (hits < 16) ? 1 : 0;
  }
  __syncthreads();
  const int isf = sisf;
  const int NT = 4 * GN + 4 * CN;
  for (int e = blockIdx.x * blockDim.x + threadIdx.x; e < NT;
       e += gridDim.x * blockDim.x) {
    const void* W;
    int pl, ee, ncol, m, nt, ks, lane, j;
    if (e < 4 * GN) {
      int li = e / (2 * GN);
      int rem = e - li * 2 * GN;
      pl = rem / GN;
      ee = rem - pl * GN;
      W = li ? wg1 : wg0;
      ncol = 128;
      j = ee & 7; lane = (ee >> 3) & 63; ks = (ee >> 9) & 3;
      nt = (ee >> 11) & 7; m = ee >> 14;
    } else {
      int c = e - 4 * GN;
      int li = c / (2 * CN);
      int rem = c - li * 2 * CN;
      pl = rem / CN;
      ee = rem - pl * CN;
      W = li ? wc1 : wc0;
      ncol = 64;
      j = ee & 7; lane = (ee >> 3) & 63; ks = (ee >> 9) & 3;
      nt = (ee >> 11) & 3; m = ee >> 13;
    }
    if (pl == 1 && !isf) continue;
    const int f = ks * 32 + ((lane >> 4) & 3) * 8 + j;
    const int col = nt * 16 + (lane & 15);
    const int si = (f * 5 + m) * ncol + col;
    unsigned short v;
    if (!isf) {
      v = ((const unsigned short*)W)[si];
    } else {
      float w = ((const float*)W)[si];
      unsigned short hh = dcr_f2b(w);
      v = (pl == 0) ? hh : dcr_f2b(w - dcr_b2f(hh));
    }
    o[e] = v;
  }
}

// ---------------- MFMA building blocks --------------------------------------
// gate proj one m-term: wave w (0..7) owns N-tile w, M-tiles 0..3 (nodes).
// A-fragments are b128 reads from L_nf terms; B = repacked global weights.
__device__ __forceinline__ void dcr_gp(f4v& A0, f4v& A1, f4v& A2, f4v& A3,
                                       const unsigned short* th,
                                       const unsigned short* tl,
                                       const unsigned short* rph,
                                       const unsigned short* rpl,
                                       int m, int w, int lane, int wlo) {
  const int ln15 = lane & 15;
  const int k8 = ((lane >> 4) & 3) * 8;
#pragma unroll
  for (int ks = 0; ks < 4; ++ks) {
    const int fo = (((m * 8 + w) * 4 + ks) * 64 + lane) * 8;
    s8v bh = *(const s8v*)(rph + fo);
    s8v bl;
    if (wlo) bl = *(const s8v*)(rpl + fo);
    const int kb = ks * 32 + k8;
#define DCR_GP_MT(AX, MT)                                                  \
    {                                                                      \
      const int node = (MT) * 16 + ln15;                                   \
      const int a = TADDR(node, kb);                                       \
      s8v ah = dcr_ld8(th + a);                                            \
      s8v al = dcr_ld8(tl + a);                                            \
      AX = MFMA16(ah, bh, AX);                                             \
      AX = MFMA16(al, bh, AX);                                             \
      if (wlo) AX = MFMA16(ah, bl, AX);                                    \
    }
    DCR_GP_MT(A0, 0)
    DCR_GP_MT(A1, 1)
    DCR_GP_MT(A2, 2)
    DCR_GP_MT(A3, 3)
#undef DCR_GP_MT
  }
}

// cand proj one m-term: wave w4 (0..3) owns cand N-tile w4. pass 0 = x-half
// (abs ks 0..1), pass 1 = rh-half (abs ks 2..3, 64-wide rh term).
__device__ __forceinline__ void dcr_cp(f4v& A0, f4v& A1, f4v& A2, f4v& A3,
                                       const unsigned short* th,
                                       const unsigned short* tl,
                                       const unsigned short* rph,
                                       const unsigned short* rpl,
                                       int m, int w4, int lane, int wlo,
                                       int pass) {
  const int ln15 = lane & 15;
  const int k8 = ((lane >> 4) & 3) * 8;
#pragma unroll
  for (int ks2 = 0; ks2 < 2; ++ks2) {
    const int ks = pass * 2 + ks2;
    const int fo = (((m * 4 + w4) * 4 + ks) * 64 + lane) * 8;
    s8v bh = *(const s8v*)(rph + fo);
    s8v bl;
    if (wlo) bl = *(const s8v*)(rpl + fo);
    const int kb = ks2 * 32 + k8;
#define DCR_CP_MT(AX, MT)                                                  \
    {                                                                      \
      const int node = (MT) * 16 + ln15;                                   \
      const int a = TADDR(node, kb);                                       \
      s8v ah = dcr_ld8(th + a);                                            \
      s8v al = dcr_ld8(tl + a);                                            \
      AX = MFMA16(ah, bh, AX);                                             \
      AX = MFMA16(al, bh, AX);                                             \
      if (wlo) AX = MFMA16(ah, bl, AX);                                    \
    }
    DCR_CP_MT(A0, 0)
    DCR_CP_MT(A1, 1)
    DCR_CP_MT(A2, 2)
    DCR_CP_MT(A3, 3)
#undef DCR_CP_MT
  }
}

// apply: Y[out-node][feat] = S @ X, reoriented: A = S[out][in] (b128 from
// LDS, stride RSS), B = X[in][feat] (u16 gathers from L_nf, swizzle makes
// lane-groups bank-disjoint). Wave idx owns out-node tile idx; NMT feat
// tiles. Cheb via C-init = -init/2 and 2x writeback. Named accumulators.
#define DCR_AP_INIT(ACX, NT)                                               \
  {                                                                        \
    if (ih_) {                                                             \
      _Pragma("unroll") for (int r = 0; r < 4; ++r) {                      \
        const int a = TADDR(orow + rq + r, (NT) * 16 + ln15);              \
        ACX[r] = -0.5f * (dcr_b2f(ih_[a]) + dcr_b2f(il_[a]));              \
      }                                                                    \
    } else {                                                               \
      ACX[0] = 0.0f; ACX[1] = 0.0f; ACX[2] = 0.0f; ACX[3] = 0.0f;          \
    }                                                                      \
  }
#define DCR_AP_MFMA(ACX, NT)                                               \
  {                                                                        \
    s8v bh, b2;                                                            \
    _Pragma("unroll") for (int j = 0; j < 8; ++j) {                        \
      const int a = TADDR(kb + j, (NT) * 16 + ln15);                       \
      bh[j] = (short)srch[a];                                              \
      b2[j] = (short)srcl[a];                                              \
    }                                                                      \
    ACX = MFMA16(ah, bh, ACX);                                             \
    ACX = MFMA16(ah, b2, ACX);                                             \
    if (wlo) ACX = MFMA16(al, bh, ACX);                                    \
  }
#define DCR_AP_STORE(ACX, NT)                                              \
  {                                                                        \
    _Pragma("unroll") for (int r = 0; r < 4; ++r) {                        \
      const int a = TADDR(orow + rq + r, (NT) * 16 + ln15);                \
      const float v = fct * ACX[r];                                        \
      unsigned short hh, hl;                                               \
      dcr_split(v, hh, hl);                                                \
      dh_[a] = hh;                                                         \
      dl_[a] = hl;                                                         \
    }                                                                      \
  }

template <int NMT>
__device__ __forceinline__ void dcr_ap(const unsigned short* sh_,
                                       const unsigned short* sl_,
                                       const unsigned short* srch,
                                       const unsigned short* srcl,
                                       unsigned short* dh_, unsigned short* dl_,
                                       const unsigned short* ih_,
                                       const unsigned short* il_,
                                       int idx, int lane, int wlo) {
  const int ln15 = lane & 15;
  const int k8 = ((lane >> 4) & 3) * 8;
  const int rq = ((lane >> 4) & 3) * 4;
  const int orow = idx * 16;  // wave's out-node base
  f4v AC0, AC1, AC2, AC3, AC4, AC5, AC6, AC7;
  DCR_AP_INIT(AC0, 0)
  DCR_AP_INIT(AC1, 1)
  DCR_AP_INIT(AC2, 2)
  DCR_AP_INIT(AC3, 3)
  if constexpr (NMT == 8) {
    DCR_AP_INIT(AC4, 4)
    DCR_AP_INIT(AC5, 5)
    DCR_AP_INIT(AC6, 6)
    DCR_AP_INIT(AC7, 7)
  }
#pragma unroll
  for (int ks = 0; ks < 2; ++ks) {
    const int kb = ks * 32 + k8;
    s8v ah = dcr_ld8(sh_ + (orow + ln15) * RSS + kb);
    s8v al;
    if (wlo) al = dcr_ld8(sl_ + (orow + ln15) * RSS + kb);
    DCR_AP_MFMA(AC0, 0)
    DCR_AP_MFMA(AC1, 1)
    DCR_AP_MFMA(AC2, 2)
    DCR_AP_MFMA(AC3, 3)
    if constexpr (NMT == 8) {
      DCR_AP_MFMA(AC4, 4)
      DCR_AP_MFMA(AC5, 5)
      DCR_AP_MFMA(AC6, 6)
      DCR_AP_MFMA(AC7, 7)
    }
  }
  const float fct = ih_ ? 2.0f : 1.0f;
  DCR_AP_STORE(AC0, 0)
  DCR_AP_STORE(AC1, 1)
  DCR_AP_STORE(AC2, 2)
  DCR_AP_STORE(AC3, 3)
  if constexpr (NMT == 8) {
    DCR_AP_STORE(AC4, 4)
    DCR_AP_STORE(AC5, 5)
    DCR_AP_STORE(AC6, 6)
    DCR_AP_STORE(AC7, 7)
  }
}

// ---------------- one DCGRU layer step (compile-time L, no ptr selects) -----
template <int L>
__device__ __forceinline__ void dcr_layer(
    f4v& hA0, f4v& hA1, f4v& hA2, f4v& hA3,
    f4v& hB0, f4v& hB1, f4v& hB2, f4v& hB3,
    const void* xseq, int b, int t, int isf, int wlo,
    const unsigned short* rp,
    unsigned short* T0h, unsigned short* T0l,
    unsigned short* T1h, unsigned short* T1l,
    unsigned short* T2h, unsigned short* T2l,
    const unsigned short* S0h, const unsigned short* S0l,
    const unsigned short* S1h, const unsigned short* S1l,
    unsigned short* HBh, unsigned short* HBl,
    const float* BG, const float* BC,
    int tid, int lane, int wid) {
  const int ln15 = lane & 15;
  const int rq = ((lane >> 4) & 3) * 4;
  const unsigned short* rpgh = rp + (L * 2 + 0) * GN;
  const unsigned short* rpgl = rp + (L * 2 + 1) * GN;
  const unsigned short* rpch = rp + 4 * GN + (L * 2 + 0) * CN;
  const unsigned short* rpcl = rp + 4 * GN + (L * 2 + 1) * CN;

  f4v A0 = {0.0f, 0.0f, 0.0f, 0.0f};
  f4v A1 = {0.0f, 0.0f, 0.0f, 0.0f};
  f4v A2 = {0.0f, 0.0f, 0.0f, 0.0f};
  f4v A3 = {0.0f, 0.0f, 0.0f, 0.0f};

  // ---------------- P0: build cat = [x | h] in T0 (L_nf), h copy in HB -----
  if constexpr (L == 0) {
    if (wid < 8) {
      const int n = tid >> 3;
      const int f0 = (tid & 7) * 8;
      const int xo = (b * 96 + t) * 4096 + n * 64 + f0;
      const int base = TADDR(n, f0);  // 8-run contiguous, 16B aligned
      if (isf) {
        const float* xp = (const float*)xseq + xo;
        s8v vh, vl;
#pragma unroll
        for (int j = 0; j < 8; ++j) {
          unsigned short hh, hl;
          dcr_split(xp[j], hh, hl);
          vh[j] = (short)hh;
          vl[j] = (short)hl;
        }
        dcr_st8(T0h + base, vh);
        dcr_st8(T0l + base, vl);
      } else {
        const unsigned short* xp = (const unsigned short*)xseq + xo;
        s8v v = *(const s8v*)xp;
        s8v z = {0, 0, 0, 0, 0, 0, 0, 0};
        dcr_st8(T0h + base, v);
        dcr_st8(T0l + base, z);
      }
    } else if (wid < 12) {
      const int f = (wid - 8) * 16 + ln15;
#define DCR_ST0(HX, MT)                                                    \
      { _Pragma("unroll") for (int r = 0; r < 4; ++r) {                    \
          const int node = (MT) * 16 + rq + r;                             \
          const int a = TADDR(node, 64 + f);                               \
          unsigned short hh, hl;                                           \
          dcr_split(HX[r], hh, hl);                                        \
          T0h[a] = hh;                                                     \
          T0l[a] = hl;                                                     \
          HBh[node * RSH + f] = hh;                                        \
          HBl[node * RSH + f] = hl; } }
      DCR_ST0(hA0, 0)
      DCR_ST0(hA1, 1)
      DCR_ST0(hA2, 2)
      DCR_ST0(hA3, 3)
#undef DCR_ST0
    }
  } else {
    if (wid >= 8 && wid < 12) {
      const int f = (wid - 8) * 16 + ln15;
#define DCR_ST1(HAX, HBX, MT)                                              \
      { _Pragma("unroll") for (int r = 0; r < 4; ++r) {                    \
          const int node = (MT) * 16 + rq + r;                             \
          unsigned short hh, hl;                                           \
          dcr_split(HAX[r], hh, hl);                                       \
          const int a0 = TADDR(node, f);                                   \
          T0h[a0] = hh;                                                    \
          T0l[a0] = hl;                                                    \
          dcr_split(HBX[r], hh, hl);                                       \
          const int a1 = TADDR(node, 64 + f);                              \
          T0h[a1] = hh;                                                    \
          T0l[a1] = hl;                                                    \
          HBh[node * RSH + f] = hh;                                        \
          HBl[node * RSH + f] = hl; } }
      DCR_ST1(hA0, hB0, 0)
      DCR_ST1(hA1, hB1, 1)
      DCR_ST1(hA2, hB2, 2)
      DCR_ST1(hA3, hB3, 3)
#undef DCR_ST1
    }
  }
  __syncthreads();

  // ---------------- gate pass: pm0..pm4 ------------------------------------
  if (wid < 8) dcr_gp(A0, A1, A2, A3, T0h, T0l, rpgh, rpgl, 0, wid, lane, wlo);
  else if (wid < 12) dcr_cp(A0, A1, A2, A3, T0h, T0l, rpch, rpcl, 0, wid - 8, lane, wlo, 0);
  else dcr_ap<8>(S0h, S0l, T0h, T0l, T1h, T1l, nullptr, nullptr, wid - 12, lane, wlo);
  __syncthreads();
  if (wid < 8) dcr_gp(A0, A1, A2, A3, T1h, T1l, rpgh, rpgl, 1, wid, lane, wlo);
  else if (wid < 12) dcr_cp(A0, A1, A2, A3, T1h, T1l, rpch, rpcl, 1, wid - 8, lane, wlo, 0);
  else dcr_ap<8>(S0h, S0l, T1h, T1l, T2h, T2l, T0h, T0l, wid - 12, lane, wlo);
  __syncthreads();
  if (wid < 8) dcr_gp(A0, A1, A2, A3, T2h, T2l, rpgh, rpgl, 2, wid, lane, wlo);
  else if (wid < 12) dcr_cp(A0, A1, A2, A3, T2h, T2l, rpch, rpcl, 2, wid - 8, lane, wlo, 0);
  else dcr_ap<8>(S1h, S1l, T1h, T1l, T0h, T0l, nullptr, nullptr, wid - 12, lane, wlo);
  __syncthreads();
  if (wid < 8) dcr_gp(A0, A1, A2, A3, T0h, T0l, rpgh, rpgl, 3, wid, lane, wlo);
  else if (wid < 12) dcr_cp(A0, A1, A2, A3, T0h, T0l, rpch, rpcl, 3, wid - 8, lane, wlo, 0);
  else dcr_ap<8>(S1h, S1l, T0h, T0l, T2h, T2l, T1h, T1l, wid - 12, lane, wlo);
  __syncthreads();
  if (wid < 8) dcr_gp(A0, A1, A2, A3, T2h, T2l, rpgh, rpgl, 4, wid, lane, wlo);
  else if (wid < 12) dcr_cp(A0, A1, A2, A3, T2h, T2l, rpch, rpcl, 4, wid - 8, lane, wlo, 0);
  __syncthreads();

  // ---------------- gate finish: r -> rh (T0 feats 0-63), u -> T1 64-127 ---
  if (wid < 8) {
    const int g = wid * 16 + ln15;
    const float bgv = BG[L * 128 + g];
#define DCR_GFIN(AX, MT)                                                   \
    { _Pragma("unroll") for (int r = 0; r < 4; ++r) {                      \
        const int node = (MT) * 16 + rq + r;                               \
        const float s = dcr_sigm(AX[r] + bgv);                             \
        unsigned short hh, hl;                                             \
        if (wid < 4) {                                                     \
          const float h = dcr_b2f(HBh[node * RSH + g]) +                   \
                          dcr_b2f(HBl[node * RSH + g]);                    \
          dcr_split(s * h, hh, hl);                                        \
          const int a = TADDR(node, g);                                    \
          T0h[a] = hh;                                                     \
          T0l[a] = hl;                                                     \
        } else {                                                           \
          dcr_split(s, hh, hl);                                            \
          const int a = TADDR(node, g);                                    \
          T1h[a] = hh;                                                     \
          T1l[a] = hl;                                                     \
        } } }
    DCR_GFIN(A0, 0)
    DCR_GFIN(A1, 1)
    DCR_GFIN(A2, 2)
    DCR_GFIN(A3, 3)
#undef DCR_GFIN
  }
  __syncthreads();

  // ---------------- rh pass: pr0..pr4 (64-wide) ----------------------------
  if (wid >= 8 && wid < 12) dcr_cp(A0, A1, A2, A3, T0h, T0l, rpch, rpcl, 0, wid - 8, lane, wlo, 1);
  else if (wid >= 12) dcr_ap<4>(S0h, S0l, T0h, T0l, T1h, T1l, nullptr, nullptr, wid - 12, lane, wlo);
  __syncthreads();
  if (wid >= 8 && wid < 12) dcr_cp(A0, A1, A2, A3, T1h, T1l, rpch, rpcl, 1, wid - 8, lane, wlo, 1);
  else if (wid >= 12) dcr_ap<4>(S0h, S0l, T1h, T1l, T2h, T2l, T0h, T0l, wid - 12, lane, wlo);
  __syncthreads();
  if (wid >= 8 && wid < 12) dcr_cp(A0, A1, A2, A3, T2h, T2l, rpch, rpcl, 2, wid - 8, lane, wlo, 1);
  else if (wid >= 12) dcr_ap<4>(S1h, S1l, T1h, T1l, T0h, T0l, nullptr, nullptr, wid - 12, lane, wlo);
  __syncthreads();
  if (wid >= 8 && wid < 12) dcr_cp(A0, A1, A2, A3, T0h, T0l, rpch, rpcl, 3, wid - 8, lane, wlo, 1);
  else if (wid >= 12) dcr_ap<4>(S1h, S1l, T0h, T0l, T1h, T1l, T1h, T1l, wid - 12, lane, wlo);
  __syncthreads();
  if (wid >= 8 && wid < 12) dcr_cp(A0, A1, A2, A3, T1h, T1l, rpch, rpcl, 4, wid - 8, lane, wlo, 1);
  __syncthreads();

  // ---------------- cand finish: h_new = u*h + (1-u)*tanh(C+bc) ------------
  if (wid >= 8 && wid < 12) {
    const int f = (wid - 8) * 16 + ln15;
    const float bcv = BC[L * 64 + f];
#define DCR_CFIN(AX, HX, MT)                                               \
    { _Pragma("unroll") for (int r = 0; r < 4; ++r) {                      \
        const int node = (MT) * 16 + rq + r;                               \
        const float c = dcr_tanh(AX[r] + bcv);                             \
        const int a = TADDR(node, 64 + f);                                 \
        const float u = dcr_b2f(T1h[a]) + dcr_b2f(T1l[a]);                 \
        HX[r] = u * HX[r] + (1.0f - u) * c; } }
    if constexpr (L == 0) {
      DCR_CFIN(A0, hA0, 0)
      DCR_CFIN(A1, hA1, 1)
      DCR_CFIN(A2, hA2, 2)
      DCR_CFIN(A3, hA3, 3)
    } else {
      DCR_CFIN(A0, hB0, 0)
      DCR_CFIN(A1, hB1, 1)
      DCR_CFIN(A2, hB2, 2)
      DCR_CFIN(A3, hB3, 3)
    }
#undef DCR_CFIN
  }
  __syncthreads();
}

// ---------------- main MFMA kernel ------------------------------------------
__global__ __launch_bounds__(1024)
__attribute__((amdgpu_waves_per_eu(4, 4)))
void dcr_mfma(
    const void* xseq, const void* s0, const void* s1,
    const void* bg0, const void* bg1,
    const void* p64a, const void* p64b, const void* p64c,
    const void* fcw, const void* fcb, const void* idw, const void* idb,
    const unsigned short* rp, void* outp) {
  extern __shared__ char sm[];
  unsigned short* const T0h = (unsigned short*)(sm);
  unsigned short* const T0l = (unsigned short*)(sm + TPB);
  unsigned short* const T1h = (unsigned short*)(sm + 2 * TPB);
  unsigned short* const T1l = (unsigned short*)(sm + 3 * TPB);
  unsigned short* const T2h = (unsigned short*)(sm + 4 * TPB);
  unsigned short* const T2l = (unsigned short*)(sm + 5 * TPB);
  unsigned short* const S0h = (unsigned short*)(sm + OFF_S);
  unsigned short* const S0l = (unsigned short*)(sm + OFF_S + 8192);
  unsigned short* const S1h = (unsigned short*)(sm + OFF_S + 16384);
  unsigned short* const S1l = (unsigned short*)(sm + OFF_S + 24576);
  unsigned short* const HBh = (unsigned short*)(sm + OFF_HB);
  unsigned short* const HBl = (unsigned short*)(sm + OFF_HB + 8704);
  float* const BG = (float*)(sm + OFF_BG);
  float* const BC = (float*)(sm + OFF_BC);
  int* const ctl = (int*)(sm + OFF_CTL);

  const int tid = threadIdx.x;
  const int b = blockIdx.x;
  const int lane = tid & 63;
  const int wid = tid >> 6;

  // ---- on-device identification ----
  if (tid == 0) {
    const unsigned short* ss = (const unsigned short*)s0;
    int hits = 0;
    for (int i = 0; i < 32; ++i) {
      unsigned hb = ((unsigned)ss[2 * i] >> 8) & 0xFFu;
      if (hb >= 0x30u && hb <= 0x3Fu) ++hits;
    }
    int isf_ = (hits < 16) ? 1 : 0;
    int sel = 0;
    {
      const unsigned* w = (const unsigned*)p64a;
      unsigned any = 0;
      for (int i = 0; i < 16; ++i) any |= w[i];
      if (!any) {
        sel = 1;
        const unsigned* w1 = (const unsigned*)p64b;
        unsigned any1 = 0;
        for (int i = 0; i < 16; ++i) any1 |= w1[i];
        if (!any1) sel = 2;
      }
    }
    const unsigned* w =
        (const unsigned*)(sel == 0 ? p64a : (sel == 1 ? p64b : p64c));
    int i64 = 1;
    for (int i = 0; i < 8; ++i)
      if (w[2 * i + 1] != 0u) i64 = 0;
    ctl[0] = isf_;
    ctl[1] = sel;
    ctl[2] = i64;
  }
  __syncthreads();
  const int isf = ctl[0];
  const int sel = ctl[1];
  const int i64 = ctl[2];
  const int wlo = isf;  // lo planes of S/W meaningful only for fp32 inputs
  const void* seqp = (sel == 0) ? p64a : (sel == 1 ? p64b : p64c);
  const void* bcA = (sel == 0) ? p64b : p64a;
  const void* bcB = (sel == 2) ? p64b : p64c;

  // ---- stage supports (hi/lo, [out][in] stride RSS) and biases ----
  for (int i = 0; i < 4; ++i) {
    const int flat = i * 1024 + tid;  // = out*64 + in
    float v0, v1;
    if (isf) {
      v0 = ((const float*)s0)[flat];
      v1 = ((const float*)s1)[flat];
    } else {
      v0 = dcr_b2f(((const unsigned short*)s0)[flat]);
      v1 = dcr_b2f(((const unsigned short*)s1)[flat]);
    }
    unsigned short hh, hl;
    dcr_split(v0, hh, hl);
    S0h[flat] = hh;
    S0l[flat] = hl;
    dcr_split(v1, hh, hl);
    S1h[flat] = hh;
    S1l[flat] = hl;
  }
  if (tid < 128) {
    BG[tid] = dcr_ld(bg0, tid, isf);
    BG[128 + tid] = dcr_ld(bg1, tid, isf);
  } else if (tid < 192) {
    const int j = tid - 128;
    BC[j] = dcr_ld(bcA, j, isf);
    BC[64 + j] = dcr_ld(bcB, j, isf);
  }

  int tl_;
  if (i64) tl_ = (int)((const long long*)seqp)[b] - 1;
  else     tl_ = ((const int*)seqp)[b] - 1;
  if (tl_ < 0) tl_ = 0;
  if (tl_ > 95) tl_ = 95;

  f4v hA0 = {0.0f, 0.0f, 0.0f, 0.0f};
  f4v hA1 = {0.0f, 0.0f, 0.0f, 0.0f};
  f4v hA2 = {0.0f, 0.0f, 0.0f, 0.0f};
  f4v hA3 = {0.0f, 0.0f, 0.0f, 0.0f};
  f4v hB0 = {0.0f, 0.0f, 0.0f, 0.0f};
  f4v hB1 = {0.0f, 0.0f, 0.0f, 0.0f};
  f4v hB2 = {0.0f, 0.0f, 0.0f, 0.0f};
  f4v hB3 = {0.0f, 0.0f, 0.0f, 0.0f};
  __syncthreads();

  for (int t = 0; t < 96; ++t) {
    dcr_layer<0>(hA0, hA1, hA2, hA3, hB0, hB1, hB2, hB3,
                 xseq, b, t, isf, wlo, rp,
                 T0h, T0l, T1h, T1l, T2h, T2l,
                 S0h, S0l, S1h, S1l, HBh, HBl, BG, BC, tid, lane, wid);
    dcr_layer<1>(hA0, hA1, hA2, hA3, hB0, hB1, hB2, hB3,
                 xseq, b, t, isf, wlo, rp,
                 T0h, T0l, T1h, T1l, T2h, T2l,
                 S0h, S0l, S1h, S1l, HBh, HBl, BG, BC, tid, lane, wid);
    if (t == tl_) break;
  }

  // ---------------- heads: relu(h1) -> fc/id matmul -> max over nodes -------
  __syncthreads();
  const int ln15 = lane & 15;
  const int rq = ((lane >> 4) & 3) * 4;
  float* const hx = (float*)sm;              // [64][66]
  float* const hw = (float*)(sm + 2 * TPB);  // [64][56]
  float* const red = (float*)(sm + 4 * TPB); // [16][54]
  if (wid >= 8 && wid < 12) {
    const int f = (wid - 8) * 16 + ln15;
#define DCR_HX(HX, MT)                                                     \
    { _Pragma("unroll") for (int r = 0; r < 4; ++r) {                      \
        const int node = (MT) * 16 + rq + r;                               \
        hx[node * 66 + f] = fmaxf(HX[r], 0.0f); } }
    DCR_HX(hB0, 0)
    DCR_HX(hB1, 1)
    DCR_HX(hB2, 2)
    DCR_HX(hB3, 3)
#undef DCR_HX
  }
  {
    const int u = tid >> 4;
    for (int c = (tid & 15); c < 54; c += 16)
      hw[u * 56 + c] = (c < 4) ? dcr_ld(fcw, u * 4 + c, isf)
                               : dcr_ld(idw, u * 50 + (c - 4), isf);
  }
  __syncthreads();
  if (tid < 864) {
    const int c = tid % 54, nb = tid / 54;
    float mx = -3.4e38f;
    for (int nn = nb * 4; nn < nb * 4 + 4; ++nn) {
      float s = 0.0f;
#pragma unroll 8
      for (int uu = 0; uu < 64; ++uu) s += hx[nn * 66 + uu] * hw[uu * 56 + c];
      mx = fmaxf(mx, s);
    }
    red[nb * 54 + c] = mx;
  }
  __syncthreads();
  if (tid < 54) {
    float mx = red[tid];
#pragma unroll
    for (int g = 1; g < 16; ++g) mx = fmaxf(mx, red[g * 54 + tid]);
    mx += (tid < 4) ? dcr_ld(fcb, tid, isf) : dcr_ld(idb, tid - 4, isf);
    const int o = (tid < 4) ? (b * 4 + tid) : (256 + b * 50 + (tid - 4));
    if (isf) ((float*)outp)[o] = mx;
    else     ((unsigned short*)outp)[o] = dcr_f2b(mx);
  }
}

// ============================================================================
// Fallback: proven scalar kernel (round-1, 1024 threads) for ws-too-small.
// ============================================================================
__device__ void dcr_proj(float* aG, float* aC, const float (*buf)[68],
                         const void* Wg, const void* Wc, int m, int fh,
                         int n, int fb, int doG, int doC, int isf) {
  if (!isf) {
    const unsigned* G = (const unsigned*)Wg;
    const unsigned* C = (const unsigned*)Wc;
    const int fd = fb >> 1;
#pragma unroll 4
    for (int k = 0; k < 64; ++k) {
      float xk = buf[n][k];
      int row = (fh + k) * 5 + m;
      if (doG) {
        const unsigned* wr = G + row * 64 + fd;
        unsigned p0 = wr[0], p1 = wr[1], p2 = wr[32], p3 = wr[33];
        aG[0] += xk * __uint_as_float(p0 << 16);
        aG[1] += xk * __uint_as_float(p0 & 0xFFFF0000u);
        aG[2] += xk * __uint_as_float(p1 << 16);
        aG[3] += xk * __uint_as_float(p1 & 0xFFFF0000u);
        aG[4] += xk * __uint_as_float(p2 << 16);
        aG[5] += xk * __uint_as_float(p2 & 0xFFFF0000u);
        aG[6] += xk * __uint_as_float(p3 << 16);
        aG[7] += xk * __uint_as_float(p3 & 0xFFFF0000u);
      }
      if (doC) {
        const unsigned* wr = C + row * 32 + fd;
        unsigned p0 = wr[0], p1 = wr[1];
        aC[0] += xk * __uint_as_float(p0 << 16);
        aC[1] += xk * __uint_as_float(p0 & 0xFFFF0000u);
        aC[2] += xk * __uint_as_float(p1 << 16);
        aC[3] += xk * __uint_as_float(p1 & 0xFFFF0000u);
      }
    }
  } else {
    const float* G = (const float*)Wg;
    const float* C = (const float*)Wc;
#pragma unroll 4
    for (int k = 0; k < 64; ++k) {
      float xk = buf[n][k];
      int row = (fh + k) * 5 + m;
      if (doG) {
        const float* wr = G + row * 128 + fb;
#pragma unroll
        for (int j = 0; j < 4; ++j) {
          aG[j] += xk * wr[j];
          aG[4 + j] += xk * wr[64 + j];
        }
      }
      if (doC) {
        const float* wr = C + row * 64 + fb;
#pragma unroll
        for (int j = 0; j < 4; ++j) aC[j] += xk * wr[j];
      }
    }
  }
}

__device__ void dcr_apply(float (*dst)[68], const float (*src)[68],
                          const unsigned short (*sS)[65], int n, int fb,
                          int cheb) {
  float a0 = 0.0f, a1 = 0.0f, a2 = 0.0f, a3 = 0.0f;
#pragma unroll 8
  for (int m = 0; m < 64; ++m) {
    float s = dcr_b2f(sS[n][m]);
    float4 v = *(const float4*)(&src[m][fb]);
    a0 += s * v.x;
    a1 += s * v.y;
    a2 += s * v.z;
    a3 += s * v.w;
  }
  if (cheb) {
    dst[n][fb + 0] = 2.0f * a0 - dst[n][fb + 0];
    dst[n][fb + 1] = 2.0f * a1 - dst[n][fb + 1];
    dst[n][fb + 2] = 2.0f * a2 - dst[n][fb + 2];
    dst[n][fb + 3] = 2.0f * a3 - dst[n][fb + 3];
  } else {
    dst[n][fb + 0] = a0;
    dst[n][fb + 1] = a1;
    dst[n][fb + 2] = a2;
    dst[n][fb + 3] = a3;
  }
}

__device__ void dcr_half(float* aG, float* aC, const void* Wg, const void* Wc,
                         int fh, int doG, int doC, float (*xa)[68],
                         float (*xb)[68], const unsigned short (*sS0)[65],
                         const unsigned short (*sS1)[65], int n, int fb,
                         int isf) {
  dcr_proj(aG, aC, xa, Wg, Wc, 0, fh, n, fb, doG, doC, isf);
  dcr_apply(xb, xa, sS0, n, fb, 0);
  __syncthreads();
  dcr_proj(aG, aC, xb, Wg, Wc, 1, fh, n, fb, doG, doC, isf);
  dcr_apply(xa, xb, sS0, n, fb, 1);
  __syncthreads();
  dcr_proj(aG, aC, xa, Wg, Wc, 2, fh, n, fb, doG, doC, isf);
  __syncthreads();
  dcr_apply(xa, xb, sS1, n, fb, 0);
  __syncthreads();
  dcr_proj(aG, aC, xa, Wg, Wc, 3, fh, n, fb, doG, doC, isf);
  dcr_apply(xb, xa, sS1, n, fb, 1);
  __syncthreads();
  dcr_proj(aG, aC, xb, Wg, Wc, 4, fh, n, fb, doG, doC, isf);
  __syncthreads();
}

__global__ __launch_bounds__(1024) void dcr_scalar(
    const void* xseq, const void* s0, const void* s1, const void* wg0,
    const void* wc0, const void* wg1, const void* wc1, const void* bg0,
    const void* bg1, const void* p64a, const void* p64b, const void* p64c,
    const void* fcw, const void* fcb, const void* idw, const void* idb,
    void* outp) {
  __shared__ float xa[64][68];
  __shared__ float xb[64][68];
  __shared__ unsigned short sS[2][64][65];
  __shared__ float bGs[2][128];
  __shared__ float bCs[2][64];
  __shared__ float red[16][54];
  __shared__ int ctl[4];

  const int tid = threadIdx.x;
  const int b = blockIdx.x;
  const int n = tid >> 4;
  const int fb = (tid & 15) * 4;

  if (tid == 0) {
    const unsigned short* ss = (const unsigned short*)s0;
    int hits = 0;
    for (int i = 0; i < 32; ++i) {
      unsigned hb = ((unsigned)ss[2 * i] >> 8) & 0xFFu;
      if (hb >= 0x30u && hb <= 0x3Fu) ++hits;
    }
    int isf = (hits < 16) ? 1 : 0;
    int sel = 0;
    {
      const unsigned* w = (const unsigned*)p64a;
      unsigned any = 0;
      for (int i = 0; i < 16; ++i) any |= w[i];
      if (!any) {
        sel = 1;
        const unsigned* w1 = (const unsigned*)p64b;
        unsigned any1 = 0;
        for (int i = 0; i < 16; ++i) any1 |= w1[i];
        if (!any1) sel = 2;
      }
    }
    const unsigned* w =
        (const unsigned*)(sel == 0 ? p64a : (sel == 1 ? p64b : p64c));
    int i64 = 1;
    for (int i = 0; i < 8; ++i)
      if (w[2 * i + 1] != 0u) i64 = 0;
    ctl[0] = isf;
    ctl[1] = sel;
    ctl[2] = i64;
  }
  __syncthreads();
  const int isf = ctl[0];
  const int sel = ctl[1];
  const int i64 = ctl[2];
  const void* seqp = (sel == 0) ? p64a : (sel == 1 ? p64b : p64c);
  const void* bcA = (sel == 0) ? p64b : p64a;
  const void* bcB = (sel == 2) ? p64b : p64c;

  for (int i = 0; i < 4; ++i) {
    int flat = i * 1024 + tid;
    int nn = flat >> 6, mm = flat & 63;
    unsigned short v0, v1;
    if (isf) {
      v0 = dcr_f2b(((const float*)s0)[flat]);
      v1 = dcr_f2b(((const float*)s1)[flat]);
    } else {
      v0 = ((const unsigned short*)s0)[flat];
      v1 = ((const unsigned short*)s1)[flat];
    }
    sS[0][nn][mm] = v0;
    sS[1][nn][mm] = v1;
  }
  if (tid < 128) {
    bGs[0][tid] = dcr_ld(bg0, tid, isf);
    bGs[1][tid] = dcr_ld(bg1, tid, isf);
  } else if (tid < 192) {
    int j = tid - 128;
    bCs[0][j] = dcr_ld(bcA, j, isf);
    bCs[1][j] = dcr_ld(bcB, j, isf);
  }

  int tl;
  if (i64) tl = (int)((const long long*)seqp)[b] - 1;
  else     tl = ((const int*)seqp)[b] - 1;
  if (tl < 0) tl = 0;
  if (tl > 95) tl = 95;

  float h0r[4], h1r[4];
#pragma unroll
  for (int j = 0; j < 4; ++j) {
    h0r[j] = 0.0f;
    h1r[j] = 0.0f;
  }
  __syncthreads();

  for (int t = 0; t < 96; ++t) {
    {
      float aG[8], aC[4];
#pragma unroll
      for (int j = 0; j < 8; ++j) aG[j] = 0.0f;
#pragma unroll
      for (int j = 0; j < 4; ++j) aC[j] = 0.0f;
      int xoff = (b * 96 + t) * 4096 + n * 64 + fb;
#pragma unroll
      for (int j = 0; j < 4; ++j) xa[n][fb + j] = dcr_ld(xseq, xoff + j, isf);
      __syncthreads();
      dcr_half(aG, aC, wg0, wc0, 0, 1, 1, xa, xb, sS[0], sS[1], n, fb, isf);
#pragma unroll
      for (int j = 0; j < 4; ++j) xa[n][fb + j] = h0r[j];
      __syncthreads();
      dcr_half(aG, aC, wg0, wc0, 64, 1, 0, xa, xb, sS[0], sS[1], n, fb, isf);
      float rr[4], uu[4];
#pragma unroll
      for (int j = 0; j < 4; ++j) {
        rr[j] = dcr_sigm(aG[j] + bGs[0][fb + j]);
        uu[j] = dcr_sigm(aG[4 + j] + bGs[0][64 + fb + j]);
      }
#pragma unroll
      for (int j = 0; j < 4; ++j) xa[n][fb + j] = rr[j] * h0r[j];
      __syncthreads();
      dcr_half(aG, aC, wg0, wc0, 64, 0, 1, xa, xb, sS[0], sS[1], n, fb, isf);
#pragma unroll
      for (int j = 0; j < 4; ++j) {
        float c = dcr_tanh(aC[j] + bCs[0][fb + j]);
        h0r[j] = uu[j] * h0r[j] + (1.0f - uu[j]) * c;
      }
    }
    {
      float aG[8], aC[4];
#pragma unroll
      for (int j = 0; j < 8; ++j) aG[j] = 0.0f;
#pragma unroll
      for (int j = 0; j < 4; ++j) aC[j] = 0.0f;
#pragma unroll
      for (int j = 0; j < 4; ++j) xa[n][fb + j] = h0r[j];
      __syncthreads();
      dcr_half(aG, aC, wg1, wc1, 0, 1, 1, xa, xb, sS[0], sS[1], n, fb, isf);
#pragma unroll
      for (int j = 0; j < 4; ++j) xa[n][fb + j] = h1r[j];
      __syncthreads();
      dcr_half(aG, aC, wg1, wc1, 64, 1, 0, xa, xb, sS[0], sS[1], n, fb, isf);
      float rr[4], uu[4];
#pragma unroll
      for (int j = 0; j < 4; ++j) {
        rr[j] = dcr_sigm(aG[j] + bGs[1][fb + j]);
        uu[j] = dcr_sigm(aG[4 + j] + bGs[1][64 + fb + j]);
      }
#pragma unroll
      for (int j = 0; j < 4; ++j) xa[n][fb + j] = rr[j] * h1r[j];
      __syncthreads();
      dcr_half(aG, aC, wg1, wc1, 64, 0, 1, xa, xb, sS[0], sS[1], n, fb, isf);
#pragma unroll
      for (int j = 0; j < 4; ++j) {
        float c = dcr_tanh(aC[j] + bCs[1][fb + j]);
        h1r[j] = uu[j] * h1r[j] + (1.0f - uu[j]) * c;
      }
    }
    if (t == tl) break;
  }

  __syncthreads();
#pragma unroll
  for (int j = 0; j < 4; ++j) xa[n][fb + j] = fmaxf(h1r[j], 0.0f);
  {
    int u = tid >> 4;
    for (int c = (tid & 15); c < 54; c += 16)
      xb[u][c] = (c < 4) ? dcr_ld(fcw, u * 4 + c, isf)
                         : dcr_ld(idw, u * 50 + (c - 4), isf);
  }
  __syncthreads();
  if (tid < 864) {
    int c = tid % 54, nb = tid / 54;
    float mx = -3.4e38f;
    for (int nn = nb * 4; nn < nb * 4 + 4; ++nn) {
      float s = 0.0f;
#pragma unroll 8
      for (int u = 0; u < 64; ++u) s += xa[nn][u] * xb[u][c];
      mx = fmaxf(mx, s);
    }
    red[nb][c] = mx;
  }
  __syncthreads();
  if (tid < 54) {
    float mx = red[0][tid];
#pragma unroll
    for (int g = 1; g < 16; ++g) mx = fmaxf(mx, red[g][tid]);
    mx += (tid < 4) ? dcr_ld(fcb, tid, isf) : dcr_ld(idb, tid - 4, isf);
    int o = (tid < 4) ? (b * 4 + tid) : (256 + b * 50 + (tid - 4));
    if (isf) ((float*)outp)[o] = mx;
    else     ((unsigned short*)outp)[o] = dcr_f2b(mx);
  }
}

// ---------------------------------------------------------------------------
static int dcr_find_nth(const int* s, int n, int sz, int nth) {
  int c = 0;
  for (int i = 0; i < n; ++i)
    if (s[i] == sz) {
      if (c == nth) return i;
      ++c;
    }
  return -1;
}

extern "C" void kernel_launch(void* const* d_in, const int* in_sizes, int n_in,
                              void* d_out, int out_size, void* d_ws,
                              size_t ws_size, hipStream_t stream) {
  (void)out_size;
  int i_seq = dcr_find_nth(in_sizes, n_in, 393216, 0);
  int i_s0 = dcr_find_nth(in_sizes, n_in, 4096, 0);
  int i_s1 = dcr_find_nth(in_sizes, n_in, 4096, 1);
  int i_wg0 = dcr_find_nth(in_sizes, n_in, 81920, 0);
  int i_wg1 = dcr_find_nth(in_sizes, n_in, 81920, 1);
  int i_wc0 = dcr_find_nth(in_sizes, n_in, 40960, 0);
  int i_wc1 = dcr_find_nth(in_sizes, n_in, 40960, 1);
  int i_bg0 = dcr_find_nth(in_sizes, n_in, 128, 0);
  int i_bg1 = dcr_find_nth(in_sizes, n_in, 128, 1);
  int i_64a = dcr_find_nth(in_sizes, n_in, 64, 0);
  int i_64b = dcr_find_nth(in_sizes, n_in, 64, 1);
  int i_64c = dcr_find_nth(in_sizes, n_in, 64, 2);
  int i_fcw = dcr_find_nth(in_sizes, n_in, 256, 0);
  int i_fcb = dcr_find_nth(in_sizes, n_in, 4, 0);
  int i_idw = dcr_find_nth(in_sizes, n_in, 3200, 0);
  int i_idb = dcr_find_nth(in_sizes, n_in, 50, 0);
  if (i_seq < 0 || i_s0 < 0 || i_s1 < 0 || i_wg0 < 0 || i_wg1 < 0 ||
      i_wc0 < 0 || i_wc1 < 0 || i_bg0 < 0 || i_bg1 < 0 || i_64a < 0 ||
      i_64b < 0 || i_64c < 0 || i_fcw < 0 || i_fcb < 0 || i_idw < 0 ||
      i_idb < 0) {
    i_seq = 0;  i_64a = 1;  i_s0 = 2;   i_s1 = 3;
    i_wg0 = 4;  i_bg0 = 5;  i_wc0 = 6;  i_64b = 7;
    i_wg1 = 8;  i_bg1 = 9;  i_wc1 = 10; i_64c = 11;
    i_fcw = 12; i_fcb = 13; i_idw = 14; i_idb = 15;
  }

  if (d_ws == nullptr || ws_size < (size_t)WS_NEED) {
    dcr_scalar<<<dim3(64), dim3(1024), 0, stream>>>(
        d_in[i_seq], d_in[i_s0], d_in[i_s1], d_in[i_wg0], d_in[i_wc0],
        d_in[i_wg1], d_in[i_wc1], d_in[i_bg0], d_in[i_bg1], d_in[i_64a],
        d_in[i_64b], d_in[i_64c], d_in[i_fcw], d_in[i_fcb], d_in[i_idw],
        d_in[i_idb], d_out);
    return;
  }

  dcr_repack<<<dim3(256), dim3(256), 0, stream>>>(
      d_in[i_wg0], d_in[i_wc0], d_in[i_wg1], d_in[i_wc1], d_in[i_s0],
      (unsigned short*)d_ws);

  static bool attr_set = false;
  if (!attr_set) {
    (void)hipFuncSetAttribute((const void*)dcr_mfma,
                              hipFuncAttributeMaxDynamicSharedMemorySize,
                              SMEM_SZ);
    attr_set = true;
  }

  dcr_mfma<<<dim3(64), dim3(1024), SMEM_SZ, stream>>>(
      d_in[i_seq], d_in[i_s0], d_in[i_s1], d_in[i_bg0], d_in[i_bg1],
      d_in[i_64a], d_in[i_64b], d_in[i_64c], d_in[i_fcw], d_in[i_fcb],
      d_in[i_idw], d_in[i_idb], (const unsigned short*)d_ws, d_out);
}

// Round 7
// 15338.365 us; speedup vs baseline: 2.1570x; 1.0101x over previous
//
#include <hip/hip_runtime.h>

// ---------------------------------------------------------------------------
// DCRNN (2-layer DCGRU encoder) -- MFMA round, interleaved-u32 terms.
// R6 post-mortem: 15.5ms; LDS-port issue ~65% of phase time, dominated by
// apply's scalar u16 hi/lo gather pairs + S-plane 16-way bank conflict
// (stride 64 u16 == 0 mod 32 banks; SQ_LDS_BANK_CONFLICT 2.1e8).
// This round (same math, verified absmax 2.4e-4 lineage):
//   * term planes store (lo<<16)|hi as ONE u32/element -> every paired
//     access (apply B-gathers, stores, gate/cand-finish, cheb-init) is one
//     b32 instead of two u16; proj reads 2xb128 + free VALU unpack
//   * gate waves 8 -> 4, each owning 2 N-tiles (32 cols): halves the
//     redundant term-A re-reads (A shared across both tiles in-wave)
//   * S planes padded to stride 68 u16 (conflict-free b128)
//   * swizzle feat ^= ((node>>3)&7)<<3 on u32 index (apply lane-groups
//     bank-disjoint; 16B alignment preserved)
//   * gate-finish merged into pm4, cand-finish into pr4 (13 -> 11 barriers)
// Wave roles: wid 0-3 gate(2NT) | 8-11 cand | 12-15 apply | 4-7 idle.
// ---------------------------------------------------------------------------

#define GN 81920           // gate repack elems per (layer,plane)
#define CN 40960           // cand repack elems per (layer,plane)
#define WS_NEED ((4*GN + 4*CN) * 2)

#define OFF_T0  0          // term planes: [64][132] u32 (33792 B each)
#define OFF_T1  33792
#define OFF_T2  67584
#define OFF_S0H 101376     // S planes: [64][68] u16 (8704 B each)
#define OFF_S0L 110080
#define OFF_S1H 118784
#define OFF_S1L 127488
#define OFF_HB  136192     // HB: [64][66] u32 (16896 B)
#define OFF_BG  153088
#define OFF_BC  154112
#define OFF_CTL 154624
#define SMEM_SZ 154640

#define RSS 68             // S plane row stride (u16)
#define RSHB 66            // HB row stride (u32)

// swizzled term element index (u32 units)
#define TA(node, feat) ((node) * 132 + ((feat) ^ ((((node) >> 3) & 7) << 3)))

typedef __attribute__((ext_vector_type(4))) short s4v;
typedef __attribute__((ext_vector_type(8))) short s8v;
typedef __attribute__((ext_vector_type(4))) float f4v;

#define MFMA16(a, b, c) __builtin_amdgcn_mfma_f32_16x16x32_bf16((a), (b), (c), 0, 0, 0)

__device__ __forceinline__ float dcr_b2f(unsigned short x) {
  return __uint_as_float(((unsigned)x) << 16);
}
__device__ __forceinline__ unsigned short dcr_f2b(float x) {
  unsigned u = __float_as_uint(x);
  u += 0x7fffu + ((u >> 16) & 1u);
  return (unsigned short)(u >> 16);
}
__device__ __forceinline__ unsigned dcr_pack(float v) {
  unsigned short hh = dcr_f2b(v);
  unsigned short hl = dcr_f2b(v - dcr_b2f(hh));
  return ((unsigned)hl << 16) | (unsigned)hh;
}
__device__ __forceinline__ float dcr_rdw(unsigned w) {
  return dcr_b2f((unsigned short)w) + dcr_b2f((unsigned short)(w >> 16));
}
__device__ __forceinline__ float dcr_ld(const void* p, int idx, int isf) {
  if (isf) return ((const float*)p)[idx];
  return dcr_b2f(((const unsigned short*)p)[idx]);
}
__device__ __forceinline__ float dcr_sigm(float x) {
  return 1.0f / (1.0f + __expf(-x));
}
__device__ __forceinline__ float dcr_tanh(float x) {
  return 2.0f / (1.0f + __expf(-2.0f * x)) - 1.0f;
}
__device__ __forceinline__ s8v dcr_ld8(const unsigned short* p) {
  s8v r;
  *(s4v*)&r = *(const s4v*)p;
  *((s4v*)&r + 1) = *(const s4v*)(p + 4);
  return r;
}

// read 8 interleaved term elements (feats kb..kb+7 of one node) -> ah/al
#define UNPACK8(AH, AL, TP, NODE, KB)                                      \
  {                                                                        \
    const int a0_ = TA(NODE, KB);                                          \
    uint4 q0_ = *(const uint4*)((TP) + a0_);                               \
    uint4 q1_ = *(const uint4*)((TP) + a0_ + 4);                           \
    AH[0] = (short)(q0_.x); AL[0] = (short)(q0_.x >> 16);                  \
    AH[1] = (short)(q0_.y); AL[1] = (short)(q0_.y >> 16);                  \
    AH[2] = (short)(q0_.z); AL[2] = (short)(q0_.z >> 16);                  \
    AH[3] = (short)(q0_.w); AL[3] = (short)(q0_.w >> 16);                  \
    AH[4] = (short)(q1_.x); AL[4] = (short)(q1_.x >> 16);                  \
    AH[5] = (short)(q1_.y); AL[5] = (short)(q1_.y >> 16);                  \
    AH[6] = (short)(q1_.z); AL[6] = (short)(q1_.z >> 16);                  \
    AH[7] = (short)(q1_.w); AL[7] = (short)(q1_.w >> 16);                  \
  }

// ---------------- weight repack: W[(f*5+m)][col] -> fragment order -----------
// gate (per layer,plane): e = (((m*8+nt)*4+ks)*64+lane)*8 + j
// cand (per layer,plane): e = (((m*4+nt)*4+ks)*64+lane)*8 + j
// element = W[(ks*32 + ((lane>>4)&3)*8 + j)*5 + m][nt*16 + (lane&15)]
__global__ void dcr_repack(const void* wg0, const void* wc0,
                           const void* wg1, const void* wc1,
                           const void* s0, unsigned short* o) {
  __shared__ int sisf;
  if (threadIdx.x == 0) {
    const unsigned short* ss = (const unsigned short*)s0;
    int hits = 0;
    for (int i = 0; i < 32; ++i) {
      unsigned hb = ((unsigned)ss[2 * i] >> 8) & 0xFFu;
      if (hb >= 0x30u && hb <= 0x3Fu) ++hits;
    }
    sisf = (hits < 16) ? 1 : 0;
  }
  __syncthreads();
  const int isf = sisf;
  const int NT = 4 * GN + 4 * CN;
  for (int e = blockIdx.x * blockDim.x + threadIdx.x; e < NT;
       e += gridDim.x * blockDim.x) {
    const void* W;
    int pl, ee, ncol, m, nt, ks, lane, j;
    if (e < 4 * GN) {
      int li = e / (2 * GN);
      int rem = e - li * 2 * GN;
      pl = rem / GN;
      ee = rem - pl * GN;
      W = li ? wg1 : wg0;
      ncol = 128;
      j = ee & 7; lane = (ee >> 3) & 63; ks = (ee >> 9) & 3;
      nt = (ee >> 11) & 7; m = ee >> 14;
    } else {
      int c = e - 4 * GN;
      int li = c / (2 * CN);
      int rem = c - li * 2 * CN;
      pl = rem / CN;
      ee = rem - pl * CN;
      W = li ? wc1 : wc0;
      ncol = 64;
      j = ee & 7; lane = (ee >> 3) & 63; ks = (ee >> 9) & 3;
      nt = (ee >> 11) & 3; m = ee >> 13;
    }
    if (pl == 1 && !isf) continue;
    const int f = ks * 32 + ((lane >> 4) & 3) * 8 + j;
    const int col = nt * 16 + (lane & 15);
    const int si = (f * 5 + m) * ncol + col;
    unsigned short v;
    if (!isf) {
      v = ((const unsigned short*)W)[si];
    } else {
      float w = ((const float*)W)[si];
      unsigned short hh = dcr_f2b(w);
      v = (pl == 0) ? hh : dcr_f2b(w - dcr_b2f(hh));
    }
    o[e] = v;
  }
}

// ---------------- MFMA building blocks --------------------------------------
// gate proj one m-term: wave w (0..3) owns 2 N-tiles (cols w*32..w*32+31),
// M-tiles 0..3. Term A read ONCE per (ks,mt), shared by both N-tiles.
__device__ __forceinline__ void dcr_gp(
    f4v& A0, f4v& A1, f4v& A2, f4v& A3,
    f4v& A4, f4v& A5, f4v& A6, f4v& A7,
    const unsigned* T, const unsigned short* rph, const unsigned short* rpl,
    int m, int w, int lane, int wlo) {
  const int ln15 = lane & 15;
  const int k8 = ((lane >> 4) & 3) * 8;
#pragma unroll
  for (int ks = 0; ks < 4; ++ks) {
    const int fo0 = (((m * 8 + w * 2 + 0) * 4 + ks) * 64 + lane) * 8;
    const int fo1 = (((m * 8 + w * 2 + 1) * 4 + ks) * 64 + lane) * 8;
    s8v bh0 = dcr_ld8(rph + fo0);
    s8v bh1 = dcr_ld8(rph + fo1);
    s8v bl0, bl1;
    if (wlo) { bl0 = dcr_ld8(rpl + fo0); bl1 = dcr_ld8(rpl + fo1); }
    const int kb = ks * 32 + k8;
#define DCR_GPM(AX, AY, MT)                                                \
    {                                                                      \
      const int node = (MT) * 16 + ln15;                                   \
      s8v ah, al;                                                          \
      UNPACK8(ah, al, T, node, kb)                                         \
      AX = MFMA16(ah, bh0, AX);                                            \
      AX = MFMA16(al, bh0, AX);                                            \
      if (wlo) AX = MFMA16(ah, bl0, AX);                                   \
      AY = MFMA16(ah, bh1, AY);                                            \
      AY = MFMA16(al, bh1, AY);                                            \
      if (wlo) AY = MFMA16(ah, bl1, AY);                                   \
    }
    DCR_GPM(A0, A4, 0)
    DCR_GPM(A1, A5, 1)
    DCR_GPM(A2, A6, 2)
    DCR_GPM(A3, A7, 3)
#undef DCR_GPM
  }
}

// cand proj one m-term: wave w4 (0..3) owns cand N-tile w4. pass 0 = x-half
// (abs ks 0..1), pass 1 = rh-half (abs ks 2..3, 64-wide rh term).
__device__ __forceinline__ void dcr_cp(f4v& A0, f4v& A1, f4v& A2, f4v& A3,
                                       const unsigned* T,
                                       const unsigned short* rph,
                                       const unsigned short* rpl,
                                       int m, int w4, int lane, int wlo,
                                       int pass) {
  const int ln15 = lane & 15;
  const int k8 = ((lane >> 4) & 3) * 8;
#pragma unroll
  for (int ks2 = 0; ks2 < 2; ++ks2) {
    const int ks = pass * 2 + ks2;
    const int fo = (((m * 4 + w4) * 4 + ks) * 64 + lane) * 8;
    s8v bh = dcr_ld8(rph + fo);
    s8v bl;
    if (wlo) bl = dcr_ld8(rpl + fo);
    const int kb = ks2 * 32 + k8;
#define DCR_CPM(AX, MT)                                                    \
    {                                                                      \
      const int node = (MT) * 16 + ln15;                                   \
      s8v ah, al;                                                          \
      UNPACK8(ah, al, T, node, kb)                                         \
      AX = MFMA16(ah, bh, AX);                                             \
      AX = MFMA16(al, bh, AX);                                             \
      if (wlo) AX = MFMA16(ah, bl, AX);                                    \
    }
    DCR_CPM(A0, 0)
    DCR_CPM(A1, 1)
    DCR_CPM(A2, 2)
    DCR_CPM(A3, 3)
#undef DCR_CPM
  }
}

// apply: Y = S @ X. A = S [out][in] (b128, u16 planes, stride RSS=68),
// B = X (interleaved u32 gathers from term, one b32 per element),
// cheb via C-init = -init/2 and 2x writeback. Named accumulators.
#define DCR_API(ACX, NT)                                                   \
  {                                                                        \
    if (ih_) {                                                             \
      _Pragma("unroll") for (int r = 0; r < 4; ++r)                        \
        ACX[r] = -0.5f * dcr_rdw(ih_[TA(orow + rq + r, (NT) * 16 + ln15)]);\
    } else {                                                               \
      ACX[0] = 0.0f; ACX[1] = 0.0f; ACX[2] = 0.0f; ACX[3] = 0.0f;          \
    }                                                                      \
  }
#define DCR_APM(ACX, NT)                                                   \
  {                                                                        \
    s8v bh, b2;                                                            \
    _Pragma("unroll") for (int j = 0; j < 8; ++j) {                        \
      const unsigned w_ = src[TA(kb + j, (NT) * 16 + ln15)];               \
      bh[j] = (short)w_;                                                   \
      b2[j] = (short)(w_ >> 16);                                           \
    }                                                                      \
    ACX = MFMA16(ah, bh, ACX);                                             \
    ACX = MFMA16(ah, b2, ACX);                                             \
    if (wlo) ACX = MFMA16(al, bh, ACX);                                    \
  }
#define DCR_APS(ACX, NT)                                                   \
  {                                                                        \
    _Pragma("unroll") for (int r = 0; r < 4; ++r)                          \
      dst[TA(orow + rq + r, (NT) * 16 + ln15)] = dcr_pack(fct * ACX[r]);   \
  }

template <int NMT>
__device__ __forceinline__ void dcr_ap(const unsigned short* sh_,
                                       const unsigned short* sl_,
                                       const unsigned* src, unsigned* dst,
                                       const unsigned* ih_,
                                       int idx, int lane, int wlo) {
  const int ln15 = lane & 15;
  const int k8 = ((lane >> 4) & 3) * 8;
  const int rq = ((lane >> 4) & 3) * 4;
  const int orow = idx * 16;  // wave's out-node base
  f4v AC0, AC1, AC2, AC3, AC4, AC5, AC6, AC7;
  DCR_API(AC0, 0)
  DCR_API(AC1, 1)
  DCR_API(AC2, 2)
  DCR_API(AC3, 3)
  if constexpr (NMT == 8) {
    DCR_API(AC4, 4)
    DCR_API(AC5, 5)
    DCR_API(AC6, 6)
    DCR_API(AC7, 7)
  }
#pragma unroll
  for (int ks = 0; ks < 2; ++ks) {
    const int kb = ks * 32 + k8;
    s8v ah = dcr_ld8(sh_ + (orow + ln15) * RSS + kb);
    s8v al;
    if (wlo) al = dcr_ld8(sl_ + (orow + ln15) * RSS + kb);
    DCR_APM(AC0, 0)
    DCR_APM(AC1, 1)
    DCR_APM(AC2, 2)
    DCR_APM(AC3, 3)
    if constexpr (NMT == 8) {
      DCR_APM(AC4, 4)
      DCR_APM(AC5, 5)
      DCR_APM(AC6, 6)
      DCR_APM(AC7, 7)
    }
  }
  const float fct = ih_ ? 2.0f : 1.0f;
  DCR_APS(AC0, 0)
  DCR_APS(AC1, 1)
  DCR_APS(AC2, 2)
  DCR_APS(AC3, 3)
  if constexpr (NMT == 8) {
    DCR_APS(AC4, 4)
    DCR_APS(AC5, 5)
    DCR_APS(AC6, 6)
    DCR_APS(AC7, 7)
  }
}

// ---------------- one DCGRU layer step (compile-time L) ---------------------
template <int L>
__device__ __forceinline__ void dcr_layer(
    f4v& hA0, f4v& hA1, f4v& hA2, f4v& hA3,
    f4v& hB0, f4v& hB1, f4v& hB2, f4v& hB3,
    const void* xseq, int b, int t, int isf, int wlo,
    const unsigned short* rp,
    unsigned* T0, unsigned* T1, unsigned* T2,
    const unsigned short* S0h, const unsigned short* S0l,
    const unsigned short* S1h, const unsigned short* S1l,
    unsigned* HB, const float* BG, const float* BC,
    int tid, int lane, int wid) {
  const int ln15 = lane & 15;
  const int rq = ((lane >> 4) & 3) * 4;
  const unsigned short* rpgh = rp + (L * 2 + 0) * GN;
  const unsigned short* rpgl = rp + (L * 2 + 1) * GN;
  const unsigned short* rpch = rp + 4 * GN + (L * 2 + 0) * CN;
  const unsigned short* rpcl = rp + 4 * GN + (L * 2 + 1) * CN;

  f4v A0 = {0.0f, 0.0f, 0.0f, 0.0f}, A1 = A0, A2 = A0, A3 = A0;
  f4v A4 = A0, A5 = A0, A6 = A0, A7 = A0;

  // ---------------- P0: build cat = [x | h] in T0, h copy in HB ------------
  if constexpr (L == 0) {
    if (wid < 8) {
      const int n = tid >> 3;
      const int f0 = (tid & 7) * 8;
      const int xo = (b * 96 + t) * 4096 + n * 64 + f0;
      const int base = TA(n, f0);
      uint4 q0, q1;
      if (isf) {
        const float* xp = (const float*)xseq + xo;
        q0.x = dcr_pack(xp[0]); q0.y = dcr_pack(xp[1]);
        q0.z = dcr_pack(xp[2]); q0.w = dcr_pack(xp[3]);
        q1.x = dcr_pack(xp[4]); q1.y = dcr_pack(xp[5]);
        q1.z = dcr_pack(xp[6]); q1.w = dcr_pack(xp[7]);
      } else {
        const unsigned short* xp = (const unsigned short*)xseq + xo;
        s8v v = *(const s8v*)xp;
        q0.x = (unsigned)(unsigned short)v[0];
        q0.y = (unsigned)(unsigned short)v[1];
        q0.z = (unsigned)(unsigned short)v[2];
        q0.w = (unsigned)(unsigned short)v[3];
        q1.x = (unsigned)(unsigned short)v[4];
        q1.y = (unsigned)(unsigned short)v[5];
        q1.z = (unsigned)(unsigned short)v[6];
        q1.w = (unsigned)(unsigned short)v[7];
      }
      *(uint4*)(T0 + base) = q0;
      *(uint4*)(T0 + base + 4) = q1;
    } else if (wid < 12) {
      const int f = (wid - 8) * 16 + ln15;
#define DCR_ST0(HX, MT)                                                    \
      { _Pragma("unroll") for (int r = 0; r < 4; ++r) {                    \
          const int node = (MT) * 16 + rq + r;                             \
          const unsigned pw = dcr_pack(HX[r]);                             \
          T0[TA(node, 64 + f)] = pw;                                       \
          HB[node * RSHB + f] = pw; } }
      DCR_ST0(hA0, 0)
      DCR_ST0(hA1, 1)
      DCR_ST0(hA2, 2)
      DCR_ST0(hA3, 3)
#undef DCR_ST0
    }
  } else {
    if (wid >= 8 && wid < 12) {
      const int f = (wid - 8) * 16 + ln15;
#define DCR_ST1(HAX, HBX, MT)                                              \
      { _Pragma("unroll") for (int r = 0; r < 4; ++r) {                    \
          const int node = (MT) * 16 + rq + r;                             \
          T0[TA(node, f)] = dcr_pack(HAX[r]);                              \
          const unsigned pw = dcr_pack(HBX[r]);                            \
          T0[TA(node, 64 + f)] = pw;                                       \
          HB[node * RSHB + f] = pw; } }
      DCR_ST1(hA0, hB0, 0)
      DCR_ST1(hA1, hB1, 1)
      DCR_ST1(hA2, hB2, 2)
      DCR_ST1(hA3, hB3, 3)
#undef DCR_ST1
    }
  }
  __syncthreads();

  // ---------------- gate pass: pm0..pm3 ------------------------------------
  if (wid < 4) dcr_gp(A0, A1, A2, A3, A4, A5, A6, A7, T0, rpgh, rpgl, 0, wid, lane, wlo);
  else if (wid >= 8 && wid < 12) dcr_cp(A0, A1, A2, A3, T0, rpch, rpcl, 0, wid - 8, lane, wlo, 0);
  else if (wid >= 12) dcr_ap<8>(S0h, S0l, T0, T1, nullptr, wid - 12, lane, wlo);
  __syncthreads();
  if (wid < 4) dcr_gp(A0, A1, A2, A3, A4, A5, A6, A7, T1, rpgh, rpgl, 1, wid, lane, wlo);
  else if (wid >= 8 && wid < 12) dcr_cp(A0, A1, A2, A3, T1, rpch, rpcl, 1, wid - 8, lane, wlo, 0);
  else if (wid >= 12) dcr_ap<8>(S0h, S0l, T1, T2, T0, wid - 12, lane, wlo);
  __syncthreads();
  if (wid < 4) dcr_gp(A0, A1, A2, A3, A4, A5, A6, A7, T2, rpgh, rpgl, 2, wid, lane, wlo);
  else if (wid >= 8 && wid < 12) dcr_cp(A0, A1, A2, A3, T2, rpch, rpcl, 2, wid - 8, lane, wlo, 0);
  else if (wid >= 12) dcr_ap<8>(S1h, S1l, T1, T0, nullptr, wid - 12, lane, wlo);
  __syncthreads();
  if (wid < 4) dcr_gp(A0, A1, A2, A3, A4, A5, A6, A7, T0, rpgh, rpgl, 3, wid, lane, wlo);
  else if (wid >= 8 && wid < 12) dcr_cp(A0, A1, A2, A3, T0, rpch, rpcl, 3, wid - 8, lane, wlo, 0);
  else if (wid >= 12) dcr_ap<8>(S1h, S1l, T0, T2, T1, wid - 12, lane, wlo);
  __syncthreads();

  // ---------------- pm4: proj(m4) + gate finish (merged) -------------------
  if (wid < 4) {
    dcr_gp(A0, A1, A2, A3, A4, A5, A6, A7, T2, rpgh, rpgl, 4, wid, lane, wlo);
    const int g0 = wid * 32 + ln15;
    const float bg0v = BG[L * 128 + g0];
    const float bg1v = BG[L * 128 + g0 + 16];
#define DCR_GF(AX, AY, MT)                                                 \
    { _Pragma("unroll") for (int r = 0; r < 4; ++r) {                      \
        const int node = (MT) * 16 + rq + r;                               \
        const float s0_ = dcr_sigm(AX[r] + bg0v);                          \
        const float s1_ = dcr_sigm(AY[r] + bg1v);                          \
        if (wid < 2) {                                                     \
          const float h0_ = dcr_rdw(HB[node * RSHB + g0]);                 \
          const float h1_ = dcr_rdw(HB[node * RSHB + g0 + 16]);            \
          T0[TA(node, g0)] = dcr_pack(s0_ * h0_);                          \
          T0[TA(node, g0 + 16)] = dcr_pack(s1_ * h1_);                     \
        } else {                                                           \
          T1[TA(node, g0)] = dcr_pack(s0_);                                \
          T1[TA(node, g0 + 16)] = dcr_pack(s1_);                           \
        } } }
    DCR_GF(A0, A4, 0)
    DCR_GF(A1, A5, 1)
    DCR_GF(A2, A6, 2)
    DCR_GF(A3, A7, 3)
#undef DCR_GF
  } else if (wid >= 8 && wid < 12) {
    dcr_cp(A0, A1, A2, A3, T2, rpch, rpcl, 4, wid - 8, lane, wlo, 0);
  }
  __syncthreads();

  // ---------------- rh pass: pr0..pr3 (64-wide) ----------------------------
  if (wid >= 8 && wid < 12) dcr_cp(A0, A1, A2, A3, T0, rpch, rpcl, 0, wid - 8, lane, wlo, 1);
  else if (wid >= 12) dcr_ap<4>(S0h, S0l, T0, T1, nullptr, wid - 12, lane, wlo);
  __syncthreads();
  if (wid >= 8 && wid < 12) dcr_cp(A0, A1, A2, A3, T1, rpch, rpcl, 1, wid - 8, lane, wlo, 1);
  else if (wid >= 12) dcr_ap<4>(S0h, S0l, T1, T2, T0, wid - 12, lane, wlo);
  __syncthreads();
  if (wid >= 8 && wid < 12) dcr_cp(A0, A1, A2, A3, T2, rpch, rpcl, 2, wid - 8, lane, wlo, 1);
  else if (wid >= 12) dcr_ap<4>(S1h, S1l, T1, T0, nullptr, wid - 12, lane, wlo);
  __syncthreads();
  if (wid >= 8 && wid < 12) dcr_cp(A0, A1, A2, A3, T0, rpch, rpcl, 3, wid - 8, lane, wlo, 1);
  else if (wid >= 12) dcr_ap<4>(S1h, S1l, T0, T1, T1, wid - 12, lane, wlo);
  __syncthreads();

  // ---------------- pr4: cp(m4') + cand finish (merged) --------------------
  if (wid >= 8 && wid < 12) {
    dcr_cp(A0, A1, A2, A3, T1, rpch, rpcl, 4, wid - 8, lane, wlo, 1);
    const int f = (wid - 8) * 16 + ln15;
    const float bcv = BC[L * 64 + f];
#define DCR_CF(AX, HX, MT)                                                 \
    { _Pragma("unroll") for (int r = 0; r < 4; ++r) {                      \
        const int node = (MT) * 16 + rq + r;                               \
        const float c = dcr_tanh(AX[r] + bcv);                             \
        const float u = dcr_rdw(T1[TA(node, 64 + f)]);                     \
        HX[r] = u * HX[r] + (1.0f - u) * c; } }
    if constexpr (L == 0) {
      DCR_CF(A0, hA0, 0)
      DCR_CF(A1, hA1, 1)
      DCR_CF(A2, hA2, 2)
      DCR_CF(A3, hA3, 3)
    } else {
      DCR_CF(A0, hB0, 0)
      DCR_CF(A1, hB1, 1)
      DCR_CF(A2, hB2, 2)
      DCR_CF(A3, hB3, 3)
    }
#undef DCR_CF
  }
  __syncthreads();
}

// ---------------- main MFMA kernel ------------------------------------------
__global__ __launch_bounds__(1024)
__attribute__((amdgpu_waves_per_eu(4, 4)))
void dcr_mfma(
    const void* xseq, const void* s0, const void* s1,
    const void* bg0, const void* bg1,
    const void* p64a, const void* p64b, const void* p64c,
    const void* fcw, const void* fcb, const void* idw, const void* idb,
    const unsigned short* rp, void* outp) {
  extern __shared__ char sm[];
  unsigned* const T0 = (unsigned*)(sm + OFF_T0);
  unsigned* const T1 = (unsigned*)(sm + OFF_T1);
  unsigned* const T2 = (unsigned*)(sm + OFF_T2);
  unsigned short* const S0h = (unsigned short*)(sm + OFF_S0H);
  unsigned short* const S0l = (unsigned short*)(sm + OFF_S0L);
  unsigned short* const S1h = (unsigned short*)(sm + OFF_S1H);
  unsigned short* const S1l = (unsigned short*)(sm + OFF_S1L);
  unsigned* const HB = (unsigned*)(sm + OFF_HB);
  float* const BG = (float*)(sm + OFF_BG);
  float* const BC = (float*)(sm + OFF_BC);
  int* const ctl = (int*)(sm + OFF_CTL);

  const int tid = threadIdx.x;
  const int b = blockIdx.x;
  const int lane = tid & 63;
  const int wid = tid >> 6;

  // ---- on-device identification ----
  if (tid == 0) {
    const unsigned short* ss = (const unsigned short*)s0;
    int hits = 0;
    for (int i = 0; i < 32; ++i) {
      unsigned hb = ((unsigned)ss[2 * i] >> 8) & 0xFFu;
      if (hb >= 0x30u && hb <= 0x3Fu) ++hits;
    }
    int isf_ = (hits < 16) ? 1 : 0;
    int sel = 0;
    {
      const unsigned* w = (const unsigned*)p64a;
      unsigned any = 0;
      for (int i = 0; i < 16; ++i) any |= w[i];
      if (!any) {
        sel = 1;
        const unsigned* w1 = (const unsigned*)p64b;
        unsigned any1 = 0;
        for (int i = 0; i < 16; ++i) any1 |= w1[i];
        if (!any1) sel = 2;
      }
    }
    const unsigned* w =
        (const unsigned*)(sel == 0 ? p64a : (sel == 1 ? p64b : p64c));
    int i64 = 1;
    for (int i = 0; i < 8; ++i)
      if (w[2 * i + 1] != 0u) i64 = 0;
    ctl[0] = isf_;
    ctl[1] = sel;
    ctl[2] = i64;
  }
  __syncthreads();
  const int isf = ctl[0];
  const int sel = ctl[1];
  const int i64 = ctl[2];
  const int wlo = isf;  // lo planes of S/W meaningful only for fp32 inputs
  const void* seqp = (sel == 0) ? p64a : (sel == 1 ? p64b : p64c);
  const void* bcA = (sel == 0) ? p64b : p64a;
  const void* bcB = (sel == 2) ? p64b : p64c;

  // ---- stage supports (hi/lo u16, stride RSS) and biases ----
  for (int i = 0; i < 4; ++i) {
    const int flat = i * 1024 + tid;  // = out*64 + in
    const int out = flat >> 6, in = flat & 63;
    float v0, v1;
    if (isf) {
      v0 = ((const float*)s0)[flat];
      v1 = ((const float*)s1)[flat];
    } else {
      v0 = dcr_b2f(((const unsigned short*)s0)[flat]);
      v1 = dcr_b2f(((const unsigned short*)s1)[flat]);
    }
    unsigned short hh = dcr_f2b(v0);
    S0h[out * RSS + in] = hh;
    S0l[out * RSS + in] = dcr_f2b(v0 - dcr_b2f(hh));
    hh = dcr_f2b(v1);
    S1h[out * RSS + in] = hh;
    S1l[out * RSS + in] = dcr_f2b(v1 - dcr_b2f(hh));
  }
  if (tid < 128) {
    BG[tid] = dcr_ld(bg0, tid, isf);
    BG[128 + tid] = dcr_ld(bg1, tid, isf);
  } else if (tid < 192) {
    const int j = tid - 128;
    BC[j] = dcr_ld(bcA, j, isf);
    BC[64 + j] = dcr_ld(bcB, j, isf);
  }

  int tl_;
  if (i64) tl_ = (int)((const long long*)seqp)[b] - 1;
  else     tl_ = ((const int*)seqp)[b] - 1;
  if (tl_ < 0) tl_ = 0;
  if (tl_ > 95) tl_ = 95;

  f4v hA0 = {0.0f, 0.0f, 0.0f, 0.0f}, hA1 = hA0, hA2 = hA0, hA3 = hA0;
  f4v hB0 = hA0, hB1 = hA0, hB2 = hA0, hB3 = hA0;
  __syncthreads();

  for (int t = 0; t < 96; ++t) {
    dcr_layer<0>(hA0, hA1, hA2, hA3, hB0, hB1, hB2, hB3,
                 xseq, b, t, isf, wlo, rp, T0, T1, T2,
                 S0h, S0l, S1h, S1l, HB, BG, BC, tid, lane, wid);
    dcr_layer<1>(hA0, hA1, hA2, hA3, hB0, hB1, hB2, hB3,
                 xseq, b, t, isf, wlo, rp, T0, T1, T2,
                 S0h, S0l, S1h, S1l, HB, BG, BC, tid, lane, wid);
    if (t == tl_) break;
  }

  // ---------------- heads: relu(h1) -> fc/id matmul -> max over nodes -------
  __syncthreads();
  const int ln15 = lane & 15;
  const int rq = ((lane >> 4) & 3) * 4;
  float* const hx = (float*)(sm + OFF_T0);   // [64][66]
  float* const hw = (float*)(sm + OFF_T1);   // [64][56]
  float* const red = (float*)(sm + OFF_T2);  // [16][54]
  if (wid >= 8 && wid < 12) {
    const int f = (wid - 8) * 16 + ln15;
#define DCR_HX(HX, MT)                                                     \
    { _Pragma("unroll") for (int r = 0; r < 4; ++r) {                      \
        const int node = (MT) * 16 + rq + r;                               \
        hx[node * 66 + f] = fmaxf(HX[r], 0.0f); } }
    DCR_HX(hB0, 0)
    DCR_HX(hB1, 1)
    DCR_HX(hB2, 2)
    DCR_HX(hB3, 3)
#undef DCR_HX
  }
  {
    const int u = tid >> 4;
    for (int c = (tid & 15); c < 54; c += 16)
      hw[u * 56 + c] = (c < 4) ? dcr_ld(fcw, u * 4 + c, isf)
                               : dcr_ld(idw, u * 50 + (c - 4), isf);
  }
  __syncthreads();
  if (tid < 864) {
    const int c = tid % 54, nb = tid / 54;
    float mx = -3.4e38f;
    for (int nn = nb * 4; nn < nb * 4 + 4; ++nn) {
      float s = 0.0f;
#pragma unroll 8
      for (int uu = 0; uu < 64; ++uu) s += hx[nn * 66 + uu] * hw[uu * 56 + c];
      mx = fmaxf(mx, s);
    }
    red[nb * 54 + c] = mx;
  }
  __syncthreads();
  if (tid < 54) {
    float mx = red[tid];
#pragma unroll
    for (int g = 1; g < 16; ++g) mx = fmaxf(mx, red[g * 54 + tid]);
    mx += (tid < 4) ? dcr_ld(fcb, tid, isf) : dcr_ld(idb, tid - 4, isf);
    const int o = (tid < 4) ? (b * 4 + tid) : (256 + b * 50 + (tid - 4));
    if (isf) ((float*)outp)[o] = mx;
    else     ((unsigned short*)outp)[o] = dcr_f2b(mx);
  }
}

// ============================================================================
// Fallback: proven scalar kernel (round-1, 1024 threads) for ws-too-small.
// ============================================================================
__device__ void dcr_proj(float* aG, float* aC, const float (*buf)[68],
                         const void* Wg, const void* Wc, int m, int fh,
                         int n, int fb, int doG, int doC, int isf) {
  if (!isf) {
    const unsigned* G = (const unsigned*)Wg;
    const unsigned* C = (const unsigned*)Wc;
    const int fd = fb >> 1;
#pragma unroll 4
    for (int k = 0; k < 64; ++k) {
      float xk = buf[n][k];
      int row = (fh + k) * 5 + m;
      if (doG) {
        const unsigned* wr = G + row * 64 + fd;
        unsigned p0 = wr[0], p1 = wr[1], p2 = wr[32], p3 = wr[33];
        aG[0] += xk * __uint_as_float(p0 << 16);
        aG[1] += xk * __uint_as_float(p0 & 0xFFFF0000u);
        aG[2] += xk * __uint_as_float(p1 << 16);
        aG[3] += xk * __uint_as_float(p1 & 0xFFFF0000u);
        aG[4] += xk * __uint_as_float(p2 << 16);
        aG[5] += xk * __uint_as_float(p2 & 0xFFFF0000u);
        aG[6] += xk * __uint_as_float(p3 << 16);
        aG[7] += xk * __uint_as_float(p3 & 0xFFFF0000u);
      }
      if (doC) {
        const unsigned* wr = C + row * 32 + fd;
        unsigned p0 = wr[0], p1 = wr[1];
        aC[0] += xk * __uint_as_float(p0 << 16);
        aC[1] += xk * __uint_as_float(p0 & 0xFFFF0000u);
        aC[2] += xk * __uint_as_float(p1 << 16);
        aC[3] += xk * __uint_as_float(p1 & 0xFFFF0000u);
      }
    }
  } else {
    const float* G = (const float*)Wg;
    const float* C = (const float*)Wc;
#pragma unroll 4
    for (int k = 0; k < 64; ++k) {
      float xk = buf[n][k];
      int row = (fh + k) * 5 + m;
      if (doG) {
        const float* wr = G + row * 128 + fb;
#pragma unroll
        for (int j = 0; j < 4; ++j) {
          aG[j] += xk * wr[j];
          aG[4 + j] += xk * wr[64 + j];
        }
      }
      if (doC) {
        const float* wr = C + row * 64 + fb;
#pragma unroll
        for (int j = 0; j < 4; ++j) aC[j] += xk * wr[j];
      }
    }
  }
}

__device__ void dcr_apply(float (*dst)[68], const float (*src)[68],
                          const unsigned short (*sS)[65], int n, int fb,
                          int cheb) {
  float a0 = 0.0f, a1 = 0.0f, a2 = 0.0f, a3 = 0.0f;
#pragma unroll 8
  for (int m = 0; m < 64; ++m) {
    float s = dcr_b2f(sS[n][m]);
    float4 v = *(const float4*)(&src[m][fb]);
    a0 += s * v.x;
    a1 += s * v.y;
    a2 += s * v.z;
    a3 += s * v.w;
  }
  if (cheb) {
    dst[n][fb + 0] = 2.0f * a0 - dst[n][fb + 0];
    dst[n][fb + 1] = 2.0f * a1 - dst[n][fb + 1];
    dst[n][fb + 2] = 2.0f * a2 - dst[n][fb + 2];
    dst[n][fb + 3] = 2.0f * a3 - dst[n][fb + 3];
  } else {
    dst[n][fb + 0] = a0;
    dst[n][fb + 1] = a1;
    dst[n][fb + 2] = a2;
    dst[n][fb + 3] = a3;
  }
}

__device__ void dcr_half(float* aG, float* aC, const void* Wg, const void* Wc,
                         int fh, int doG, int doC, float (*xa)[68],
                         float (*xb)[68], const unsigned short (*sS0)[65],
                         const unsigned short (*sS1)[65], int n, int fb,
                         int isf) {
  dcr_proj(aG, aC, xa, Wg, Wc, 0, fh, n, fb, doG, doC, isf);
  dcr_apply(xb, xa, sS0, n, fb, 0);
  __syncthreads();
  dcr_proj(aG, aC, xb, Wg, Wc, 1, fh, n, fb, doG, doC, isf);
  dcr_apply(xa, xb, sS0, n, fb, 1);
  __syncthreads();
  dcr_proj(aG, aC, xa, Wg, Wc, 2, fh, n, fb, doG, doC, isf);
  __syncthreads();
  dcr_apply(xa, xb, sS1, n, fb, 0);
  __syncthreads();
  dcr_proj(aG, aC, xa, Wg, Wc, 3, fh, n, fb, doG, doC, isf);
  dcr_apply(xb, xa, sS1, n, fb, 1);
  __syncthreads();
  dcr_proj(aG, aC, xb, Wg, Wc, 4, fh, n, fb, doG, doC, isf);
  __syncthreads();
}

__global__ __launch_bounds__(1024) void dcr_scalar(
    const void* xseq, const void* s0, const void* s1, const void* wg0,
    const void* wc0, const void* wg1, const void* wc1, const void* bg0,
    const void* bg1, const void* p64a, const void* p64b, const void* p64c,
    const void* fcw, const void* fcb, const void* idw, const void* idb,
    void* outp) {
  __shared__ float xa[64][68];
  __shared__ float xb[64][68];
  __shared__ unsigned short sS[2][64][65];
  __shared__ float bGs[2][128];
  __shared__ float bCs[2][64];
  __shared__ float red[16][54];
  __shared__ int ctl[4];

  const int tid = threadIdx.x;
  const int b = blockIdx.x;
  const int n = tid >> 4;
  const int fb = (tid & 15) * 4;

  if (tid == 0) {
    const unsigned short* ss = (const unsigned short*)s0;
    int hits = 0;
    for (int i = 0; i < 32; ++i) {
      unsigned hb = ((unsigned)ss[2 * i] >> 8) & 0xFFu;
      if (hb >= 0x30u && hb <= 0x3Fu) ++hits;
    }
    int isf = (hits < 16) ? 1 : 0;
    int sel = 0;
    {
      const unsigned* w = (const unsigned*)p64a;
      unsigned any = 0;
      for (int i = 0; i < 16; ++i) any |= w[i];
      if (!any) {
        sel = 1;
        const unsigned* w1 = (const unsigned*)p64b;
        unsigned any1 = 0;
        for (int i = 0; i < 16; ++i) any1 |= w1[i];
        if (!any1) sel = 2;
      }
    }
    const unsigned* w =
        (const unsigned*)(sel == 0 ? p64a : (sel == 1 ? p64b : p64c));
    int i64 = 1;
    for (int i = 0; i < 8; ++i)
      if (w[2 * i + 1] != 0u) i64 = 0;
    ctl[0] = isf;
    ctl[1] = sel;
    ctl[2] = i64;
  }
  __syncthreads();
  const int isf = ctl[0];
  const int sel = ctl[1];
  const int i64 = ctl[2];
  const void* seqp = (sel == 0) ? p64a : (sel == 1 ? p64b : p64c);
  const void* bcA = (sel == 0) ? p64b : p64a;
  const void* bcB = (sel == 2) ? p64b : p64c;

  for (int i = 0; i < 4; ++i) {
    int flat = i * 1024 + tid;
    int nn = flat >> 6, mm = flat & 63;
    unsigned short v0, v1;
    if (isf) {
      v0 = dcr_f2b(((const float*)s0)[flat]);
      v1 = dcr_f2b(((const float*)s1)[flat]);
    } else {
      v0 = ((const unsigned short*)s0)[flat];
      v1 = ((const unsigned short*)s1)[flat];
    }
    sS[0][nn][mm] = v0;
    sS[1][nn][mm] = v1;
  }
  if (tid < 128) {
    bGs[0][tid] = dcr_ld(bg0, tid, isf);
    bGs[1][tid] = dcr_ld(bg1, tid, isf);
  } else if (tid < 192) {
    int j = tid - 128;
    bCs[0][j] = dcr_ld(bcA, j, isf);
    bCs[1][j] = dcr_ld(bcB, j, isf);
  }

  int tl;
  if (i64) tl = (int)((const long long*)seqp)[b] - 1;
  else     tl = ((const int*)seqp)[b] - 1;
  if (tl < 0) tl = 0;
  if (tl > 95) tl = 95;

  float h0r[4], h1r[4];
#pragma unroll
  for (int j = 0; j < 4; ++j) {
    h0r[j] = 0.0f;
    h1r[j] = 0.0f;
  }
  __syncthreads();

  for (int t = 0; t < 96; ++t) {
    {
      float aG[8], aC[4];
#pragma unroll
      for (int j = 0; j < 8; ++j) aG[j] = 0.0f;
#pragma unroll
      for (int j = 0; j < 4; ++j) aC[j] = 0.0f;
      int xoff = (b * 96 + t) * 4096 + n * 64 + fb;
#pragma unroll
      for (int j = 0; j < 4; ++j) xa[n][fb + j] = dcr_ld(xseq, xoff + j, isf);
      __syncthreads();
      dcr_half(aG, aC, wg0, wc0, 0, 1, 1, xa, xb, sS[0], sS[1], n, fb, isf);
#pragma unroll
      for (int j = 0; j < 4; ++j) xa[n][fb + j] = h0r[j];
      __syncthreads();
      dcr_half(aG, aC, wg0, wc0, 64, 1, 0, xa, xb, sS[0], sS[1], n, fb, isf);
      float rr[4], uu[4];
#pragma unroll
      for (int j = 0; j < 4; ++j) {
        rr[j] = dcr_sigm(aG[j] + bGs[0][fb + j]);
        uu[j] = dcr_sigm(aG[4 + j] + bGs[0][64 + fb + j]);
      }
#pragma unroll
      for (int j = 0; j < 4; ++j) xa[n][fb + j] = rr[j] * h0r[j];
      __syncthreads();
      dcr_half(aG, aC, wg0, wc0, 64, 0, 1, xa, xb, sS[0], sS[1], n, fb, isf);
#pragma unroll
      for (int j = 0; j < 4; ++j) {
        float c = dcr_tanh(aC[j] + bCs[0][fb + j]);
        h0r[j] = uu[j] * h0r[j] + (1.0f - uu[j]) * c;
      }
    }
    {
      float aG[8], aC[4];
#pragma unroll
      for (int j = 0; j < 8; ++j) aG[j] = 0.0f;
#pragma unroll
      for (int j = 0; j < 4; ++j) aC[j] = 0.0f;
#pragma unroll
      for (int j = 0; j < 4; ++j) xa[n][fb + j] = h0r[j];
      __syncthreads();
      dcr_half(aG, aC, wg1, wc1, 0, 1, 1, xa, xb, sS[0], sS[1], n, fb, isf);
#pragma unroll
      for (int j = 0; j < 4; ++j) xa[n][fb + j] = h1r[j];
      __syncthreads();
      dcr_half(aG, aC, wg1, wc1, 64, 1, 0, xa, xb, sS[0], sS[1], n, fb, isf);
      float rr[4], uu[4];
#pragma unroll
      for (int j = 0; j < 4; ++j) {
        rr[j] = dcr_sigm(aG[j] + bGs[1][fb + j]);
        uu[j] = dcr_sigm(aG[4 + j] + bGs[1][64 + fb + j]);
      }
#pragma unroll
      for (int j = 0; j < 4; ++j) xa[n][fb + j] = rr[j] * h1r[j];
      __syncthreads();
      dcr_half(aG, aC, wg1, wc1, 64, 0, 1, xa, xb, sS[0], sS[1], n, fb, isf);
#pragma unroll
      for (int j = 0; j < 4; ++j) {
        float c = dcr_tanh(aC[j] + bCs[1][fb + j]);
        h1r[j] = uu[j] * h1r[j] + (1.0f - uu[j]) * c;
      }
    }
    if (t == tl) break;
  }

  __syncthreads();
#pragma unroll
  for (int j = 0; j < 4; ++j) xa[n][fb + j] = fmaxf(h1r[j], 0.0f);
  {
    int u = tid >> 4;
    for (int c = (tid & 15); c < 54; c += 16)
      xb[u][c] = (c < 4) ? dcr_ld(fcw, u * 4 + c, isf)
                         : dcr_ld(idw, u * 50 + (c - 4), isf);
  }
  __syncthreads();
  if (tid < 864) {
    int c = tid % 54, nb = tid / 54;
    float mx = -3.4e38f;
    for (int nn = nb * 4; nn < nb * 4 + 4; ++nn) {
      float s = 0.0f;
#pragma unroll 8
      for (int u = 0; u < 64; ++u) s += xa[nn][u] * xb[u][c];
      mx = fmaxf(mx, s);
    }
    red[nb][c] = mx;
  }
  __syncthreads();
  if (tid < 54) {
    float mx = red[0][tid];
#pragma unroll
    for (int g = 1; g < 16; ++g) mx = fmaxf(mx, red[g][tid]);
    mx += (tid < 4) ? dcr_ld(fcb, tid, isf) : dcr_ld(idb, tid - 4, isf);
    int o = (tid < 4) ? (b * 4 + tid) : (256 + b * 50 + (tid - 4));
    if (isf) ((float*)outp)[o] = mx;
    else     ((unsigned short*)outp)[o] = dcr_f2b(mx);
  }
}

// ---------------------------------------------------------------------------
static int dcr_find_nth(const int* s, int n, int sz, int nth) {
  int c = 0;
  for (int i = 0; i < n; ++i)
    if (s[i] == sz) {
      if (c == nth) return i;
      ++c;
    }
  return -1;
}

extern "C" void kernel_launch(void* const* d_in, const int* in_sizes, int n_in,
                              void* d_out, int out_size, void* d_ws,
                              size_t ws_size, hipStream_t stream) {
  (void)out_size;
  int i_seq = dcr_find_nth(in_sizes, n_in, 393216, 0);
  int i_s0 = dcr_find_nth(in_sizes, n_in, 4096, 0);
  int i_s1 = dcr_find_nth(in_sizes, n_in, 4096, 1);
  int i_wg0 = dcr_find_nth(in_sizes, n_in, 81920, 0);
  int i_wg1 = dcr_find_nth(in_sizes, n_in, 81920, 1);
  int i_wc0 = dcr_find_nth(in_sizes, n_in, 40960, 0);
  int i_wc1 = dcr_find_nth(in_sizes, n_in, 40960, 1);
  int i_bg0 = dcr_find_nth(in_sizes, n_in, 128, 0);
  int i_bg1 = dcr_find_nth(in_sizes, n_in, 128, 1);
  int i_64a = dcr_find_nth(in_sizes, n_in, 64, 0);
  int i_64b = dcr_find_nth(in_sizes, n_in, 64, 1);
  int i_64c = dcr_find_nth(in_sizes, n_in, 64, 2);
  int i_fcw = dcr_find_nth(in_sizes, n_in, 256, 0);
  int i_fcb = dcr_find_nth(in_sizes, n_in, 4, 0);
  int i_idw = dcr_find_nth(in_sizes, n_in, 3200, 0);
  int i_idb = dcr_find_nth(in_sizes, n_in, 50, 0);
  if (i_seq < 0 || i_s0 < 0 || i_s1 < 0 || i_wg0 < 0 || i_wg1 < 0 ||
      i_wc0 < 0 || i_wc1 < 0 || i_bg0 < 0 || i_bg1 < 0 || i_64a < 0 ||
      i_64b < 0 || i_64c < 0 || i_fcw < 0 || i_fcb < 0 || i_idw < 0 ||
      i_idb < 0) {
    i_seq = 0;  i_64a = 1;  i_s0 = 2;   i_s1 = 3;
    i_wg0 = 4;  i_bg0 = 5;  i_wc0 = 6;  i_64b = 7;
    i_wg1 = 8;  i_bg1 = 9;  i_wc1 = 10; i_64c = 11;
    i_fcw = 12; i_fcb = 13; i_idw = 14; i_idb = 15;
  }

  if (d_ws == nullptr || ws_size < (size_t)WS_NEED) {
    dcr_scalar<<<dim3(64), dim3(1024), 0, stream>>>(
        d_in[i_seq], d_in[i_s0], d_in[i_s1], d_in[i_wg0], d_in[i_wc0],
        d_in[i_wg1], d_in[i_wc1], d_in[i_bg0], d_in[i_bg1], d_in[i_64a],
        d_in[i_64b], d_in[i_64c], d_in[i_fcw], d_in[i_fcb], d_in[i_idw],
        d_in[i_idb], d_out);
    return;
  }

  dcr_repack<<<dim3(256), dim3(256), 0, stream>>>(
      d_in[i_wg0], d_in[i_wc0], d_in[i_wg1], d_in[i_wc1], d_in[i_s0],
      (unsigned short*)d_ws);

  static bool attr_set = false;
  if (!attr_set) {
    (void)hipFuncSetAttribute((const void*)dcr_mfma,
                              hipFuncAttributeMaxDynamicSharedMemorySize,
                              SMEM_SZ);
    attr_set = true;
  }

  dcr_mfma<<<dim3(64), dim3(1024), SMEM_SZ, stream>>>(
      d_in[i_seq], d_in[i_s0], d_in[i_s1], d_in[i_bg0], d_in[i_bg1],
      d_in[i_64a], d_in[i_64b], d_in[i_64c], d_in[i_fcw], d_in[i_fcb],
      d_in[i_idw], d_in[i_idb], (const unsigned short*)d_ws, d_out);
}

// Round 8
// 10621.442 us; speedup vs baseline: 3.1149x; 1.4441x over previous
//
#include <hip/hip_runtime.h>

// ---------------------------------------------------------------------------
// DCRNN (2-layer DCGRU encoder) -- MFMA round, latency rebalance.
// R7 post-mortem: halving LDS ops left dur flat (15.5->15.3ms) => phases are
// ~90% latency stall, not port-bound. Per SIMD: 1 gate + 1 cand + 1 apply +
// 1 IDLE wave, each a serial LDS->unpack->MFMA chain at 64 VGPR.
// This round:
//   * applies split over 8 waves (waves 4-7 + 12-15; 4 node-tiles x 2
//     feat-halves, wave-uniform nmt0) -> apply critical path halves,
//     apply acc 32->16 VGPR
//   * P0 staging folded into previous pr4 (waves 0-7 stage x_{t+1} while
//     cand runs cp(m4'); cand writes h directly) -> 11->10 barriers/layer
//     and the x global-load latency is buried under compute
//   * dataflow/buffers identical to R7 (absmax 2.4e-4 lineage)
// Roles: wid 0-3 gate(2NT) | 8-11 cand | 4-7 & 12-15 apply halves.
// ---------------------------------------------------------------------------

#define GN 81920           // gate repack elems per (layer,plane)
#define CN 40960           // cand repack elems per (layer,plane)
#define WS_NEED ((4*GN + 4*CN) * 2)

#define OFF_T0  0          // term planes: [64][132] u32 (33792 B each)
#define OFF_T1  33792
#define OFF_T2  67584
#define OFF_S0H 101376     // S planes: [64][68] u16 (8704 B each)
#define OFF_S0L 110080
#define OFF_S1H 118784
#define OFF_S1L 127488
#define OFF_HB  136192     // HB: [64][66] u32 (16896 B)
#define OFF_BG  153088
#define OFF_BC  154112
#define OFF_CTL 154624
#define SMEM_SZ 154640

#define RSS 68             // S plane row stride (u16)
#define RSHB 66            // HB row stride (u32)

// swizzled term element index (u32 units)
#define TA(node, feat) ((node) * 132 + ((feat) ^ ((((node) >> 3) & 7) << 3)))

typedef __attribute__((ext_vector_type(4))) short s4v;
typedef __attribute__((ext_vector_type(8))) short s8v;
typedef __attribute__((ext_vector_type(4))) float f4v;

#define MFMA16(a, b, c) __builtin_amdgcn_mfma_f32_16x16x32_bf16((a), (b), (c), 0, 0, 0)

__device__ __forceinline__ float dcr_b2f(unsigned short x) {
  return __uint_as_float(((unsigned)x) << 16);
}
__device__ __forceinline__ unsigned short dcr_f2b(float x) {
  unsigned u = __float_as_uint(x);
  u += 0x7fffu + ((u >> 16) & 1u);
  return (unsigned short)(u >> 16);
}
__device__ __forceinline__ unsigned dcr_pack(float v) {
  unsigned short hh = dcr_f2b(v);
  unsigned short hl = dcr_f2b(v - dcr_b2f(hh));
  return ((unsigned)hl << 16) | (unsigned)hh;
}
__device__ __forceinline__ float dcr_rdw(unsigned w) {
  return dcr_b2f((unsigned short)w) + dcr_b2f((unsigned short)(w >> 16));
}
__device__ __forceinline__ float dcr_ld(const void* p, int idx, int isf) {
  if (isf) return ((const float*)p)[idx];
  return dcr_b2f(((const unsigned short*)p)[idx]);
}
__device__ __forceinline__ float dcr_sigm(float x) {
  return 1.0f / (1.0f + __expf(-x));
}
__device__ __forceinline__ float dcr_tanh(float x) {
  return 2.0f / (1.0f + __expf(-2.0f * x)) - 1.0f;
}
__device__ __forceinline__ s8v dcr_ld8(const unsigned short* p) {
  s8v r;
  *(s4v*)&r = *(const s4v*)p;
  *((s4v*)&r + 1) = *(const s4v*)(p + 4);
  return r;
}

// read 8 interleaved term elements (feats kb..kb+7 of one node) -> ah/al
#define UNPACK8(AH, AL, TP, NODE, KB)                                      \
  {                                                                        \
    const int a0_ = TA(NODE, KB);                                          \
    uint4 q0_ = *(const uint4*)((TP) + a0_);                               \
    uint4 q1_ = *(const uint4*)((TP) + a0_ + 4);                           \
    AH[0] = (short)(q0_.x); AL[0] = (short)(q0_.x >> 16);                  \
    AH[1] = (short)(q0_.y); AL[1] = (short)(q0_.y >> 16);                  \
    AH[2] = (short)(q0_.z); AL[2] = (short)(q0_.z >> 16);                  \
    AH[3] = (short)(q0_.w); AL[3] = (short)(q0_.w >> 16);                  \
    AH[4] = (short)(q1_.x); AL[4] = (short)(q1_.x >> 16);                  \
    AH[5] = (short)(q1_.y); AL[5] = (short)(q1_.y >> 16);                  \
    AH[6] = (short)(q1_.z); AL[6] = (short)(q1_.z >> 16);                  \
    AH[7] = (short)(q1_.w); AL[7] = (short)(q1_.w >> 16);                  \
  }

// ---------------- weight repack: W[(f*5+m)][col] -> fragment order -----------
__global__ void dcr_repack(const void* wg0, const void* wc0,
                           const void* wg1, const void* wc1,
                           const void* s0, unsigned short* o) {
  __shared__ int sisf;
  if (threadIdx.x == 0) {
    const unsigned short* ss = (const unsigned short*)s0;
    int hits = 0;
    for (int i = 0; i < 32; ++i) {
      unsigned hb = ((unsigned)ss[2 * i] >> 8) & 0xFFu;
      if (hb >= 0x30u && hb <= 0x3Fu) ++hits;
    }
    sisf = (hits < 16) ? 1 : 0;
  }
  __syncthreads();
  const int isf = sisf;
  const int NT = 4 * GN + 4 * CN;
  for (int e = blockIdx.x * blockDim.x + threadIdx.x; e < NT;
       e += gridDim.x * blockDim.x) {
    const void* W;
    int pl, ee, ncol, m, nt, ks, lane, j;
    if (e < 4 * GN) {
      int li = e / (2 * GN);
      int rem = e - li * 2 * GN;
      pl = rem / GN;
      ee = rem - pl * GN;
      W = li ? wg1 : wg0;
      ncol = 128;
      j = ee & 7; lane = (ee >> 3) & 63; ks = (ee >> 9) & 3;
      nt = (ee >> 11) & 7; m = ee >> 14;
    } else {
      int c = e - 4 * GN;
      int li = c / (2 * CN);
      int rem = c - li * 2 * CN;
      pl = rem / CN;
      ee = rem - pl * CN;
      W = li ? wc1 : wc0;
      ncol = 64;
      j = ee & 7; lane = (ee >> 3) & 63; ks = (ee >> 9) & 3;
      nt = (ee >> 11) & 3; m = ee >> 13;
    }
    if (pl == 1 && !isf) continue;
    const int f = ks * 32 + ((lane >> 4) & 3) * 8 + j;
    const int col = nt * 16 + (lane & 15);
    const int si = (f * 5 + m) * ncol + col;
    unsigned short v;
    if (!isf) {
      v = ((const unsigned short*)W)[si];
    } else {
      float w = ((const float*)W)[si];
      unsigned short hh = dcr_f2b(w);
      v = (pl == 0) ? hh : dcr_f2b(w - dcr_b2f(hh));
    }
    o[e] = v;
  }
}

// ---------------- MFMA building blocks --------------------------------------
// gate proj one m-term: wave w (0..3) owns 2 N-tiles (cols w*32..w*32+31),
// M-tiles 0..3. Term A read ONCE per (ks,mt), shared by both N-tiles.
__device__ __forceinline__ void dcr_gp(
    f4v& A0, f4v& A1, f4v& A2, f4v& A3,
    f4v& A4, f4v& A5, f4v& A6, f4v& A7,
    const unsigned* T, const unsigned short* rph, const unsigned short* rpl,
    int m, int w, int lane, int wlo) {
  const int ln15 = lane & 15;
  const int k8 = ((lane >> 4) & 3) * 8;
#pragma unroll
  for (int ks = 0; ks < 4; ++ks) {
    const int fo0 = (((m * 8 + w * 2 + 0) * 4 + ks) * 64 + lane) * 8;
    const int fo1 = (((m * 8 + w * 2 + 1) * 4 + ks) * 64 + lane) * 8;
    s8v bh0 = dcr_ld8(rph + fo0);
    s8v bh1 = dcr_ld8(rph + fo1);
    s8v bl0, bl1;
    if (wlo) { bl0 = dcr_ld8(rpl + fo0); bl1 = dcr_ld8(rpl + fo1); }
    const int kb = ks * 32 + k8;
#define DCR_GPM(AX, AY, MT)                                                \
    {                                                                      \
      const int node = (MT) * 16 + ln15;                                   \
      s8v ah, al;                                                          \
      UNPACK8(ah, al, T, node, kb)                                         \
      AX = MFMA16(ah, bh0, AX);                                            \
      AX = MFMA16(al, bh0, AX);                                            \
      if (wlo) AX = MFMA16(ah, bl0, AX);                                   \
      AY = MFMA16(ah, bh1, AY);                                            \
      AY = MFMA16(al, bh1, AY);                                            \
      if (wlo) AY = MFMA16(ah, bl1, AY);                                   \
    }
    DCR_GPM(A0, A4, 0)
    DCR_GPM(A1, A5, 1)
    DCR_GPM(A2, A6, 2)
    DCR_GPM(A3, A7, 3)
#undef DCR_GPM
  }
}

// cand proj one m-term: wave w4 (0..3) owns cand N-tile w4. pass 0 = x-half
// (abs ks 0..1), pass 1 = rh-half (abs ks 2..3, 64-wide rh term).
__device__ __forceinline__ void dcr_cp(f4v& A0, f4v& A1, f4v& A2, f4v& A3,
                                       const unsigned* T,
                                       const unsigned short* rph,
                                       const unsigned short* rpl,
                                       int m, int w4, int lane, int wlo,
                                       int pass) {
  const int ln15 = lane & 15;
  const int k8 = ((lane >> 4) & 3) * 8;
#pragma unroll
  for (int ks2 = 0; ks2 < 2; ++ks2) {
    const int ks = pass * 2 + ks2;
    const int fo = (((m * 4 + w4) * 4 + ks) * 64 + lane) * 8;
    s8v bh = dcr_ld8(rph + fo);
    s8v bl;
    if (wlo) bl = dcr_ld8(rpl + fo);
    const int kb = ks2 * 32 + k8;
#define DCR_CPM(AX, MT)                                                    \
    {                                                                      \
      const int node = (MT) * 16 + ln15;                                   \
      s8v ah, al;                                                          \
      UNPACK8(ah, al, T, node, kb)                                         \
      AX = MFMA16(ah, bh, AX);                                             \
      AX = MFMA16(al, bh, AX);                                             \
      if (wlo) AX = MFMA16(ah, bl, AX);                                    \
    }
    DCR_CPM(A0, 0)
    DCR_CPM(A1, 1)
    DCR_CPM(A2, 2)
    DCR_CPM(A3, 3)
#undef DCR_CPM
  }
}

// apply: Y = S @ X. A = S [out][in] (b128, u16 planes, stride RSS=68),
// B = X (interleaved u32 gathers), cheb via C-init = -init/2, 2x writeback.
// NMT feat-tiles starting at wave-uniform nmt0; wave owns out-node tile idx.
#define DCR_API(ACX, J)                                                    \
  {                                                                        \
    if (ih_) {                                                             \
      _Pragma("unroll") for (int r = 0; r < 4; ++r)                        \
        ACX[r] = -0.5f * dcr_rdw(ih_[TA(orow + rq + r, fb + (J) * 16)]);   \
    } else {                                                               \
      ACX[0] = 0.0f; ACX[1] = 0.0f; ACX[2] = 0.0f; ACX[3] = 0.0f;          \
    }                                                                      \
  }
#define DCR_APM(ACX, J)                                                    \
  {                                                                        \
    s8v bh, b2;                                                            \
    _Pragma("unroll") for (int j = 0; j < 8; ++j) {                        \
      const unsigned w_ = src[TA(kb + j, fb + (J) * 16)];                  \
      bh[j] = (short)w_;                                                   \
      b2[j] = (short)(w_ >> 16);                                           \
    }                                                                      \
    ACX = MFMA16(ah, bh, ACX);                                             \
    ACX = MFMA16(ah, b2, ACX);                                             \
    if (wlo) ACX = MFMA16(al, bh, ACX);                                    \
  }
#define DCR_APS(ACX, J)                                                    \
  {                                                                        \
    _Pragma("unroll") for (int r = 0; r < 4; ++r)                          \
      dst[TA(orow + rq + r, fb + (J) * 16)] = dcr_pack(fct * ACX[r]);      \
  }

template <int NMT>
__device__ __forceinline__ void dcr_ap(const unsigned short* sh_,
                                       const unsigned short* sl_,
                                       const unsigned* src, unsigned* dst,
                                       const unsigned* ih_,
                                       int idx, int nmt0, int lane, int wlo) {
  const int ln15 = lane & 15;
  const int k8 = ((lane >> 4) & 3) * 8;
  const int rq = ((lane >> 4) & 3) * 4;
  const int orow = idx * 16;        // wave's out-node base
  const int fb = nmt0 * 16 + ln15;  // wave's feat base (uniform nmt0)
  f4v AC0, AC1, AC2, AC3;
  DCR_API(AC0, 0)
  DCR_API(AC1, 1)
  if constexpr (NMT == 4) {
    DCR_API(AC2, 2)
    DCR_API(AC3, 3)
  }
#pragma unroll
  for (int ks = 0; ks < 2; ++ks) {
    const int kb = ks * 32 + k8;
    s8v ah = dcr_ld8(sh_ + (orow + ln15) * RSS + kb);
    s8v al;
    if (wlo) al = dcr_ld8(sl_ + (orow + ln15) * RSS + kb);
    DCR_APM(AC0, 0)
    DCR_APM(AC1, 1)
    if constexpr (NMT == 4) {
      DCR_APM(AC2, 2)
      DCR_APM(AC3, 3)
    }
  }
  const float fct = ih_ ? 2.0f : 1.0f;
  DCR_APS(AC0, 0)
  DCR_APS(AC1, 1)
  if constexpr (NMT == 4) {
    DCR_APS(AC2, 2)
    DCR_APS(AC3, 3)
  }
}

// ---------------- one DCGRU layer step (compile-time L) ---------------------
// NOTE: cat is already staged in T0 (by the previous layer's pr4 / the
// prologue). This layer's pr4 stages the NEXT layer's cat into T0.
template <int L>
__device__ __forceinline__ void dcr_layer(
    f4v& hA0, f4v& hA1, f4v& hA2, f4v& hA3,
    f4v& hB0, f4v& hB1, f4v& hB2, f4v& hB3,
    const void* xseq, int b, int t, int isf, int wlo,
    const unsigned short* rp,
    unsigned* T0, unsigned* T1, unsigned* T2,
    const unsigned short* S0h, const unsigned short* S0l,
    const unsigned short* S1h, const unsigned short* S1l,
    unsigned* HB, const float* BG, const float* BC,
    int tid, int lane, int wid) {
  const int ln15 = lane & 15;
  const int rq = ((lane >> 4) & 3) * 4;
  const unsigned short* rpgh = rp + (L * 2 + 0) * GN;
  const unsigned short* rpgl = rp + (L * 2 + 1) * GN;
  const unsigned short* rpch = rp + 4 * GN + (L * 2 + 0) * CN;
  const unsigned short* rpcl = rp + 4 * GN + (L * 2 + 1) * CN;

  f4v A0 = {0.0f, 0.0f, 0.0f, 0.0f}, A1 = A0, A2 = A0, A3 = A0;
  f4v A4 = A0, A5 = A0, A6 = A0, A7 = A0;

  // ---------------- gate pass: pm0..pm3 ------------------------------------
  if (wid < 4) dcr_gp(A0, A1, A2, A3, A4, A5, A6, A7, T0, rpgh, rpgl, 0, wid, lane, wlo);
  else if (wid >= 8 && wid < 12) dcr_cp(A0, A1, A2, A3, T0, rpch, rpcl, 0, wid - 8, lane, wlo, 0);
  else dcr_ap<4>(S0h, S0l, T0, T1, nullptr, wid & 3, (wid < 8) ? 4 : 0, lane, wlo);
  __syncthreads();
  if (wid < 4) dcr_gp(A0, A1, A2, A3, A4, A5, A6, A7, T1, rpgh, rpgl, 1, wid, lane, wlo);
  else if (wid >= 8 && wid < 12) dcr_cp(A0, A1, A2, A3, T1, rpch, rpcl, 1, wid - 8, lane, wlo, 0);
  else dcr_ap<4>(S0h, S0l, T1, T2, T0, wid & 3, (wid < 8) ? 4 : 0, lane, wlo);
  __syncthreads();
  if (wid < 4) dcr_gp(A0, A1, A2, A3, A4, A5, A6, A7, T2, rpgh, rpgl, 2, wid, lane, wlo);
  else if (wid >= 8 && wid < 12) dcr_cp(A0, A1, A2, A3, T2, rpch, rpcl, 2, wid - 8, lane, wlo, 0);
  else dcr_ap<4>(S1h, S1l, T1, T0, nullptr, wid & 3, (wid < 8) ? 4 : 0, lane, wlo);
  __syncthreads();
  if (wid < 4) dcr_gp(A0, A1, A2, A3, A4, A5, A6, A7, T0, rpgh, rpgl, 3, wid, lane, wlo);
  else if (wid >= 8 && wid < 12) dcr_cp(A0, A1, A2, A3, T0, rpch, rpcl, 3, wid - 8, lane, wlo, 0);
  else dcr_ap<4>(S1h, S1l, T0, T2, T1, wid & 3, (wid < 8) ? 4 : 0, lane, wlo);
  __syncthreads();

  // ---------------- pm4: proj(m4) + gate finish (merged) -------------------
  if (wid < 4) {
    dcr_gp(A0, A1, A2, A3, A4, A5, A6, A7, T2, rpgh, rpgl, 4, wid, lane, wlo);
    const int g0 = wid * 32 + ln15;
    const float bg0v = BG[L * 128 + g0];
    const float bg1v = BG[L * 128 + g0 + 16];
#define DCR_GF(AX, AY, MT)                                                 \
    { _Pragma("unroll") for (int r = 0; r < 4; ++r) {                      \
        const int node = (MT) * 16 + rq + r;                               \
        const float s0_ = dcr_sigm(AX[r] + bg0v);                          \
        const float s1_ = dcr_sigm(AY[r] + bg1v);                          \
        if (wid < 2) {                                                     \
          const float h0_ = dcr_rdw(HB[node * RSHB + g0]);                 \
          const float h1_ = dcr_rdw(HB[node * RSHB + g0 + 16]);            \
          T0[TA(node, g0)] = dcr_pack(s0_ * h0_);                          \
          T0[TA(node, g0 + 16)] = dcr_pack(s1_ * h1_);                     \
        } else {                                                           \
          T1[TA(node, g0)] = dcr_pack(s0_);                                \
          T1[TA(node, g0 + 16)] = dcr_pack(s1_);                           \
        } } }
    DCR_GF(A0, A4, 0)
    DCR_GF(A1, A5, 1)
    DCR_GF(A2, A6, 2)
    DCR_GF(A3, A7, 3)
#undef DCR_GF
  } else if (wid >= 8 && wid < 12) {
    dcr_cp(A0, A1, A2, A3, T2, rpch, rpcl, 4, wid - 8, lane, wlo, 0);
  }
  __syncthreads();

  // ---------------- rh pass: pr0..pr3 (64-wide) ----------------------------
  if (wid >= 8 && wid < 12) dcr_cp(A0, A1, A2, A3, T0, rpch, rpcl, 0, wid - 8, lane, wlo, 1);
  else if (wid >= 4) dcr_ap<2>(S0h, S0l, T0, T1, nullptr, wid & 3, (wid < 8) ? 2 : 0, lane, wlo);
  __syncthreads();
  if (wid >= 8 && wid < 12) dcr_cp(A0, A1, A2, A3, T1, rpch, rpcl, 1, wid - 8, lane, wlo, 1);
  else if (wid >= 4) dcr_ap<2>(S0h, S0l, T1, T2, T0, wid & 3, (wid < 8) ? 2 : 0, lane, wlo);
  __syncthreads();
  if (wid >= 8 && wid < 12) dcr_cp(A0, A1, A2, A3, T2, rpch, rpcl, 2, wid - 8, lane, wlo, 1);
  else if (wid >= 4) dcr_ap<2>(S1h, S1l, T1, T0, nullptr, wid & 3, (wid < 8) ? 2 : 0, lane, wlo);
  __syncthreads();
  if (wid >= 8 && wid < 12) dcr_cp(A0, A1, A2, A3, T0, rpch, rpcl, 3, wid - 8, lane, wlo, 1);
  else if (wid >= 4) dcr_ap<2>(S1h, S1l, T0, T1, T1, wid & 3, (wid < 8) ? 2 : 0, lane, wlo);
  __syncthreads();

  // ---------------- pr4: cp(m4') + cand finish + NEXT-cat staging ----------
  // T0 is free here (last read in pr3); cand reads only T1.
  if (wid >= 8 && wid < 12) {
    dcr_cp(A0, A1, A2, A3, T1, rpch, rpcl, 4, wid - 8, lane, wlo, 1);
    const int f = (wid - 8) * 16 + ln15;
    const float bcv = BC[L * 64 + f];
#define DCR_CF(AX, HX, MT)                                                 \
    { _Pragma("unroll") for (int r = 0; r < 4; ++r) {                      \
        const int node = (MT) * 16 + rq + r;                               \
        const float c = dcr_tanh(AX[r] + bcv);                             \
        const float u = dcr_rdw(T1[TA(node, 64 + f)]);                     \
        HX[r] = u * HX[r] + (1.0f - u) * c; } }
    if constexpr (L == 0) {
      DCR_CF(A0, hA0, 0)
      DCR_CF(A1, hA1, 1)
      DCR_CF(A2, hA2, 2)
      DCR_CF(A3, hA3, 3)
      // stage layer-1 cat = [hA | hB]; HB <- hB (layer-1 recurrent h)
#define DCR_SG0(HAX, HBX, MT)                                              \
      { _Pragma("unroll") for (int r = 0; r < 4; ++r) {                    \
          const int node = (MT) * 16 + rq + r;                             \
          T0[TA(node, f)] = dcr_pack(HAX[r]);                              \
          const unsigned pw = dcr_pack(HBX[r]);                            \
          T0[TA(node, 64 + f)] = pw;                                       \
          HB[node * RSHB + f] = pw; } }
      DCR_SG0(hA0, hB0, 0)
      DCR_SG0(hA1, hB1, 1)
      DCR_SG0(hA2, hB2, 2)
      DCR_SG0(hA3, hB3, 3)
#undef DCR_SG0
    } else {
      DCR_CF(A0, hB0, 0)
      DCR_CF(A1, hB1, 1)
      DCR_CF(A2, hB2, 2)
      DCR_CF(A3, hB3, 3)
      // stage next-t layer-0 cat h-half = hA; HB <- hA
#define DCR_SG1(HAX, MT)                                                   \
      { _Pragma("unroll") for (int r = 0; r < 4; ++r) {                    \
          const int node = (MT) * 16 + rq + r;                             \
          const unsigned pw = dcr_pack(HAX[r]);                            \
          T0[TA(node, 64 + f)] = pw;                                       \
          HB[node * RSHB + f] = pw; } }
      DCR_SG1(hA0, 0)
      DCR_SG1(hA1, 1)
      DCR_SG1(hA2, 2)
      DCR_SG1(hA3, 3)
#undef DCR_SG1
    }
#undef DCR_CF
  } else if (L == 1 && wid < 8) {
    // stage x_{t+1} -> T0 feats 0-63 (latency hidden under cand's cp work)
    const int tn = (t < 95) ? (t + 1) : 95;
    const int n = tid >> 3;
    const int f0 = (tid & 7) * 8;
    const int xo = (b * 96 + tn) * 4096 + n * 64 + f0;
    const int base = TA(n, f0);
    uint4 q0, q1;
    if (isf) {
      const float* xp = (const float*)xseq + xo;
      q0.x = dcr_pack(xp[0]); q0.y = dcr_pack(xp[1]);
      q0.z = dcr_pack(xp[2]); q0.w = dcr_pack(xp[3]);
      q1.x = dcr_pack(xp[4]); q1.y = dcr_pack(xp[5]);
      q1.z = dcr_pack(xp[6]); q1.w = dcr_pack(xp[7]);
    } else {
      const unsigned short* xp = (const unsigned short*)xseq + xo;
      s8v v = *(const s8v*)xp;
      q0.x = (unsigned)(unsigned short)v[0];
      q0.y = (unsigned)(unsigned short)v[1];
      q0.z = (unsigned)(unsigned short)v[2];
      q0.w = (unsigned)(unsigned short)v[3];
      q1.x = (unsigned)(unsigned short)v[4];
      q1.y = (unsigned)(unsigned short)v[5];
      q1.z = (unsigned)(unsigned short)v[6];
      q1.w = (unsigned)(unsigned short)v[7];
    }
    *(uint4*)(T0 + base) = q0;
    *(uint4*)(T0 + base + 4) = q1;
  }
  __syncthreads();
}

// ---------------- main MFMA kernel ------------------------------------------
__global__ __launch_bounds__(1024)
__attribute__((amdgpu_waves_per_eu(4, 4)))
void dcr_mfma(
    const void* xseq, const void* s0, const void* s1,
    const void* bg0, const void* bg1,
    const void* p64a, const void* p64b, const void* p64c,
    const void* fcw, const void* fcb, const void* idw, const void* idb,
    const unsigned short* rp, void* outp) {
  extern __shared__ char sm[];
  unsigned* const T0 = (unsigned*)(sm + OFF_T0);
  unsigned* const T1 = (unsigned*)(sm + OFF_T1);
  unsigned* const T2 = (unsigned*)(sm + OFF_T2);
  unsigned short* const S0h = (unsigned short*)(sm + OFF_S0H);
  unsigned short* const S0l = (unsigned short*)(sm + OFF_S0L);
  unsigned short* const S1h = (unsigned short*)(sm + OFF_S1H);
  unsigned short* const S1l = (unsigned short*)(sm + OFF_S1L);
  unsigned* const HB = (unsigned*)(sm + OFF_HB);
  float* const BG = (float*)(sm + OFF_BG);
  float* const BC = (float*)(sm + OFF_BC);
  int* const ctl = (int*)(sm + OFF_CTL);

  const int tid = threadIdx.x;
  const int b = blockIdx.x;
  const int lane = tid & 63;
  const int wid = tid >> 6;

  // ---- on-device identification ----
  if (tid == 0) {
    const unsigned short* ss = (const unsigned short*)s0;
    int hits = 0;
    for (int i = 0; i < 32; ++i) {
      unsigned hb = ((unsigned)ss[2 * i] >> 8) & 0xFFu;
      if (hb >= 0x30u && hb <= 0x3Fu) ++hits;
    }
    int isf_ = (hits < 16) ? 1 : 0;
    int sel = 0;
    {
      const unsigned* w = (const unsigned*)p64a;
      unsigned any = 0;
      for (int i = 0; i < 16; ++i) any |= w[i];
      if (!any) {
        sel = 1;
        const unsigned* w1 = (const unsigned*)p64b;
        unsigned any1 = 0;
        for (int i = 0; i < 16; ++i) any1 |= w1[i];
        if (!any1) sel = 2;
      }
    }
    const unsigned* w =
        (const unsigned*)(sel == 0 ? p64a : (sel == 1 ? p64b : p64c));
    int i64 = 1;
    for (int i = 0; i < 8; ++i)
      if (w[2 * i + 1] != 0u) i64 = 0;
    ctl[0] = isf_;
    ctl[1] = sel;
    ctl[2] = i64;
  }
  __syncthreads();
  const int isf = ctl[0];
  const int sel = ctl[1];
  const int i64 = ctl[2];
  const int wlo = isf;  // lo planes of S/W meaningful only for fp32 inputs
  const void* seqp = (sel == 0) ? p64a : (sel == 1 ? p64b : p64c);
  const void* bcA = (sel == 0) ? p64b : p64a;
  const void* bcB = (sel == 2) ? p64b : p64c;

  // ---- stage supports (hi/lo u16, stride RSS) and biases ----
  for (int i = 0; i < 4; ++i) {
    const int flat = i * 1024 + tid;  // = out*64 + in
    const int out = flat >> 6, in = flat & 63;
    float v0, v1;
    if (isf) {
      v0 = ((const float*)s0)[flat];
      v1 = ((const float*)s1)[flat];
    } else {
      v0 = dcr_b2f(((const unsigned short*)s0)[flat]);
      v1 = dcr_b2f(((const unsigned short*)s1)[flat]);
    }
    unsigned short hh = dcr_f2b(v0);
    S0h[out * RSS + in] = hh;
    S0l[out * RSS + in] = dcr_f2b(v0 - dcr_b2f(hh));
    hh = dcr_f2b(v1);
    S1h[out * RSS + in] = hh;
    S1l[out * RSS + in] = dcr_f2b(v1 - dcr_b2f(hh));
  }
  if (tid < 128) {
    BG[tid] = dcr_ld(bg0, tid, isf);
    BG[128 + tid] = dcr_ld(bg1, tid, isf);
  } else if (tid < 192) {
    const int j = tid - 128;
    BC[j] = dcr_ld(bcA, j, isf);
    BC[64 + j] = dcr_ld(bcB, j, isf);
  }

  int tl_;
  if (i64) tl_ = (int)((const long long*)seqp)[b] - 1;
  else     tl_ = ((const int*)seqp)[b] - 1;
  if (tl_ < 0) tl_ = 0;
  if (tl_ > 95) tl_ = 95;

  f4v hA0 = {0.0f, 0.0f, 0.0f, 0.0f}, hA1 = hA0, hA2 = hA0, hA3 = hA0;
  f4v hB0 = hA0, hB1 = hA0, hB2 = hA0, hB3 = hA0;

  const int ln15 = lane & 15;
  const int rq = ((lane >> 4) & 3) * 4;

  // ---- prologue: stage cat_0 = [x_0 | h=0] into T0, zero HB ----
  if (wid < 8) {
    const int n = tid >> 3;
    const int f0 = (tid & 7) * 8;
    const int xo = (b * 96 + 0) * 4096 + n * 64 + f0;
    const int base = TA(n, f0);
    uint4 q0, q1;
    if (isf) {
      const float* xp = (const float*)xseq + xo;
      q0.x = dcr_pack(xp[0]); q0.y = dcr_pack(xp[1]);
      q0.z = dcr_pack(xp[2]); q0.w = dcr_pack(xp[3]);
      q1.x = dcr_pack(xp[4]); q1.y = dcr_pack(xp[5]);
      q1.z = dcr_pack(xp[6]); q1.w = dcr_pack(xp[7]);
    } else {
      const unsigned short* xp = (const unsigned short*)xseq + xo;
      s8v v = *(const s8v*)xp;
      q0.x = (unsigned)(unsigned short)v[0];
      q0.y = (unsigned)(unsigned short)v[1];
      q0.z = (unsigned)(unsigned short)v[2];
      q0.w = (unsigned)(unsigned short)v[3];
      q1.x = (unsigned)(unsigned short)v[4];
      q1.y = (unsigned)(unsigned short)v[5];
      q1.z = (unsigned)(unsigned short)v[6];
      q1.w = (unsigned)(unsigned short)v[7];
    }
    *(uint4*)(T0 + base) = q0;
    *(uint4*)(T0 + base + 4) = q1;
  } else if (wid < 12) {
    const int f = (wid - 8) * 16 + ln15;
#pragma unroll
    for (int mt = 0; mt < 4; ++mt)
#pragma unroll
      for (int r = 0; r < 4; ++r) {
        const int node = mt * 16 + rq + r;
        T0[TA(node, 64 + f)] = 0u;
        HB[node * RSHB + f] = 0u;
      }
  }
  __syncthreads();

  for (int t = 0; t < 96; ++t) {
    dcr_layer<0>(hA0, hA1, hA2, hA3, hB0, hB1, hB2, hB3,
                 xseq, b, t, isf, wlo, rp, T0, T1, T2,
                 S0h, S0l, S1h, S1l, HB, BG, BC, tid, lane, wid);
    dcr_layer<1>(hA0, hA1, hA2, hA3, hB0, hB1, hB2, hB3,
                 xseq, b, t, isf, wlo, rp, T0, T1, T2,
                 S0h, S0l, S1h, S1l, HB, BG, BC, tid, lane, wid);
    if (t == tl_) break;
  }

  // ---------------- heads: relu(h1) -> fc/id matmul -> max over nodes -------
  __syncthreads();
  float* const hx = (float*)(sm + OFF_T0);   // [64][66]
  float* const hw = (float*)(sm + OFF_T1);   // [64][56]
  float* const red = (float*)(sm + OFF_T2);  // [16][54]
  if (wid >= 8 && wid < 12) {
    const int f = (wid - 8) * 16 + ln15;
#define DCR_HX(HX, MT)                                                     \
    { _Pragma("unroll") for (int r = 0; r < 4; ++r) {                      \
        const int node = (MT) * 16 + rq + r;                               \
        hx[node * 66 + f] = fmaxf(HX[r], 0.0f); } }
    DCR_HX(hB0, 0)
    DCR_HX(hB1, 1)
    DCR_HX(hB2, 2)
    DCR_HX(hB3, 3)
#undef DCR_HX
  }
  {
    const int u = tid >> 4;
    for (int c = (tid & 15); c < 54; c += 16)
      hw[u * 56 + c] = (c < 4) ? dcr_ld(fcw, u * 4 + c, isf)
                               : dcr_ld(idw, u * 50 + (c - 4), isf);
  }
  __syncthreads();
  if (tid < 864) {
    const int c = tid % 54, nb = tid / 54;
    float mx = -3.4e38f;
    for (int nn = nb * 4; nn < nb * 4 + 4; ++nn) {
      float s = 0.0f;
#pragma unroll 8
      for (int uu = 0; uu < 64; ++uu) s += hx[nn * 66 + uu] * hw[uu * 56 + c];
      mx = fmaxf(mx, s);
    }
    red[nb * 54 + c] = mx;
  }
  __syncthreads();
  if (tid < 54) {
    float mx = red[tid];
#pragma unroll
    for (int g = 1; g < 16; ++g) mx = fmaxf(mx, red[g * 54 + tid]);
    mx += (tid < 4) ? dcr_ld(fcb, tid, isf) : dcr_ld(idb, tid - 4, isf);
    const int o = (tid < 4) ? (b * 4 + tid) : (256 + b * 50 + (tid - 4));
    if (isf) ((float*)outp)[o] = mx;
    else     ((unsigned short*)outp)[o] = dcr_f2b(mx);
  }
}

// ============================================================================
// Fallback: proven scalar kernel (round-1, 1024 threads) for ws-too-small.
// ============================================================================
__device__ void dcr_proj(float* aG, float* aC, const float (*buf)[68],
                         const void* Wg, const void* Wc, int m, int fh,
                         int n, int fb, int doG, int doC, int isf) {
  if (!isf) {
    const unsigned* G = (const unsigned*)Wg;
    const unsigned* C = (const unsigned*)Wc;
    const int fd = fb >> 1;
#pragma unroll 4
    for (int k = 0; k < 64; ++k) {
      float xk = buf[n][k];
      int row = (fh + k) * 5 + m;
      if (doG) {
        const unsigned* wr = G + row * 64 + fd;
        unsigned p0 = wr[0], p1 = wr[1], p2 = wr[32], p3 = wr[33];
        aG[0] += xk * __uint_as_float(p0 << 16);
        aG[1] += xk * __uint_as_float(p0 & 0xFFFF0000u);
        aG[2] += xk * __uint_as_float(p1 << 16);
        aG[3] += xk * __uint_as_float(p1 & 0xFFFF0000u);
        aG[4] += xk * __uint_as_float(p2 << 16);
        aG[5] += xk * __uint_as_float(p2 & 0xFFFF0000u);
        aG[6] += xk * __uint_as_float(p3 << 16);
        aG[7] += xk * __uint_as_float(p3 & 0xFFFF0000u);
      }
      if (doC) {
        const unsigned* wr = C + row * 32 + fd;
        unsigned p0 = wr[0], p1 = wr[1];
        aC[0] += xk * __uint_as_float(p0 << 16);
        aC[1] += xk * __uint_as_float(p0 & 0xFFFF0000u);
        aC[2] += xk * __uint_as_float(p1 << 16);
        aC[3] += xk * __uint_as_float(p1 & 0xFFFF0000u);
      }
    }
  } else {
    const float* G = (const float*)Wg;
    const float* C = (const float*)Wc;
#pragma unroll 4
    for (int k = 0; k < 64; ++k) {
      float xk = buf[n][k];
      int row = (fh + k) * 5 + m;
      if (doG) {
        const float* wr = G + row * 128 + fb;
#pragma unroll
        for (int j = 0; j < 4; ++j) {
          aG[j] += xk * wr[j];
          aG[4 + j] += xk * wr[64 + j];
        }
      }
      if (doC) {
        const float* wr = C + row * 64 + fb;
#pragma unroll
        for (int j = 0; j < 4; ++j) aC[j] += xk * wr[j];
      }
    }
  }
}

__device__ void dcr_apply(float (*dst)[68], const float (*src)[68],
                          const unsigned short (*sS)[65], int n, int fb,
                          int cheb) {
  float a0 = 0.0f, a1 = 0.0f, a2 = 0.0f, a3 = 0.0f;
#pragma unroll 8
  for (int m = 0; m < 64; ++m) {
    float s = dcr_b2f(sS[n][m]);
    float4 v = *(const float4*)(&src[m][fb]);
    a0 += s * v.x;
    a1 += s * v.y;
    a2 += s * v.z;
    a3 += s * v.w;
  }
  if (cheb) {
    dst[n][fb + 0] = 2.0f * a0 - dst[n][fb + 0];
    dst[n][fb + 1] = 2.0f * a1 - dst[n][fb + 1];
    dst[n][fb + 2] = 2.0f * a2 - dst[n][fb + 2];
    dst[n][fb + 3] = 2.0f * a3 - dst[n][fb + 3];
  } else {
    dst[n][fb + 0] = a0;
    dst[n][fb + 1] = a1;
    dst[n][fb + 2] = a2;
    dst[n][fb + 3] = a3;
  }
}

__device__ void dcr_half(float* aG, float* aC, const void* Wg, const void* Wc,
                         int fh, int doG, int doC, float (*xa)[68],
                         float (*xb)[68], const unsigned short (*sS0)[65],
                         const unsigned short (*sS1)[65], int n, int fb,
                         int isf) {
  dcr_proj(aG, aC, xa, Wg, Wc, 0, fh, n, fb, doG, doC, isf);
  dcr_apply(xb, xa, sS0, n, fb, 0);
  __syncthreads();
  dcr_proj(aG, aC, xb, Wg, Wc, 1, fh, n, fb, doG, doC, isf);
  dcr_apply(xa, xb, sS0, n, fb, 1);
  __syncthreads();
  dcr_proj(aG, aC, xa, Wg, Wc, 2, fh, n, fb, doG, doC, isf);
  __syncthreads();
  dcr_apply(xa, xb, sS1, n, fb, 0);
  __syncthreads();
  dcr_proj(aG, aC, xa, Wg, Wc, 3, fh, n, fb, doG, doC, isf);
  dcr_apply(xb, xa, sS1, n, fb, 1);
  __syncthreads();
  dcr_proj(aG, aC, xb, Wg, Wc, 4, fh, n, fb, doG, doC, isf);
  __syncthreads();
}

__global__ __launch_bounds__(1024) void dcr_scalar(
    const void* xseq, const void* s0, const void* s1, const void* wg0,
    const void* wc0, const void* wg1, const void* wc1, const void* bg0,
    const void* bg1, const void* p64a, const void* p64b, const void* p64c,
    const void* fcw, const void* fcb, const void* idw, const void* idb,
    void* outp) {
  __shared__ float xa[64][68];
  __shared__ float xb[64][68];
  __shared__ unsigned short sS[2][64][65];
  __shared__ float bGs[2][128];
  __shared__ float bCs[2][64];
  __shared__ float red[16][54];
  __shared__ int ctl[4];

  const int tid = threadIdx.x;
  const int b = blockIdx.x;
  const int n = tid >> 4;
  const int fb = (tid & 15) * 4;

  if (tid == 0) {
    const unsigned short* ss = (const unsigned short*)s0;
    int hits = 0;
    for (int i = 0; i < 32; ++i) {
      unsigned hb = ((unsigned)ss[2 * i] >> 8) & 0xFFu;
      if (hb >= 0x30u && hb <= 0x3Fu) ++hits;
    }
    int isf = (hits < 16) ? 1 : 0;
    int sel = 0;
    {
      const unsigned* w = (const unsigned*)p64a;
      unsigned any = 0;
      for (int i = 0; i < 16; ++i) any |= w[i];
      if (!any) {
        sel = 1;
        const unsigned* w1 = (const unsigned*)p64b;
        unsigned any1 = 0;
        for (int i = 0; i < 16; ++i) any1 |= w1[i];
        if (!any1) sel = 2;
      }
    }
    const unsigned* w =
        (const unsigned*)(sel == 0 ? p64a : (sel == 1 ? p64b : p64c));
    int i64 = 1;
    for (int i = 0; i < 8; ++i)
      if (w[2 * i + 1] != 0u) i64 = 0;
    ctl[0] = isf;
    ctl[1] = sel;
    ctl[2] = i64;
  }
  __syncthreads();
  const int isf = ctl[0];
  const int sel = ctl[1];
  const int i64 = ctl[2];
  const void* seqp = (sel == 0) ? p64a : (sel == 1 ? p64b : p64c);
  const void* bcA = (sel == 0) ? p64b : p64a;
  const void* bcB = (sel == 2) ? p64b : p64c;

  for (int i = 0; i < 4; ++i) {
    int flat = i * 1024 + tid;
    int nn = flat >> 6, mm = flat & 63;
    unsigned short v0, v1;
    if (isf) {
      v0 = dcr_f2b(((const float*)s0)[flat]);
      v1 = dcr_f2b(((const float*)s1)[flat]);
    } else {
      v0 = ((const unsigned short*)s0)[flat];
      v1 = ((const unsigned short*)s1)[flat];
    }
    sS[0][nn][mm] = v0;
    sS[1][nn][mm] = v1;
  }
  if (tid < 128) {
    bGs[0][tid] = dcr_ld(bg0, tid, isf);
    bGs[1][tid] = dcr_ld(bg1, tid, isf);
  } else if (tid < 192) {
    int j = tid - 128;
    bCs[0][j] = dcr_ld(bcA, j, isf);
    bCs[1][j] = dcr_ld(bcB, j, isf);
  }

  int tl;
  if (i64) tl = (int)((const long long*)seqp)[b] - 1;
  else     tl = ((const int*)seqp)[b] - 1;
  if (tl < 0) tl = 0;
  if (tl > 95) tl = 95;

  float h0r[4], h1r[4];
#pragma unroll
  for (int j = 0; j < 4; ++j) {
    h0r[j] = 0.0f;
    h1r[j] = 0.0f;
  }
  __syncthreads();

  for (int t = 0; t < 96; ++t) {
    {
      float aG[8], aC[4];
#pragma unroll
      for (int j = 0; j < 8; ++j) aG[j] = 0.0f;
#pragma unroll
      for (int j = 0; j < 4; ++j) aC[j] = 0.0f;
      int xoff = (b * 96 + t) * 4096 + n * 64 + fb;
#pragma unroll
      for (int j = 0; j < 4; ++j) xa[n][fb + j] = dcr_ld(xseq, xoff + j, isf);
      __syncthreads();
      dcr_half(aG, aC, wg0, wc0, 0, 1, 1, xa, xb, sS[0], sS[1], n, fb, isf);
#pragma unroll
      for (int j = 0; j < 4; ++j) xa[n][fb + j] = h0r[j];
      __syncthreads();
      dcr_half(aG, aC, wg0, wc0, 64, 1, 0, xa, xb, sS[0], sS[1], n, fb, isf);
      float rr[4], uu[4];
#pragma unroll
      for (int j = 0; j < 4; ++j) {
        rr[j] = dcr_sigm(aG[j] + bGs[0][fb + j]);
        uu[j] = dcr_sigm(aG[4 + j] + bGs[0][64 + fb + j]);
      }
#pragma unroll
      for (int j = 0; j < 4; ++j) xa[n][fb + j] = rr[j] * h0r[j];
      __syncthreads();
      dcr_half(aG, aC, wg0, wc0, 64, 0, 1, xa, xb, sS[0], sS[1], n, fb, isf);
#pragma unroll
      for (int j = 0; j < 4; ++j) {
        float c = dcr_tanh(aC[j] + bCs[0][fb + j]);
        h0r[j] = uu[j] * h0r[j] + (1.0f - uu[j]) * c;
      }
    }
    {
      float aG[8], aC[4];
#pragma unroll
      for (int j = 0; j < 8; ++j) aG[j] = 0.0f;
#pragma unroll
      for (int j = 0; j < 4; ++j) aC[j] = 0.0f;
#pragma unroll
      for (int j = 0; j < 4; ++j) xa[n][fb + j] = h0r[j];
      __syncthreads();
      dcr_half(aG, aC, wg1, wc1, 0, 1, 1, xa, xb, sS[0], sS[1], n, fb, isf);
#pragma unroll
      for (int j = 0; j < 4; ++j) xa[n][fb + j] = h1r[j];
      __syncthreads();
      dcr_half(aG, aC, wg1, wc1, 64, 1, 0, xa, xb, sS[0], sS[1], n, fb, isf);
      float rr[4], uu[4];
#pragma unroll
      for (int j = 0; j < 4; ++j) {
        rr[j] = dcr_sigm(aG[j] + bGs[1][fb + j]);
        uu[j] = dcr_sigm(aG[4 + j] + bGs[1][64 + fb + j]);
      }
#pragma unroll
      for (int j = 0; j < 4; ++j) xa[n][fb + j] = rr[j] * h1r[j];
      __syncthreads();
      dcr_half(aG, aC, wg1, wc1, 64, 0, 1, xa, xb, sS[0], sS[1], n, fb, isf);
#pragma unroll
      for (int j = 0; j < 4; ++j) {
        float c = dcr_tanh(aC[j] + bCs[1][fb + j]);
        h1r[j] = uu[j] * h1r[j] + (1.0f - uu[j]) * c;
      }
    }
    if (t == tl) break;
  }

  __syncthreads();
#pragma unroll
  for (int j = 0; j < 4; ++j) xa[n][fb + j] = fmaxf(h1r[j], 0.0f);
  {
    int u = tid >> 4;
    for (int c = (tid & 15); c < 54; c += 16)
      xb[u][c] = (c < 4) ? dcr_ld(fcw, u * 4 + c, isf)
                         : dcr_ld(idw, u * 50 + (c - 4), isf);
  }
  __syncthreads();
  if (tid < 864) {
    int c = tid % 54, nb = tid / 54;
    float mx = -3.4e38f;
    for (int nn = nb * 4; nn < nb * 4 + 4; ++nn) {
      float s = 0.0f;
#pragma unroll 8
      for (int u = 0; u < 64; ++u) s += xa[nn][u] * xb[u][c];
      mx = fmaxf(mx, s);
    }
    red[nb][c] = mx;
  }
  __syncthreads();
  if (tid < 54) {
    float mx = red[0][tid];
#pragma unroll
    for (int g = 1; g < 16; ++g) mx = fmaxf(mx, red[g][tid]);
    mx += (tid < 4) ? dcr_ld(fcb, tid, isf) : dcr_ld(idb, tid - 4, isf);
    int o = (tid < 4) ? (b * 4 + tid) : (256 + b * 50 + (tid - 4));
    if (isf) ((float*)outp)[o] = mx;
    else     ((unsigned short*)outp)[o] = dcr_f2b(mx);
  }
}

// ---------------------------------------------------------------------------
static int dcr_find_nth(const int* s, int n, int sz, int nth) {
  int c = 0;
  for (int i = 0; i < n; ++i)
    if (s[i] == sz) {
      if (c == nth) return i;
      ++c;
    }
  return -1;
}

extern "C" void kernel_launch(void* const* d_in, const int* in_sizes, int n_in,
                              void* d_out, int out_size, void* d_ws,
                              size_t ws_size, hipStream_t stream) {
  (void)out_size;
  int i_seq = dcr_find_nth(in_sizes, n_in, 393216, 0);
  int i_s0 = dcr_find_nth(in_sizes, n_in, 4096, 0);
  int i_s1 = dcr_find_nth(in_sizes, n_in, 4096, 1);
  int i_wg0 = dcr_find_nth(in_sizes, n_in, 81920, 0);
  int i_wg1 = dcr_find_nth(in_sizes, n_in, 81920, 1);
  int i_wc0 = dcr_find_nth(in_sizes, n_in, 40960, 0);
  int i_wc1 = dcr_find_nth(in_sizes, n_in, 40960, 1);
  int i_bg0 = dcr_find_nth(in_sizes, n_in, 128, 0);
  int i_bg1 = dcr_find_nth(in_sizes, n_in, 128, 1);
  int i_64a = dcr_find_nth(in_sizes, n_in, 64, 0);
  int i_64b = dcr_find_nth(in_sizes, n_in, 64, 1);
  int i_64c = dcr_find_nth(in_sizes, n_in, 64, 2);
  int i_fcw = dcr_find_nth(in_sizes, n_in, 256, 0);
  int i_fcb = dcr_find_nth(in_sizes, n_in, 4, 0);
  int i_idw = dcr_find_nth(in_sizes, n_in, 3200, 0);
  int i_idb = dcr_find_nth(in_sizes, n_in, 50, 0);
  if (i_seq < 0 || i_s0 < 0 || i_s1 < 0 || i_wg0 < 0 || i_wg1 < 0 ||
      i_wc0 < 0 || i_wc1 < 0 || i_bg0 < 0 || i_bg1 < 0 || i_64a < 0 ||
      i_64b < 0 || i_64c < 0 || i_fcw < 0 || i_fcb < 0 || i_idw < 0 ||
      i_idb < 0) {
    i_seq = 0;  i_64a = 1;  i_s0 = 2;   i_s1 = 3;
    i_wg0 = 4;  i_bg0 = 5;  i_wc0 = 6;  i_64b = 7;
    i_wg1 = 8;  i_bg1 = 9;  i_wc1 = 10; i_64c = 11;
    i_fcw = 12; i_fcb = 13; i_idw = 14; i_idb = 15;
  }

  if (d_ws == nullptr || ws_size < (size_t)WS_NEED) {
    dcr_scalar<<<dim3(64), dim3(1024), 0, stream>>>(
        d_in[i_seq], d_in[i_s0], d_in[i_s1], d_in[i_wg0], d_in[i_wc0],
        d_in[i_wg1], d_in[i_wc1], d_in[i_bg0], d_in[i_bg1], d_in[i_64a],
        d_in[i_64b], d_in[i_64c], d_in[i_fcw], d_in[i_fcb], d_in[i_idw],
        d_in[i_idb], d_out);
    return;
  }

  dcr_repack<<<dim3(256), dim3(256), 0, stream>>>(
      d_in[i_wg0], d_in[i_wc0], d_in[i_wg1], d_in[i_wc1], d_in[i_s0],
      (unsigned short*)d_ws);

  static bool attr_set = false;
  if (!attr_set) {
    (void)hipFuncSetAttribute((const void*)dcr_mfma,
                              hipFuncAttributeMaxDynamicSharedMemorySize,
                              SMEM_SZ);
    attr_set = true;
  }

  dcr_mfma<<<dim3(64), dim3(1024), SMEM_SZ, stream>>>(
      d_in[i_seq], d_in[i_s0], d_in[i_s1], d_in[i_bg0], d_in[i_bg1],
      d_in[i_64a], d_in[i_64b], d_in[i_64c], d_in[i_fcw], d_in[i_fcb],
      d_in[i_idw], d_in[i_idb], (const unsigned short*)d_ws, d_out);
}

// Round 9
// 10341.585 us; speedup vs baseline: 3.1992x; 1.0271x over previous
//
#include <hip/hip_runtime.h>

// ---------------------------------------------------------------------------
// DCRNN (2-layer DCGRU encoder) -- MFMA round, gate rebalance + rh merge.
// R8 post-mortem: 10.6ms, phase critical path = gate wave (96 MFMA vs <=48
// for other roles); waves 0-3 idle through the whole rh pass; rh rotation
// wasted 4 free half-planes.
// This round (same math, absmax 2.4e-4 lineage):
//   * gate 8 waves x 1 N-tile (48 MFMA each); gate-phase applies = 4 waves
//     x ap<8> (R7's proven shape)
//   * rh pass merged 5 -> 4 phases using free half-planes:
//     rh->T1lo, u->T1hi, m1'->T2lo, {m2'->T0lo || m3'->T2hi}, m4'->T1lo,
//     double-cp in r3; applies in rh run on the (free) gate waves 0-7
//   * 9 phases/layer (was 10); staging stays in final phase
// Roles: pm: wid 0-7 gate | 8-11 cand | 12-15 apply(ap8).
//        r:  wid 0-7 apply | 8-11 cand | 12-15 idle.
// ---------------------------------------------------------------------------

#define GN 81920           // gate repack elems per (layer,plane)
#define CN 40960           // cand repack elems per (layer,plane)
#define WS_NEED ((4*GN + 4*CN) * 2)

#define OFF_T0  0          // term planes: [64][132] u32 (33792 B each)
#define OFF_T1  33792
#define OFF_T2  67584
#define OFF_S0H 101376     // S planes: [64][68] u16 (8704 B each)
#define OFF_S0L 110080
#define OFF_S1H 118784
#define OFF_S1L 127488
#define OFF_HB  136192     // HB: [64][66] u32 (16896 B)
#define OFF_BG  153088
#define OFF_BC  154112
#define OFF_CTL 154624
#define SMEM_SZ 154640

#define RSS 68             // S plane row stride (u16)
#define RSHB 66            // HB row stride (u32)

// swizzled term element index (u32 units)
#define TA(node, feat) ((node) * 132 + ((feat) ^ ((((node) >> 3) & 7) << 3)))

typedef __attribute__((ext_vector_type(4))) short s4v;
typedef __attribute__((ext_vector_type(8))) short s8v;
typedef __attribute__((ext_vector_type(4))) float f4v;

#define MFMA16(a, b, c) __builtin_amdgcn_mfma_f32_16x16x32_bf16((a), (b), (c), 0, 0, 0)

__device__ __forceinline__ float dcr_b2f(unsigned short x) {
  return __uint_as_float(((unsigned)x) << 16);
}
__device__ __forceinline__ unsigned short dcr_f2b(float x) {
  unsigned u = __float_as_uint(x);
  u += 0x7fffu + ((u >> 16) & 1u);
  return (unsigned short)(u >> 16);
}
__device__ __forceinline__ unsigned dcr_pack(float v) {
  unsigned short hh = dcr_f2b(v);
  unsigned short hl = dcr_f2b(v - dcr_b2f(hh));
  return ((unsigned)hl << 16) | (unsigned)hh;
}
__device__ __forceinline__ float dcr_rdw(unsigned w) {
  return dcr_b2f((unsigned short)w) + dcr_b2f((unsigned short)(w >> 16));
}
__device__ __forceinline__ float dcr_ld(const void* p, int idx, int isf) {
  if (isf) return ((const float*)p)[idx];
  return dcr_b2f(((const unsigned short*)p)[idx]);
}
__device__ __forceinline__ float dcr_sigm(float x) {
  return 1.0f / (1.0f + __expf(-x));
}
__device__ __forceinline__ float dcr_tanh(float x) {
  return 2.0f / (1.0f + __expf(-2.0f * x)) - 1.0f;
}
__device__ __forceinline__ s8v dcr_ld8(const unsigned short* p) {
  s8v r;
  *(s4v*)&r = *(const s4v*)p;
  *((s4v*)&r + 1) = *(const s4v*)(p + 4);
  return r;
}

// read 8 interleaved term elements (feats KB..KB+7 of one node) -> ah/al
#define UNPACK8(AH, AL, TP, NODE, KB)                                      \
  {                                                                        \
    const int a0_ = TA(NODE, KB);                                          \
    uint4 q0_ = *(const uint4*)((TP) + a0_);                               \
    uint4 q1_ = *(const uint4*)((TP) + a0_ + 4);                           \
    AH[0] = (short)(q0_.x); AL[0] = (short)(q0_.x >> 16);                  \
    AH[1] = (short)(q0_.y); AL[1] = (short)(q0_.y >> 16);                  \
    AH[2] = (short)(q0_.z); AL[2] = (short)(q0_.z >> 16);                  \
    AH[3] = (short)(q0_.w); AL[3] = (short)(q0_.w >> 16);                  \
    AH[4] = (short)(q1_.x); AL[4] = (short)(q1_.x >> 16);                  \
    AH[5] = (short)(q1_.y); AL[5] = (short)(q1_.y >> 16);                  \
    AH[6] = (short)(q1_.z); AL[6] = (short)(q1_.z >> 16);                  \
    AH[7] = (short)(q1_.w); AL[7] = (short)(q1_.w >> 16);                  \
  }

// ---------------- weight repack: W[(f*5+m)][col] -> fragment order -----------
__global__ void dcr_repack(const void* wg0, const void* wc0,
                           const void* wg1, const void* wc1,
                           const void* s0, unsigned short* o) {
  __shared__ int sisf;
  if (threadIdx.x == 0) {
    const unsigned short* ss = (const unsigned short*)s0;
    int hits = 0;
    for (int i = 0; i < 32; ++i) {
      unsigned hb = ((unsigned)ss[2 * i] >> 8) & 0xFFu;
      if (hb >= 0x30u && hb <= 0x3Fu) ++hits;
    }
    sisf = (hits < 16) ? 1 : 0;
  }
  __syncthreads();
  const int isf = sisf;
  const int NT = 4 * GN + 4 * CN;
  for (int e = blockIdx.x * blockDim.x + threadIdx.x; e < NT;
       e += gridDim.x * blockDim.x) {
    const void* W;
    int pl, ee, ncol, m, nt, ks, lane, j;
    if (e < 4 * GN) {
      int li = e / (2 * GN);
      int rem = e - li * 2 * GN;
      pl = rem / GN;
      ee = rem - pl * GN;
      W = li ? wg1 : wg0;
      ncol = 128;
      j = ee & 7; lane = (ee >> 3) & 63; ks = (ee >> 9) & 3;
      nt = (ee >> 11) & 7; m = ee >> 14;
    } else {
      int c = e - 4 * GN;
      int li = c / (2 * CN);
      int rem = c - li * 2 * CN;
      pl = rem / CN;
      ee = rem - pl * CN;
      W = li ? wc1 : wc0;
      ncol = 64;
      j = ee & 7; lane = (ee >> 3) & 63; ks = (ee >> 9) & 3;
      nt = (ee >> 11) & 3; m = ee >> 13;
    }
    if (pl == 1 && !isf) continue;
    const int f = ks * 32 + ((lane >> 4) & 3) * 8 + j;
    const int col = nt * 16 + (lane & 15);
    const int si = (f * 5 + m) * ncol + col;
    unsigned short v;
    if (!isf) {
      v = ((const unsigned short*)W)[si];
    } else {
      float w = ((const float*)W)[si];
      unsigned short hh = dcr_f2b(w);
      v = (pl == 0) ? hh : dcr_f2b(w - dcr_b2f(hh));
    }
    o[e] = v;
  }
}

// ---------------- MFMA building blocks --------------------------------------
// gate proj one m-term: wave w (0..7) owns N-tile w (16 gate cols), M-tiles
// 0..3 (all 64 nodes).
__device__ __forceinline__ void dcr_gp1(
    f4v& A0, f4v& A1, f4v& A2, f4v& A3,
    const unsigned* T, const unsigned short* rph, const unsigned short* rpl,
    int m, int w, int lane, int wlo) {
  const int ln15 = lane & 15;
  const int k8 = ((lane >> 4) & 3) * 8;
#pragma unroll
  for (int ks = 0; ks < 4; ++ks) {
    const int fo = (((m * 8 + w) * 4 + ks) * 64 + lane) * 8;
    s8v bh = dcr_ld8(rph + fo);
    s8v bl;
    if (wlo) bl = dcr_ld8(rpl + fo);
    const int kb = ks * 32 + k8;
#define DCR_G1(AX, MT)                                                     \
    {                                                                      \
      const int node = (MT) * 16 + ln15;                                   \
      s8v ah, al;                                                          \
      UNPACK8(ah, al, T, node, kb)                                         \
      AX = MFMA16(ah, bh, AX);                                             \
      AX = MFMA16(al, bh, AX);                                             \
      if (wlo) AX = MFMA16(ah, bl, AX);                                    \
    }
    DCR_G1(A0, 0)
    DCR_G1(A1, 1)
    DCR_G1(A2, 2)
    DCR_G1(A3, 3)
#undef DCR_G1
  }
}

// cand proj one m-term: wave w4 (0..3) owns cand N-tile w4. pass 0 = x-half
// (abs ks 0..1), pass 1 = rh-half (abs ks 2..3). tof = term feat-storage
// offset (64 when term lives in a hi half-plane).
__device__ __forceinline__ void dcr_cp(f4v& A0, f4v& A1, f4v& A2, f4v& A3,
                                       const unsigned* T,
                                       const unsigned short* rph,
                                       const unsigned short* rpl,
                                       int m, int w4, int lane, int wlo,
                                       int pass, int tof) {
  const int ln15 = lane & 15;
  const int k8 = ((lane >> 4) & 3) * 8;
#pragma unroll
  for (int ks2 = 0; ks2 < 2; ++ks2) {
    const int ks = pass * 2 + ks2;
    const int fo = (((m * 4 + w4) * 4 + ks) * 64 + lane) * 8;
    s8v bh = dcr_ld8(rph + fo);
    s8v bl;
    if (wlo) bl = dcr_ld8(rpl + fo);
    const int kb = ks2 * 32 + k8;
#define DCR_CPM(AX, MT)                                                    \
    {                                                                      \
      const int node = (MT) * 16 + ln15;                                   \
      s8v ah, al;                                                          \
      UNPACK8(ah, al, T, node, tof + kb)                                   \
      AX = MFMA16(ah, bh, AX);                                             \
      AX = MFMA16(al, bh, AX);                                             \
      if (wlo) AX = MFMA16(ah, bl, AX);                                    \
    }
    DCR_CPM(A0, 0)
    DCR_CPM(A1, 1)
    DCR_CPM(A2, 2)
    DCR_CPM(A3, 3)
#undef DCR_CPM
  }
}

// apply: Y = S @ X. A = S [out][in] (b128, u16 planes, stride RSS=68),
// B = X (interleaved u32 gathers), cheb via C-init = -init/2, 2x writeback.
// sof/iof/dof = feat-storage offsets for src/init/dst (64 = hi half-plane).
// NMT feat-tiles from wave-uniform nmt0; wave owns out-node tile idx.
#define DCR_API(ACX, J)                                                    \
  {                                                                        \
    if (ih_) {                                                             \
      _Pragma("unroll") for (int r = 0; r < 4; ++r)                        \
        ACX[r] = -0.5f *                                                   \
                 dcr_rdw(ih_[TA(orow + rq + r, iof + fb + (J) * 16)]);     \
    } else {                                                               \
      ACX[0] = 0.0f; ACX[1] = 0.0f; ACX[2] = 0.0f; ACX[3] = 0.0f;          \
    }                                                                      \
  }
#define DCR_APM(ACX, J)                                                    \
  {                                                                        \
    s8v bh, b2;                                                            \
    _Pragma("unroll") for (int j = 0; j < 8; ++j) {                        \
      const unsigned w_ = src[TA(kb + j, sof + fb + (J) * 16)];            \
      bh[j] = (short)w_;                                                   \
      b2[j] = (short)(w_ >> 16);                                           \
    }                                                                      \
    ACX = MFMA16(ah, bh, ACX);                                             \
    ACX = MFMA16(ah, b2, ACX);                                             \
    if (wlo) ACX = MFMA16(al, bh, ACX);                                    \
  }
#define DCR_APS(ACX, J)                                                    \
  {                                                                        \
    _Pragma("unroll") for (int r = 0; r < 4; ++r)                          \
      dst[TA(orow + rq + r, dof + fb + (J) * 16)] =                        \
          dcr_pack(fct * ACX[r]);                                          \
  }

template <int NMT>
__device__ __forceinline__ void dcr_ap(const unsigned short* sh_,
                                       const unsigned short* sl_,
                                       const unsigned* src, unsigned* dst,
                                       const unsigned* ih_,
                                       int sof, int iof, int dof,
                                       int idx, int nmt0, int lane, int wlo) {
  const int ln15 = lane & 15;
  const int k8 = ((lane >> 4) & 3) * 8;
  const int rq = ((lane >> 4) & 3) * 4;
  const int orow = idx * 16;        // wave's out-node base
  const int fb = nmt0 * 16 + ln15;  // wave's feat base (uniform nmt0)
  f4v AC0, AC1, AC2, AC3, AC4, AC5, AC6, AC7;
  DCR_API(AC0, 0)
  DCR_API(AC1, 1)
  if constexpr (NMT >= 4) {
    DCR_API(AC2, 2)
    DCR_API(AC3, 3)
  }
  if constexpr (NMT == 8) {
    DCR_API(AC4, 4)
    DCR_API(AC5, 5)
    DCR_API(AC6, 6)
    DCR_API(AC7, 7)
  }
#pragma unroll
  for (int ks = 0; ks < 2; ++ks) {
    const int kb = ks * 32 + k8;
    s8v ah = dcr_ld8(sh_ + (orow + ln15) * RSS + kb);
    s8v al;
    if (wlo) al = dcr_ld8(sl_ + (orow + ln15) * RSS + kb);
    DCR_APM(AC0, 0)
    DCR_APM(AC1, 1)
    if constexpr (NMT >= 4) {
      DCR_APM(AC2, 2)
      DCR_APM(AC3, 3)
    }
    if constexpr (NMT == 8) {
      DCR_APM(AC4, 4)
      DCR_APM(AC5, 5)
      DCR_APM(AC6, 6)
      DCR_APM(AC7, 7)
    }
  }
  const float fct = ih_ ? 2.0f : 1.0f;
  DCR_APS(AC0, 0)
  DCR_APS(AC1, 1)
  if constexpr (NMT >= 4) {
    DCR_APS(AC2, 2)
    DCR_APS(AC3, 3)
  }
  if constexpr (NMT == 8) {
    DCR_APS(AC4, 4)
    DCR_APS(AC5, 5)
    DCR_APS(AC6, 6)
    DCR_APS(AC7, 7)
  }
}

// ---------------- one DCGRU layer step (compile-time L) ---------------------
// cat pre-staged in T0 (prev layer's r3 / prologue). Buffer map:
// pm0: m1=S0@T0->T1        pm1: m2=2S0@T1-T0->T2   pm2: m3=S1@T1->T0
// pm3: m4=2S1@T0-T1->T2    pm4: gfin rh->T1lo u->T1hi
// r0:  m1'=S0@T1lo->T2lo   r1: m2'=2S0@T2lo-T1lo->T0lo || m3'=S1@T2lo->T2hi
// r2:  m4'=2S1@T2hi-T2lo->T1lo   r3: cps m3',m4' + cfin + stage cat->T0
template <int L>
__device__ __forceinline__ void dcr_layer(
    f4v& hA0, f4v& hA1, f4v& hA2, f4v& hA3,
    f4v& hB0, f4v& hB1, f4v& hB2, f4v& hB3,
    const void* xseq, int b, int t, int isf, int wlo,
    const unsigned short* rp,
    unsigned* T0, unsigned* T1, unsigned* T2,
    const unsigned short* S0h, const unsigned short* S0l,
    const unsigned short* S1h, const unsigned short* S1l,
    unsigned* HB, const float* BG, const float* BC,
    int tid, int lane, int wid) {
  const int ln15 = lane & 15;
  const int rq = ((lane >> 4) & 3) * 4;
  const unsigned short* rpgh = rp + (L * 2 + 0) * GN;
  const unsigned short* rpgl = rp + (L * 2 + 1) * GN;
  const unsigned short* rpch = rp + 4 * GN + (L * 2 + 0) * CN;
  const unsigned short* rpcl = rp + 4 * GN + (L * 2 + 1) * CN;

  f4v A0 = {0.0f, 0.0f, 0.0f, 0.0f}, A1 = A0, A2 = A0, A3 = A0;

  // ---------------- pm0 ----------------
  if (wid < 8) dcr_gp1(A0, A1, A2, A3, T0, rpgh, rpgl, 0, wid, lane, wlo);
  else if (wid < 12) dcr_cp(A0, A1, A2, A3, T0, rpch, rpcl, 0, wid - 8, lane, wlo, 0, 0);
  else dcr_ap<8>(S0h, S0l, T0, T1, nullptr, 0, 0, 0, wid - 12, 0, lane, wlo);
  __syncthreads();
  // ---------------- pm1 ----------------
  if (wid < 8) dcr_gp1(A0, A1, A2, A3, T1, rpgh, rpgl, 1, wid, lane, wlo);
  else if (wid < 12) dcr_cp(A0, A1, A2, A3, T1, rpch, rpcl, 1, wid - 8, lane, wlo, 0, 0);
  else dcr_ap<8>(S0h, S0l, T1, T2, T0, 0, 0, 0, wid - 12, 0, lane, wlo);
  __syncthreads();
  // ---------------- pm2 ----------------
  if (wid < 8) dcr_gp1(A0, A1, A2, A3, T2, rpgh, rpgl, 2, wid, lane, wlo);
  else if (wid < 12) dcr_cp(A0, A1, A2, A3, T2, rpch, rpcl, 2, wid - 8, lane, wlo, 0, 0);
  else dcr_ap<8>(S1h, S1l, T1, T0, nullptr, 0, 0, 0, wid - 12, 0, lane, wlo);
  __syncthreads();
  // ---------------- pm3 ----------------
  if (wid < 8) dcr_gp1(A0, A1, A2, A3, T0, rpgh, rpgl, 3, wid, lane, wlo);
  else if (wid < 12) dcr_cp(A0, A1, A2, A3, T0, rpch, rpcl, 3, wid - 8, lane, wlo, 0, 0);
  else dcr_ap<8>(S1h, S1l, T0, T2, T1, 0, 0, 0, wid - 12, 0, lane, wlo);
  __syncthreads();
  // ---------------- pm4: proj m4 + gate finish ----------------
  if (wid < 8) {
    dcr_gp1(A0, A1, A2, A3, T2, rpgh, rpgl, 4, wid, lane, wlo);
    const int g = wid * 16 + ln15;
    const float bgv = BG[L * 128 + g];
#define DCR_GF(AX, MT)                                                     \
    { _Pragma("unroll") for (int r = 0; r < 4; ++r) {                      \
        const int node = (MT) * 16 + rq + r;                               \
        const float s_ = dcr_sigm(AX[r] + bgv);                            \
        if (wid < 4) {                                                     \
          const float h_ = dcr_rdw(HB[node * RSHB + g]);                   \
          T1[TA(node, g)] = dcr_pack(s_ * h_);                             \
        } else {                                                           \
          T1[TA(node, g)] = dcr_pack(s_);                                  \
        } } }
    DCR_GF(A0, 0)
    DCR_GF(A1, 1)
    DCR_GF(A2, 2)
    DCR_GF(A3, 3)
#undef DCR_GF
  } else if (wid < 12) {
    dcr_cp(A0, A1, A2, A3, T2, rpch, rpcl, 4, wid - 8, lane, wlo, 0, 0);
  }
  __syncthreads();
  // ---------------- r0: apply m1' ; cp m0' ----------------
  if (wid < 8) dcr_ap<2>(S0h, S0l, T1, T2, nullptr, 0, 0, 0, wid & 3, (wid < 4) ? 0 : 2, lane, wlo);
  else if (wid < 12) dcr_cp(A0, A1, A2, A3, T1, rpch, rpcl, 0, wid - 8, lane, wlo, 1, 0);
  __syncthreads();
  // ---------------- r1: apply m2' || m3' ; cp m1' ----------------
  if (wid < 4) dcr_ap<4>(S0h, S0l, T2, T0, T1, 0, 0, 0, wid & 3, 0, lane, wlo);
  else if (wid < 8) dcr_ap<4>(S1h, S1l, T2, T2, nullptr, 0, 0, 64, wid & 3, 0, lane, wlo);
  else if (wid < 12) dcr_cp(A0, A1, A2, A3, T2, rpch, rpcl, 1, wid - 8, lane, wlo, 1, 0);
  __syncthreads();
  // ---------------- r2: apply m4' ; cp m2' ----------------
  if (wid < 8) dcr_ap<2>(S1h, S1l, T2, T1, T2, 64, 0, 0, wid & 3, (wid < 4) ? 0 : 2, lane, wlo);
  else if (wid < 12) dcr_cp(A0, A1, A2, A3, T0, rpch, rpcl, 2, wid - 8, lane, wlo, 1, 0);
  __syncthreads();
  // ---------------- r3: cp m3' + cp m4' + cand finish + staging ----------
  if (wid >= 8 && wid < 12) {
    dcr_cp(A0, A1, A2, A3, T2, rpch, rpcl, 3, wid - 8, lane, wlo, 1, 64);
    dcr_cp(A0, A1, A2, A3, T1, rpch, rpcl, 4, wid - 8, lane, wlo, 1, 0);
    const int f = (wid - 8) * 16 + ln15;
    const float bcv = BC[L * 64 + f];
#define DCR_CF(AX, HX, MT)                                                 \
    { _Pragma("unroll") for (int r = 0; r < 4; ++r) {                      \
        const int node = (MT) * 16 + rq + r;                               \
        const float c = dcr_tanh(AX[r] + bcv);                             \
        const float u = dcr_rdw(T1[TA(node, 64 + f)]);                     \
        HX[r] = u * HX[r] + (1.0f - u) * c; } }
    if constexpr (L == 0) {
      DCR_CF(A0, hA0, 0)
      DCR_CF(A1, hA1, 1)
      DCR_CF(A2, hA2, 2)
      DCR_CF(A3, hA3, 3)
      // stage layer-1 cat = [hA | hB]; HB <- hB (layer-1 recurrent h)
#define DCR_SG0(HAX, HBX, MT)                                              \
      { _Pragma("unroll") for (int r = 0; r < 4; ++r) {                    \
          const int node = (MT) * 16 + rq + r;                             \
          T0[TA(node, f)] = dcr_pack(HAX[r]);                              \
          const unsigned pw = dcr_pack(HBX[r]);                            \
          T0[TA(node, 64 + f)] = pw;                                       \
          HB[node * RSHB + f] = pw; } }
      DCR_SG0(hA0, hB0, 0)
      DCR_SG0(hA1, hB1, 1)
      DCR_SG0(hA2, hB2, 2)
      DCR_SG0(hA3, hB3, 3)
#undef DCR_SG0
    } else {
      DCR_CF(A0, hB0, 0)
      DCR_CF(A1, hB1, 1)
      DCR_CF(A2, hB2, 2)
      DCR_CF(A3, hB3, 3)
      // stage next-t layer-0 cat h-half = hA; HB <- hA
#define DCR_SG1(HAX, MT)                                                   \
      { _Pragma("unroll") for (int r = 0; r < 4; ++r) {                    \
          const int node = (MT) * 16 + rq + r;                             \
          const unsigned pw = dcr_pack(HAX[r]);                            \
          T0[TA(node, 64 + f)] = pw;                                       \
          HB[node * RSHB + f] = pw; } }
      DCR_SG1(hA0, 0)
      DCR_SG1(hA1, 1)
      DCR_SG1(hA2, 2)
      DCR_SG1(hA3, 3)
#undef DCR_SG1
    }
#undef DCR_CF
  } else if (L == 1 && wid < 8) {
    // stage x_{t+1} -> T0 feats 0-63 (latency hidden under cand's cps)
    const int tn = (t < 95) ? (t + 1) : 95;
    const int n = tid >> 3;
    const int f0 = (tid & 7) * 8;
    const int xo = (b * 96 + tn) * 4096 + n * 64 + f0;
    const int base = TA(n, f0);
    uint4 q0, q1;
    if (isf) {
      const float* xp = (const float*)xseq + xo;
      q0.x = dcr_pack(xp[0]); q0.y = dcr_pack(xp[1]);
      q0.z = dcr_pack(xp[2]); q0.w = dcr_pack(xp[3]);
      q1.x = dcr_pack(xp[4]); q1.y = dcr_pack(xp[5]);
      q1.z = dcr_pack(xp[6]); q1.w = dcr_pack(xp[7]);
    } else {
      const unsigned short* xp = (const unsigned short*)xseq + xo;
      s8v v = *(const s8v*)xp;
      q0.x = (unsigned)(unsigned short)v[0];
      q0.y = (unsigned)(unsigned short)v[1];
      q0.z = (unsigned)(unsigned short)v[2];
      q0.w = (unsigned)(unsigned short)v[3];
      q1.x = (unsigned)(unsigned short)v[4];
      q1.y = (unsigned)(unsigned short)v[5];
      q1.z = (unsigned)(unsigned short)v[6];
      q1.w = (unsigned)(unsigned short)v[7];
    }
    *(uint4*)(T0 + base) = q0;
    *(uint4*)(T0 + base + 4) = q1;
  }
  __syncthreads();
}

// ---------------- main MFMA kernel ------------------------------------------
__global__ __launch_bounds__(1024)
__attribute__((amdgpu_waves_per_eu(4, 4)))
void dcr_mfma(
    const void* xseq, const void* s0, const void* s1,
    const void* bg0, const void* bg1,
    const void* p64a, const void* p64b, const void* p64c,
    const void* fcw, const void* fcb, const void* idw, const void* idb,
    const unsigned short* rp, void* outp) {
  extern __shared__ char sm[];
  unsigned* const T0 = (unsigned*)(sm + OFF_T0);
  unsigned* const T1 = (unsigned*)(sm + OFF_T1);
  unsigned* const T2 = (unsigned*)(sm + OFF_T2);
  unsigned short* const S0h = (unsigned short*)(sm + OFF_S0H);
  unsigned short* const S0l = (unsigned short*)(sm + OFF_S0L);
  unsigned short* const S1h = (unsigned short*)(sm + OFF_S1H);
  unsigned short* const S1l = (unsigned short*)(sm + OFF_S1L);
  unsigned* const HB = (unsigned*)(sm + OFF_HB);
  float* const BG = (float*)(sm + OFF_BG);
  float* const BC = (float*)(sm + OFF_BC);
  int* const ctl = (int*)(sm + OFF_CTL);

  const int tid = threadIdx.x;
  const int b = blockIdx.x;
  const int lane = tid & 63;
  const int wid = tid >> 6;

  // ---- on-device identification ----
  if (tid == 0) {
    const unsigned short* ss = (const unsigned short*)s0;
    int hits = 0;
    for (int i = 0; i < 32; ++i) {
      unsigned hb = ((unsigned)ss[2 * i] >> 8) & 0xFFu;
      if (hb >= 0x30u && hb <= 0x3Fu) ++hits;
    }
    int isf_ = (hits < 16) ? 1 : 0;
    int sel = 0;
    {
      const unsigned* w = (const unsigned*)p64a;
      unsigned any = 0;
      for (int i = 0; i < 16; ++i) any |= w[i];
      if (!any) {
        sel = 1;
        const unsigned* w1 = (const unsigned*)p64b;
        unsigned any1 = 0;
        for (int i = 0; i < 16; ++i) any1 |= w1[i];
        if (!any1) sel = 2;
      }
    }
    const unsigned* w =
        (const unsigned*)(sel == 0 ? p64a : (sel == 1 ? p64b : p64c));
    int i64 = 1;
    for (int i = 0; i < 8; ++i)
      if (w[2 * i + 1] != 0u) i64 = 0;
    ctl[0] = isf_;
    ctl[1] = sel;
    ctl[2] = i64;
  }
  __syncthreads();
  const int isf = ctl[0];
  const int sel = ctl[1];
  const int i64 = ctl[2];
  const int wlo = isf;  // lo planes of S/W meaningful only for fp32 inputs
  const void* seqp = (sel == 0) ? p64a : (sel == 1 ? p64b : p64c);
  const void* bcA = (sel == 0) ? p64b : p64a;
  const void* bcB = (sel == 2) ? p64b : p64c;

  // ---- stage supports (hi/lo u16, stride RSS) and biases ----
  for (int i = 0; i < 4; ++i) {
    const int flat = i * 1024 + tid;  // = out*64 + in
    const int out = flat >> 6, in = flat & 63;
    float v0, v1;
    if (isf) {
      v0 = ((const float*)s0)[flat];
      v1 = ((const float*)s1)[flat];
    } else {
      v0 = dcr_b2f(((const unsigned short*)s0)[flat]);
      v1 = dcr_b2f(((const unsigned short*)s1)[flat]);
    }
    unsigned short hh = dcr_f2b(v0);
    S0h[out * RSS + in] = hh;
    S0l[out * RSS + in] = dcr_f2b(v0 - dcr_b2f(hh));
    hh = dcr_f2b(v1);
    S1h[out * RSS + in] = hh;
    S1l[out * RSS + in] = dcr_f2b(v1 - dcr_b2f(hh));
  }
  if (tid < 128) {
    BG[tid] = dcr_ld(bg0, tid, isf);
    BG[128 + tid] = dcr_ld(bg1, tid, isf);
  } else if (tid < 192) {
    const int j = tid - 128;
    BC[j] = dcr_ld(bcA, j, isf);
    BC[64 + j] = dcr_ld(bcB, j, isf);
  }

  int tl_;
  if (i64) tl_ = (int)((const long long*)seqp)[b] - 1;
  else     tl_ = ((const int*)seqp)[b] - 1;
  if (tl_ < 0) tl_ = 0;
  if (tl_ > 95) tl_ = 95;

  f4v hA0 = {0.0f, 0.0f, 0.0f, 0.0f}, hA1 = hA0, hA2 = hA0, hA3 = hA0;
  f4v hB0 = hA0, hB1 = hA0, hB2 = hA0, hB3 = hA0;

  const int ln15 = lane & 15;
  const int rq = ((lane >> 4) & 3) * 4;

  // ---- prologue: stage cat_0 = [x_0 | h=0] into T0, zero HB ----
  if (wid < 8) {
    const int n = tid >> 3;
    const int f0 = (tid & 7) * 8;
    const int xo = (b * 96 + 0) * 4096 + n * 64 + f0;
    const int base = TA(n, f0);
    uint4 q0, q1;
    if (isf) {
      const float* xp = (const float*)xseq + xo;
      q0.x = dcr_pack(xp[0]); q0.y = dcr_pack(xp[1]);
      q0.z = dcr_pack(xp[2]); q0.w = dcr_pack(xp[3]);
      q1.x = dcr_pack(xp[4]); q1.y = dcr_pack(xp[5]);
      q1.z = dcr_pack(xp[6]); q1.w = dcr_pack(xp[7]);
    } else {
      const unsigned short* xp = (const unsigned short*)xseq + xo;
      s8v v = *(const s8v*)xp;
      q0.x = (unsigned)(unsigned short)v[0];
      q0.y = (unsigned)(unsigned short)v[1];
      q0.z = (unsigned)(unsigned short)v[2];
      q0.w = (unsigned)(unsigned short)v[3];
      q1.x = (unsigned)(unsigned short)v[4];
      q1.y = (unsigned)(unsigned short)v[5];
      q1.z = (unsigned)(unsigned short)v[6];
      q1.w = (unsigned)(unsigned short)v[7];
    }
    *(uint4*)(T0 + base) = q0;
    *(uint4*)(T0 + base + 4) = q1;
  } else if (wid < 12) {
    const int f = (wid - 8) * 16 + ln15;
#pragma unroll
    for (int mt = 0; mt < 4; ++mt)
#pragma unroll
      for (int r = 0; r < 4; ++r) {
        const int node = mt * 16 + rq + r;
        T0[TA(node, 64 + f)] = 0u;
        HB[node * RSHB + f] = 0u;
      }
  }
  __syncthreads();

  for (int t = 0; t < 96; ++t) {
    dcr_layer<0>(hA0, hA1, hA2, hA3, hB0, hB1, hB2, hB3,
                 xseq, b, t, isf, wlo, rp, T0, T1, T2,
                 S0h, S0l, S1h, S1l, HB, BG, BC, tid, lane, wid);
    dcr_layer<1>(hA0, hA1, hA2, hA3, hB0, hB1, hB2, hB3,
                 xseq, b, t, isf, wlo, rp, T0, T1, T2,
                 S0h, S0l, S1h, S1l, HB, BG, BC, tid, lane, wid);
    if (t == tl_) break;
  }

  // ---------------- heads: relu(h1) -> fc/id matmul -> max over nodes -------
  __syncthreads();
  float* const hx = (float*)(sm + OFF_T0);   // [64][66]
  float* const hw = (float*)(sm + OFF_T1);   // [64][56]
  float* const red = (float*)(sm + OFF_T2);  // [16][54]
  if (wid >= 8 && wid < 12) {
    const int f = (wid - 8) * 16 + ln15;
#define DCR_HX(HX, MT)                                                     \
    { _Pragma("unroll") for (int r = 0; r < 4; ++r) {                      \
        const int node = (MT) * 16 + rq + r;                               \
        hx[node * 66 + f] = fmaxf(HX[r], 0.0f); } }
    DCR_HX(hB0, 0)
    DCR_HX(hB1, 1)
    DCR_HX(hB2, 2)
    DCR_HX(hB3, 3)
#undef DCR_HX
  }
  {
    const int u = tid >> 4;
    for (int c = (tid & 15); c < 54; c += 16)
      hw[u * 56 + c] = (c < 4) ? dcr_ld(fcw, u * 4 + c, isf)
                               : dcr_ld(idw, u * 50 + (c - 4), isf);
  }
  __syncthreads();
  if (tid < 864) {
    const int c = tid % 54, nb = tid / 54;
    float mx = -3.4e38f;
    for (int nn = nb * 4; nn < nb * 4 + 4; ++nn) {
      float s = 0.0f;
#pragma unroll 8
      for (int uu = 0; uu < 64; ++uu) s += hx[nn * 66 + uu] * hw[uu * 56 + c];
      mx = fmaxf(mx, s);
    }
    red[nb * 54 + c] = mx;
  }
  __syncthreads();
  if (tid < 54) {
    float mx = red[tid];
#pragma unroll
    for (int g = 1; g < 16; ++g) mx = fmaxf(mx, red[g * 54 + tid]);
    mx += (tid < 4) ? dcr_ld(fcb, tid, isf) : dcr_ld(idb, tid - 4, isf);
    const int o = (tid < 4) ? (b * 4 + tid) : (256 + b * 50 + (tid - 4));
    if (isf) ((float*)outp)[o] = mx;
    else     ((unsigned short*)outp)[o] = dcr_f2b(mx);
  }
}

// ============================================================================
// Fallback: proven scalar kernel (round-1, 1024 threads) for ws-too-small.
// ============================================================================
__device__ void dcr_proj(float* aG, float* aC, const float (*buf)[68],
                         const void* Wg, const void* Wc, int m, int fh,
                         int n, int fb, int doG, int doC, int isf) {
  if (!isf) {
    const unsigned* G = (const unsigned*)Wg;
    const unsigned* C = (const unsigned*)Wc;
    const int fd = fb >> 1;
#pragma unroll 4
    for (int k = 0; k < 64; ++k) {
      float xk = buf[n][k];
      int row = (fh + k) * 5 + m;
      if (doG) {
        const unsigned* wr = G + row * 64 + fd;
        unsigned p0 = wr[0], p1 = wr[1], p2 = wr[32], p3 = wr[33];
        aG[0] += xk * __uint_as_float(p0 << 16);
        aG[1] += xk * __uint_as_float(p0 & 0xFFFF0000u);
        aG[2] += xk * __uint_as_float(p1 << 16);
        aG[3] += xk * __uint_as_float(p1 & 0xFFFF0000u);
        aG[4] += xk * __uint_as_float(p2 << 16);
        aG[5] += xk * __uint_as_float(p2 & 0xFFFF0000u);
        aG[6] += xk * __uint_as_float(p3 << 16);
        aG[7] += xk * __uint_as_float(p3 & 0xFFFF0000u);
      }
      if (doC) {
        const unsigned* wr = C + row * 32 + fd;
        unsigned p0 = wr[0], p1 = wr[1];
        aC[0] += xk * __uint_as_float(p0 << 16);
        aC[1] += xk * __uint_as_float(p0 & 0xFFFF0000u);
        aC[2] += xk * __uint_as_float(p1 << 16);
        aC[3] += xk * __uint_as_float(p1 & 0xFFFF0000u);
      }
    }
  } else {
    const float* G = (const float*)Wg;
    const float* C = (const float*)Wc;
#pragma unroll 4
    for (int k = 0; k < 64; ++k) {
      float xk = buf[n][k];
      int row = (fh + k) * 5 + m;
      if (doG) {
        const float* wr = G + row * 128 + fb;
#pragma unroll
        for (int j = 0; j < 4; ++j) {
          aG[j] += xk * wr[j];
          aG[4 + j] += xk * wr[64 + j];
        }
      }
      if (doC) {
        const float* wr = C + row * 64 + fb;
#pragma unroll
        for (int j = 0; j < 4; ++j) aC[j] += xk * wr[j];
      }
    }
  }
}

__device__ void dcr_apply(float (*dst)[68], const float (*src)[68],
                          const unsigned short (*sS)[65], int n, int fb,
                          int cheb) {
  float a0 = 0.0f, a1 = 0.0f, a2 = 0.0f, a3 = 0.0f;
#pragma unroll 8
  for (int m = 0; m < 64; ++m) {
    float s = dcr_b2f(sS[n][m]);
    float4 v = *(const float4*)(&src[m][fb]);
    a0 += s * v.x;
    a1 += s * v.y;
    a2 += s * v.z;
    a3 += s * v.w;
  }
  if (cheb) {
    dst[n][fb + 0] = 2.0f * a0 - dst[n][fb + 0];
    dst[n][fb + 1] = 2.0f * a1 - dst[n][fb + 1];
    dst[n][fb + 2] = 2.0f * a2 - dst[n][fb + 2];
    dst[n][fb + 3] = 2.0f * a3 - dst[n][fb + 3];
  } else {
    dst[n][fb + 0] = a0;
    dst[n][fb + 1] = a1;
    dst[n][fb + 2] = a2;
    dst[n][fb + 3] = a3;
  }
}

__device__ void dcr_half(float* aG, float* aC, const void* Wg, const void* Wc,
                         int fh, int doG, int doC, float (*xa)[68],
                         float (*xb)[68], const unsigned short (*sS0)[65],
                         const unsigned short (*sS1)[65], int n, int fb,
                         int isf) {
  dcr_proj(aG, aC, xa, Wg, Wc, 0, fh, n, fb, doG, doC, isf);
  dcr_apply(xb, xa, sS0, n, fb, 0);
  __syncthreads();
  dcr_proj(aG, aC, xb, Wg, Wc, 1, fh, n, fb, doG, doC, isf);
  dcr_apply(xa, xb, sS0, n, fb, 1);
  __syncthreads();
  dcr_proj(aG, aC, xa, Wg, Wc, 2, fh, n, fb, doG, doC, isf);
  __syncthreads();
  dcr_apply(xa, xb, sS1, n, fb, 0);
  __syncthreads();
  dcr_proj(aG, aC, xa, Wg, Wc, 3, fh, n, fb, doG, doC, isf);
  dcr_apply(xb, xa, sS1, n, fb, 1);
  __syncthreads();
  dcr_proj(aG, aC, xb, Wg, Wc, 4, fh, n, fb, doG, doC, isf);
  __syncthreads();
}

__global__ __launch_bounds__(1024) void dcr_scalar(
    const void* xseq, const void* s0, const void* s1, const void* wg0,
    const void* wc0, const void* wg1, const void* wc1, const void* bg0,
    const void* bg1, const void* p64a, const void* p64b, const void* p64c,
    const void* fcw, const void* fcb, const void* idw, const void* idb,
    void* outp) {
  __shared__ float xa[64][68];
  __shared__ float xb[64][68];
  __shared__ unsigned short sS[2][64][65];
  __shared__ float bGs[2][128];
  __shared__ float bCs[2][64];
  __shared__ float red[16][54];
  __shared__ int ctl[4];

  const int tid = threadIdx.x;
  const int b = blockIdx.x;
  const int n = tid >> 4;
  const int fb = (tid & 15) * 4;

  if (tid == 0) {
    const unsigned short* ss = (const unsigned short*)s0;
    int hits = 0;
    for (int i = 0; i < 32; ++i) {
      unsigned hb = ((unsigned)ss[2 * i] >> 8) & 0xFFu;
      if (hb >= 0x30u && hb <= 0x3Fu) ++hits;
    }
    int isf = (hits < 16) ? 1 : 0;
    int sel = 0;
    {
      const unsigned* w = (const unsigned*)p64a;
      unsigned any = 0;
      for (int i = 0; i < 16; ++i) any |= w[i];
      if (!any) {
        sel = 1;
        const unsigned* w1 = (const unsigned*)p64b;
        unsigned any1 = 0;
        for (int i = 0; i < 16; ++i) any1 |= w1[i];
        if (!any1) sel = 2;
      }
    }
    const unsigned* w =
        (const unsigned*)(sel == 0 ? p64a : (sel == 1 ? p64b : p64c));
    int i64 = 1;
    for (int i = 0; i < 8; ++i)
      if (w[2 * i + 1] != 0u) i64 = 0;
    ctl[0] = isf;
    ctl[1] = sel;
    ctl[2] = i64;
  }
  __syncthreads();
  const int isf = ctl[0];
  const int sel = ctl[1];
  const int i64 = ctl[2];
  const void* seqp = (sel == 0) ? p64a : (sel == 1 ? p64b : p64c);
  const void* bcA = (sel == 0) ? p64b : p64a;
  const void* bcB = (sel == 2) ? p64b : p64c;

  for (int i = 0; i < 4; ++i) {
    int flat = i * 1024 + tid;
    int nn = flat >> 6, mm = flat & 63;
    unsigned short v0, v1;
    if (isf) {
      v0 = dcr_f2b(((const float*)s0)[flat]);
      v1 = dcr_f2b(((const float*)s1)[flat]);
    } else {
      v0 = ((const unsigned short*)s0)[flat];
      v1 = ((const unsigned short*)s1)[flat];
    }
    sS[0][nn][mm] = v0;
    sS[1][nn][mm] = v1;
  }
  if (tid < 128) {
    bGs[0][tid] = dcr_ld(bg0, tid, isf);
    bGs[1][tid] = dcr_ld(bg1, tid, isf);
  } else if (tid < 192) {
    int j = tid - 128;
    bCs[0][j] = dcr_ld(bcA, j, isf);
    bCs[1][j] = dcr_ld(bcB, j, isf);
  }

  int tl;
  if (i64) tl = (int)((const long long*)seqp)[b] - 1;
  else     tl = ((const int*)seqp)[b] - 1;
  if (tl < 0) tl = 0;
  if (tl > 95) tl = 95;

  float h0r[4], h1r[4];
#pragma unroll
  for (int j = 0; j < 4; ++j) {
    h0r[j] = 0.0f;
    h1r[j] = 0.0f;
  }
  __syncthreads();

  for (int t = 0; t < 96; ++t) {
    {
      float aG[8], aC[4];
#pragma unroll
      for (int j = 0; j < 8; ++j) aG[j] = 0.0f;
#pragma unroll
      for (int j = 0; j < 4; ++j) aC[j] = 0.0f;
      int xoff = (b * 96 + t) * 4096 + n * 64 + fb;
#pragma unroll
      for (int j = 0; j < 4; ++j) xa[n][fb + j] = dcr_ld(xseq, xoff + j, isf);
      __syncthreads();
      dcr_half(aG, aC, wg0, wc0, 0, 1, 1, xa, xb, sS[0], sS[1], n, fb, isf);
#pragma unroll
      for (int j = 0; j < 4; ++j) xa[n][fb + j] = h0r[j];
      __syncthreads();
      dcr_half(aG, aC, wg0, wc0, 64, 1, 0, xa, xb, sS[0], sS[1], n, fb, isf);
      float rr[4], uu[4];
#pragma unroll
      for (int j = 0; j < 4; ++j) {
        rr[j] = dcr_sigm(aG[j] + bGs[0][fb + j]);
        uu[j] = dcr_sigm(aG[4 + j] + bGs[0][64 + fb + j]);
      }
#pragma unroll
      for (int j = 0; j < 4; ++j) xa[n][fb + j] = rr[j] * h0r[j];
      __syncthreads();
      dcr_half(aG, aC, wg0, wc0, 64, 0, 1, xa, xb, sS[0], sS[1], n, fb, isf);
#pragma unroll
      for (int j = 0; j < 4; ++j) {
        float c = dcr_tanh(aC[j] + bCs[0][fb + j]);
        h0r[j] = uu[j] * h0r[j] + (1.0f - uu[j]) * c;
      }
    }
    {
      float aG[8], aC[4];
#pragma unroll
      for (int j = 0; j < 8; ++j) aG[j] = 0.0f;
#pragma unroll
      for (int j = 0; j < 4; ++j) aC[j] = 0.0f;
#pragma unroll
      for (int j = 0; j < 4; ++j) xa[n][fb + j] = h0r[j];
      __syncthreads();
      dcr_half(aG, aC, wg1, wc1, 0, 1, 1, xa, xb, sS[0], sS[1], n, fb, isf);
#pragma unroll
      for (int j = 0; j < 4; ++j) xa[n][fb + j] = h1r[j];
      __syncthreads();
      dcr_half(aG, aC, wg1, wc1, 64, 1, 0, xa, xb, sS[0], sS[1], n, fb, isf);
      float rr[4], uu[4];
#pragma unroll
      for (int j = 0; j < 4; ++j) {
        rr[j] = dcr_sigm(aG[j] + bGs[1][fb + j]);
        uu[j] = dcr_sigm(aG[4 + j] + bGs[1][64 + fb + j]);
      }
#pragma unroll
      for (int j = 0; j < 4; ++j) xa[n][fb + j] = rr[j] * h1r[j];
      __syncthreads();
      dcr_half(aG, aC, wg1, wc1, 64, 0, 1, xa, xb, sS[0], sS[1], n, fb, isf);
#pragma unroll
      for (int j = 0; j < 4; ++j) {
        float c = dcr_tanh(aC[j] + bCs[1][fb + j]);
        h1r[j] = uu[j] * h1r[j] + (1.0f - uu[j]) * c;
      }
    }
    if (t == tl) break;
  }

  __syncthreads();
#pragma unroll
  for (int j = 0; j < 4; ++j) xa[n][fb + j] = fmaxf(h1r[j], 0.0f);
  {
    int u = tid >> 4;
    for (int c = (tid & 15); c < 54; c += 16)
      xb[u][c] = (c < 4) ? dcr_ld(fcw, u * 4 + c, isf)
                         : dcr_ld(idw, u * 50 + (c - 4), isf);
  }
  __syncthreads();
  if (tid < 864) {
    int c = tid % 54, nb = tid / 54;
    float mx = -3.4e38f;
    for (int nn = nb * 4; nn < nb * 4 + 4; ++nn) {
      float s = 0.0f;
#pragma unroll 8
      for (int u = 0; u < 64; ++u) s += xa[nn][u] * xb[u][c];
      mx = fmaxf(mx, s);
    }
    red[nb][c] = mx;
  }
  __syncthreads();
  if (tid < 54) {
    float mx = red[0][tid];
#pragma unroll
    for (int g = 1; g < 16; ++g) mx = fmaxf(mx, red[g][tid]);
    mx += (tid < 4) ? dcr_ld(fcb, tid, isf) : dcr_ld(idb, tid - 4, isf);
    int o = (tid < 4) ? (b * 4 + tid) : (256 + b * 50 + (tid - 4));
    if (isf) ((float*)outp)[o] = mx;
    else     ((unsigned short*)outp)[o] = dcr_f2b(mx);
  }
}

// ---------------------------------------------------------------------------
static int dcr_find_nth(const int* s, int n, int sz, int nth) {
  int c = 0;
  for (int i = 0; i < n; ++i)
    if (s[i] == sz) {
      if (c == nth) return i;
      ++c;
    }
  return -1;
}

extern "C" void kernel_launch(void* const* d_in, const int* in_sizes, int n_in,
                              void* d_out, int out_size, void* d_ws,
                              size_t ws_size, hipStream_t stream) {
  (void)out_size;
  int i_seq = dcr_find_nth(in_sizes, n_in, 393216, 0);
  int i_s0 = dcr_find_nth(in_sizes, n_in, 4096, 0);
  int i_s1 = dcr_find_nth(in_sizes, n_in, 4096, 1);
  int i_wg0 = dcr_find_nth(in_sizes, n_in, 81920, 0);
  int i_wg1 = dcr_find_nth(in_sizes, n_in, 81920, 1);
  int i_wc0 = dcr_find_nth(in_sizes, n_in, 40960, 0);
  int i_wc1 = dcr_find_nth(in_sizes, n_in, 40960, 1);
  int i_bg0 = dcr_find_nth(in_sizes, n_in, 128, 0);
  int i_bg1 = dcr_find_nth(in_sizes, n_in, 128, 1);
  int i_64a = dcr_find_nth(in_sizes, n_in, 64, 0);
  int i_64b = dcr_find_nth(in_sizes, n_in, 64, 1);
  int i_64c = dcr_find_nth(in_sizes, n_in, 64, 2);
  int i_fcw = dcr_find_nth(in_sizes, n_in, 256, 0);
  int i_fcb = dcr_find_nth(in_sizes, n_in, 4, 0);
  int i_idw = dcr_find_nth(in_sizes, n_in, 3200, 0);
  int i_idb = dcr_find_nth(in_sizes, n_in, 50, 0);
  if (i_seq < 0 || i_s0 < 0 || i_s1 < 0 || i_wg0 < 0 || i_wg1 < 0 ||
      i_wc0 < 0 || i_wc1 < 0 || i_bg0 < 0 || i_bg1 < 0 || i_64a < 0 ||
      i_64b < 0 || i_64c < 0 || i_fcw < 0 || i_fcb < 0 || i_idw < 0 ||
      i_idb < 0) {
    i_seq = 0;  i_64a = 1;  i_s0 = 2;   i_s1 = 3;
    i_wg0 = 4;  i_bg0 = 5;  i_wc0 = 6;  i_64b = 7;
    i_wg1 = 8;  i_bg1 = 9;  i_wc1 = 10; i_64c = 11;
    i_fcw = 12; i_fcb = 13; i_idw = 14; i_idb = 15;
  }

  if (d_ws == nullptr || ws_size < (size_t)WS_NEED) {
    dcr_scalar<<<dim3(64), dim3(1024), 0, stream>>>(
        d_in[i_seq], d_in[i_s0], d_in[i_s1], d_in[i_wg0], d_in[i_wc0],
        d_in[i_wg1], d_in[i_wc1], d_in[i_bg0], d_in[i_bg1], d_in[i_64a],
        d_in[i_64b], d_in[i_64c], d_in[i_fcw], d_in[i_fcb], d_in[i_idw],
        d_in[i_idb], d_out);
    return;
  }

  dcr_repack<<<dim3(256), dim3(256), 0, stream>>>(
      d_in[i_wg0], d_in[i_wc0], d_in[i_wg1], d_in[i_wc1], d_in[i_s0],
      (unsigned short*)d_ws);

  static bool attr_set = false;
  if (!attr_set) {
    (void)hipFuncSetAttribute((const void*)dcr_mfma,
                              hipFuncAttributeMaxDynamicSharedMemorySize,
                              SMEM_SZ);
    attr_set = true;
  }

  dcr_mfma<<<dim3(64), dim3(1024), SMEM_SZ, stream>>>(
      d_in[i_seq], d_in[i_s0], d_in[i_s1], d_in[i_bg0], d_in[i_bg1],
      d_in[i_64a], d_in[i_64b], d_in[i_64c], d_in[i_fcw], d_in[i_fcb],
      d_in[i_idw], d_in[i_idb], (const unsigned short*)d_ws, d_out);
}